// Round 2
// baseline (518.706 us; speedup 1.0000x reference)
//
#include <hip/hip_runtime.h>
#include <math.h>

#define N_NODES 100000
#define N_EDGES 1600000
#define NFEAT 128
#define NHID 128
#define NS 64
#define NCLASS 16
#define BB 8192

#define SCAN_NB 391   // ceil(N_NODES / 256)

// ---------------- bf16 helpers ----------------

__device__ __forceinline__ float bf2f(unsigned short u) {
  union { unsigned int i; float f; } c;
  c.i = ((unsigned int)u) << 16;
  return c.f;
}
__device__ __forceinline__ unsigned short f2bf(float f) {
  unsigned int u = __float_as_uint(f);
  return (unsigned short)((u + 0x7fffu + ((u >> 16) & 1u)) >> 16);  // RNE
}

// ---------------- CSR build ----------------

__global__ __launch_bounds__(256) void hist_kernel(const int* __restrict__ row,
                                                   int* __restrict__ counts) {
  int i = blockIdx.x * blockDim.x + threadIdx.x;
  int stride = gridDim.x * blockDim.x;
  for (; i < N_EDGES; i += stride) atomicAdd(&counts[row[i]], 1);
}

__global__ __launch_bounds__(256) void partial_kernel(const int* __restrict__ counts,
                                                      int* __restrict__ bsum) {
  __shared__ int sd[256];
  int i = blockIdx.x * 256 + threadIdx.x;
  sd[threadIdx.x] = (i < N_NODES) ? counts[i] : 0;
  __syncthreads();
  for (int o = 128; o > 0; o >>= 1) {
    if (threadIdx.x < o) sd[threadIdx.x] += sd[threadIdx.x + o];
    __syncthreads();
  }
  if (threadIdx.x == 0) bsum[blockIdx.x] = sd[0];
}

__global__ __launch_bounds__(512) void scanp_kernel(const int* __restrict__ bsum,
                                                    int* __restrict__ bpre,
                                                    int* __restrict__ offs) {
  __shared__ int sd[512];
  int tid = threadIdx.x;
  int v = (tid < SCAN_NB) ? bsum[tid] : 0;
  sd[tid] = v;
  __syncthreads();
  for (int o = 1; o < 512; o <<= 1) {
    int add = (tid >= o) ? sd[tid - o] : 0;
    __syncthreads();
    sd[tid] += add;
    __syncthreads();
  }
  if (tid < SCAN_NB) bpre[tid] = sd[tid] - v;        // exclusive prefix of block sums
  if (tid == SCAN_NB - 1) offs[N_NODES] = sd[tid];   // total edge count
}

__global__ __launch_bounds__(256) void apply_kernel(const int* __restrict__ counts,
                                                    const int* __restrict__ bpre,
                                                    int* __restrict__ offs,
                                                    int* __restrict__ cursor) {
  __shared__ int sd[256];
  int tid = threadIdx.x;
  int i = blockIdx.x * 256 + tid;
  int v = (i < N_NODES) ? counts[i] : 0;
  sd[tid] = v;
  __syncthreads();
  for (int o = 1; o < 256; o <<= 1) {
    int add = (tid >= o) ? sd[tid - o] : 0;
    __syncthreads();
    sd[tid] += add;
    __syncthreads();
  }
  int off = bpre[blockIdx.x] + sd[tid] - v;  // global exclusive prefix
  if (i < N_NODES) {
    offs[i] = off;
    cursor[i] = off;
  }
}

// packed scatter: one 8B store per edge (col in low 32, val bits in high 32)
__global__ __launch_bounds__(256) void scatter_kernel(const int* __restrict__ row,
                                                      const int* __restrict__ col,
                                                      const float* __restrict__ val,
                                                      int* __restrict__ cursor,
                                                      unsigned long long* __restrict__ edat) {
  int i = blockIdx.x * blockDim.x + threadIdx.x;
  int stride = gridDim.x * blockDim.x;
  for (; i < N_EDGES; i += stride) {
    int r = row[i];
    unsigned long long packed =
        ((unsigned long long)__float_as_uint(val[i]) << 32) | (unsigned int)col[i];
    int p = atomicAdd(&cursor[r], 1);
    edat[p] = packed;
  }
}

// ---------------- dense GEMM: C[nr,128] = A[nr,128] @ W[128,128] (+bias) ----------------
// block = 256 threads, 32 rows per block; W staged in LDS in two 64-row halves.
// Each thread computes a 4-row x 4-col register tile. OUT_BF16 selects output dtype.

__device__ __forceinline__ void fma4(float4& acc, const float4& a,
                                     const float4& w0, const float4& w1,
                                     const float4& w2, const float4& w3) {
  acc.x = fmaf(a.x, w0.x, fmaf(a.y, w1.x, fmaf(a.z, w2.x, fmaf(a.w, w3.x, acc.x))));
  acc.y = fmaf(a.x, w0.y, fmaf(a.y, w1.y, fmaf(a.z, w2.y, fmaf(a.w, w3.y, acc.y))));
  acc.z = fmaf(a.x, w0.z, fmaf(a.y, w1.z, fmaf(a.z, w2.z, fmaf(a.w, w3.z, acc.z))));
  acc.w = fmaf(a.x, w0.w, fmaf(a.y, w1.w, fmaf(a.z, w2.w, fmaf(a.w, w3.w, acc.w))));
}

template <int OUT_BF16>
__global__ __launch_bounds__(256) void gemm128_kernel(const float* __restrict__ A,
                                                      const float* __restrict__ W,
                                                      const float* __restrict__ bias,
                                                      void* __restrict__ C,
                                                      int do_bias) {
  __shared__ float Ws[64 * 128];
  int tid = threadIdx.x;
  int c0 = (tid & 31) * 4;   // col 0..124 step 4
  int rg = tid >> 5;         // row group 0..7
  long rbase = (long)blockIdx.x * 32 + rg * 4;
  const float* A0 = A + rbase * 128;
  float4* Ws4 = (float4*)Ws;

  float4 acc0 = {0, 0, 0, 0}, acc1 = {0, 0, 0, 0}, acc2 = {0, 0, 0, 0}, acc3 = {0, 0, 0, 0};

  for (int half = 0; half < 2; ++half) {
    const float4* Wsrc = (const float4*)(W + half * 64 * 128);
#pragma unroll
    for (int i = 0; i < 8; ++i) Ws4[tid + i * 256] = Wsrc[tid + i * 256];
    __syncthreads();
    const float* Ah = A0 + half * 64;
#pragma unroll 4
    for (int k = 0; k < 64; k += 4) {
      float4 w0 = *(const float4*)&Ws[(k + 0) * 128 + c0];
      float4 w1 = *(const float4*)&Ws[(k + 1) * 128 + c0];
      float4 w2 = *(const float4*)&Ws[(k + 2) * 128 + c0];
      float4 w3 = *(const float4*)&Ws[(k + 3) * 128 + c0];
      float4 a0 = *(const float4*)(Ah + 0 * 128 + k);
      float4 a1 = *(const float4*)(Ah + 1 * 128 + k);
      float4 a2 = *(const float4*)(Ah + 2 * 128 + k);
      float4 a3 = *(const float4*)(Ah + 3 * 128 + k);
      fma4(acc0, a0, w0, w1, w2, w3);
      fma4(acc1, a1, w0, w1, w2, w3);
      fma4(acc2, a2, w0, w1, w2, w3);
      fma4(acc3, a3, w0, w1, w2, w3);
    }
    __syncthreads();
  }

  float4 bv = {0, 0, 0, 0};
  if (do_bias) bv = *(const float4*)&bias[c0];
  acc0.x += bv.x; acc0.y += bv.y; acc0.z += bv.z; acc0.w += bv.w;
  acc1.x += bv.x; acc1.y += bv.y; acc1.z += bv.z; acc1.w += bv.w;
  acc2.x += bv.x; acc2.y += bv.y; acc2.z += bv.z; acc2.w += bv.w;
  acc3.x += bv.x; acc3.y += bv.y; acc3.z += bv.z; acc3.w += bv.w;

  if (OUT_BF16) {
    unsigned short* Cp = (unsigned short*)C + rbase * 128 + c0;
    ushort4 o0 = {f2bf(acc0.x), f2bf(acc0.y), f2bf(acc0.z), f2bf(acc0.w)};
    ushort4 o1 = {f2bf(acc1.x), f2bf(acc1.y), f2bf(acc1.z), f2bf(acc1.w)};
    ushort4 o2 = {f2bf(acc2.x), f2bf(acc2.y), f2bf(acc2.z), f2bf(acc2.w)};
    ushort4 o3 = {f2bf(acc3.x), f2bf(acc3.y), f2bf(acc3.z), f2bf(acc3.w)};
    *(ushort4*)(Cp + 0 * 128) = o0;
    *(ushort4*)(Cp + 1 * 128) = o1;
    *(ushort4*)(Cp + 2 * 128) = o2;
    *(ushort4*)(Cp + 3 * 128) = o3;
  } else {
    float* Cp = (float*)C + rbase * 128 + c0;
    *(float4*)(Cp + 0 * 128) = acc0;
    *(float4*)(Cp + 1 * 128) = acc1;
    *(float4*)(Cp + 2 * 128) = acc2;
    *(float4*)(Cp + 3 * 128) = acc3;
  }
}

// ---------------- CSR spmm (one wave per row, 2 feats/lane, bf16 gather) ----------------

__global__ __launch_bounds__(64) void spmm_row_kernel(const int* __restrict__ offs,
                                                      const unsigned long long* __restrict__ edat,
                                                      const unsigned short* __restrict__ a,
                                                      const float* __restrict__ bias,
                                                      unsigned short* __restrict__ h) {
  int r = blockIdx.x;
  int tid = threadIdx.x;
  int s = offs[r], e = offs[r + 1];
  float2 acc = {0.f, 0.f};
  for (int j = s; j < e; ++j) {
    unsigned long long p = edat[j];
    int c = (int)(unsigned int)(p & 0xffffffffu);
    float v = __uint_as_float((unsigned int)(p >> 32));
    ushort2 av = *(const ushort2*)(a + (long)c * 128 + tid * 2);
    acc.x = fmaf(v, bf2f(av.x), acc.x);
    acc.y = fmaf(v, bf2f(av.y), acc.y);
  }
  float2 bv = *(const float2*)(bias + tid * 2);
  ushort2 o;
  o.x = f2bf(fmaxf(acc.x + bv.x, 0.f));
  o.y = f2bf(fmaxf(acc.y + bv.y, 0.f));
  *(ushort2*)(h + (long)r * 128 + tid * 2) = o;
}

// spmm restricted to the 8192 selected rows (layer 2 aggregation, pre-GEMM)
__global__ __launch_bounds__(64) void spmm_sel_kernel(const int* __restrict__ offs,
                                                      const unsigned long long* __restrict__ edat,
                                                      const unsigned short* __restrict__ h1,
                                                      const int* __restrict__ index,
                                                      float* __restrict__ g2) {
  int b = blockIdx.x;
  int tid = threadIdx.x;
  int r = index[b];
  int s = offs[r], e = offs[r + 1];
  float2 acc = {0.f, 0.f};
  for (int j = s; j < e; ++j) {
    unsigned long long p = edat[j];
    int c = (int)(unsigned int)(p & 0xffffffffu);
    float v = __uint_as_float((unsigned int)(p >> 32));
    ushort2 av = *(const ushort2*)(h1 + (long)c * 128 + tid * 2);
    acc.x = fmaf(v, bf2f(av.x), acc.x);
    acc.y = fmaf(v, bf2f(av.y), acc.y);
  }
  *(float2*)(g2 + (long)b * 128 + tid * 2) = acc;
}

// ---------------- final: z = concat(t, s) @ Wl + bl; log_softmax ----------------

__global__ __launch_bounds__(128) void final_kernel(const float* __restrict__ t,
                                                    const float* __restrict__ s,
                                                    const float* __restrict__ Wl,
                                                    const float* __restrict__ bl,
                                                    float* __restrict__ out) {
  int b = blockIdx.x * 128 + threadIdx.x;  // 8192 threads exactly
  float z[16];
#pragma unroll
  for (int c = 0; c < 16; ++c) z[c] = bl[c];
  const float4* tb = (const float4*)(t + (long)b * 128);
#pragma unroll 4
  for (int k4 = 0; k4 < 32; ++k4) {
    float4 tv = tb[k4];
    const float* w = Wl + (k4 * 4) * 16;
#pragma unroll
    for (int c = 0; c < 16; ++c)
      z[c] += tv.x * w[c] + tv.y * w[16 + c] + tv.z * w[32 + c] + tv.w * w[48 + c];
  }
  const float4* sb = (const float4*)(s + (long)b * 64);
#pragma unroll 4
  for (int k4 = 0; k4 < 16; ++k4) {
    float4 sv = sb[k4];
    const float* w = Wl + (128 + k4 * 4) * 16;
#pragma unroll
    for (int c = 0; c < 16; ++c)
      z[c] += sv.x * w[c] + sv.y * w[16 + c] + sv.z * w[32 + c] + sv.w * w[48 + c];
  }
  float m = z[0];
#pragma unroll
  for (int c = 1; c < 16; ++c) m = fmaxf(m, z[c]);
  float sum = 0.f;
#pragma unroll
  for (int c = 0; c < 16; ++c) sum += expf(z[c] - m);
  float lse = m + logf(sum);
  float* ob = out + (long)b * 16;
#pragma unroll
  for (int c = 0; c < 16; ++c) ob[c] = z[c] - lse;
}

// ---------------- launch ----------------

extern "C" void kernel_launch(void* const* d_in, const int* in_sizes, int n_in,
                              void* d_out, int out_size, void* d_ws, size_t ws_size,
                              hipStream_t stream) {
  const float* s_in  = (const float*)d_in[0];
  const float* x     = (const float*)d_in[1];
  const int*   row   = (const int*)d_in[2];
  const int*   col   = (const int*)d_in[3];
  const float* val   = (const float*)d_in[4];
  const int*   index = (const int*)d_in[5];
  const float* W1    = (const float*)d_in[6];
  const float* b1    = (const float*)d_in[7];
  const float* W2    = (const float*)d_in[8];
  const float* b2    = (const float*)d_in[9];
  const float* Wl    = (const float*)d_in[10];
  const float* bl    = (const float*)d_in[11];
  float* out = (float*)d_out;

  // workspace carve (~74 MB). edat first for 8B alignment.
  unsigned long long* edat = (unsigned long long*)d_ws;              // [1.6M] packed (col,val)
  unsigned short* a  = (unsigned short*)(edat + N_EDGES);            // xW1 bf16   [100000,128]
  unsigned short* h1 = a + (size_t)N_NODES * 128;                    // layer1 bf16[100000,128]
  float* g2   = (float*)(h1 + (size_t)N_NODES * 128);                // sel spmm   [8192,128]
  float* tmat = g2 + (size_t)BB * 128;                               // g2@W2+b2   [8192,128]
  int* counts = (int*)(tmat + (size_t)BB * 128);                     // [100000]
  int* offs   = counts + N_NODES;                                    // [100001]
  int* cursor = offs + (N_NODES + 1);                                // [100000]
  int* bsum   = cursor + N_NODES;                                    // [391]
  int* bpre   = bsum + SCAN_NB;                                      // [391]

  hipMemsetAsync(counts, 0, N_NODES * sizeof(int), stream);
  hist_kernel<<<4096, 256, 0, stream>>>(row, counts);
  partial_kernel<<<SCAN_NB, 256, 0, stream>>>(counts, bsum);
  scanp_kernel<<<1, 512, 0, stream>>>(bsum, bpre, offs);
  apply_kernel<<<SCAN_NB, 256, 0, stream>>>(counts, bpre, offs, cursor);
  scatter_kernel<<<4096, 256, 0, stream>>>(row, col, val, cursor, edat);

  gemm128_kernel<1><<<N_NODES / 32, 256, 0, stream>>>(x, W1, nullptr, a, 0);
  spmm_row_kernel<<<N_NODES, 64, 0, stream>>>(offs, edat, a, b1, h1);
  spmm_sel_kernel<<<BB, 64, 0, stream>>>(offs, edat, h1, index, g2);
  gemm128_kernel<0><<<BB / 32, 256, 0, stream>>>(g2, W2, b2, tmat, 1);
  final_kernel<<<BB / 128, 128, 0, stream>>>(tmat, s_in, Wl, bl, out);
}

// Round 3
// 467.230 us; speedup vs baseline: 1.1102x; 1.1102x over previous
//
#include <hip/hip_runtime.h>
#include <math.h>

#define N_NODES 100000
#define N_EDGES 1600000
#define NFEAT 128
#define NHID 128
#define NS 64
#define NCLASS 16
#define BB 8192

#define SCAN_NB 391   // ceil(N_NODES / 256)

// binned CSR build geometry
#define B1_SHIFT 11               // 2048 rows per L1 bucket
#define NB1 49                    // ceil(100000 / 2048)
#define SUB_SHIFT 5               // 32 rows per sub-bucket
#define NSUB 3125                 // 100000 / 32
#define CHUNK 1024                // edges per block-iteration in bin passes

typedef unsigned long long ull;

// ---------------- bf16 helpers ----------------

__device__ __forceinline__ float bf2f(unsigned short u) {
  union { unsigned int i; float f; } c;
  c.i = ((unsigned int)u) << 16;
  return c.f;
}
__device__ __forceinline__ unsigned short f2bf(float f) {
  unsigned int u = __float_as_uint(f);
  return (unsigned short)((u + 0x7fffu + ((u >> 16) & 1u)) >> 16);  // RNE
}

// ---------------- edge packing: [63:34]=val[31:2], [33:17]=row, [16:0]=col ----------------

__device__ __forceinline__ ull pack_edge(float v, int r, int c) {
  return ((ull)(__float_as_uint(v) >> 2) << 34) | ((ull)(unsigned)r << 17) | (unsigned)c;
}
__device__ __forceinline__ int edge_col(ull p) { return (int)(p & 0x1FFFFu); }
__device__ __forceinline__ int edge_row(ull p) { return (int)((unsigned)(p >> 17) & 0x1FFFFu); }
__device__ __forceinline__ float edge_val(ull p) {
  return __uint_as_float(((unsigned)(p >> 34)) << 2);
}

// ---------------- row histogram + offs scan ----------------

__global__ __launch_bounds__(256) void hist_kernel(const int* __restrict__ row,
                                                   int* __restrict__ counts) {
  int i = blockIdx.x * blockDim.x + threadIdx.x;
  int stride = gridDim.x * blockDim.x;
  for (; i < N_EDGES; i += stride) atomicAdd(&counts[row[i]], 1);
}

__global__ __launch_bounds__(256) void partial_kernel(const int* __restrict__ counts,
                                                      int* __restrict__ bsum) {
  __shared__ int sd[256];
  int i = blockIdx.x * 256 + threadIdx.x;
  sd[threadIdx.x] = (i < N_NODES) ? counts[i] : 0;
  __syncthreads();
  for (int o = 128; o > 0; o >>= 1) {
    if (threadIdx.x < o) sd[threadIdx.x] += sd[threadIdx.x + o];
    __syncthreads();
  }
  if (threadIdx.x == 0) bsum[blockIdx.x] = sd[0];
}

__global__ __launch_bounds__(512) void scanp_kernel(const int* __restrict__ bsum,
                                                    int* __restrict__ bpre,
                                                    int* __restrict__ offs) {
  __shared__ int sd[512];
  int tid = threadIdx.x;
  int v = (tid < SCAN_NB) ? bsum[tid] : 0;
  sd[tid] = v;
  __syncthreads();
  for (int o = 1; o < 512; o <<= 1) {
    int add = (tid >= o) ? sd[tid - o] : 0;
    __syncthreads();
    sd[tid] += add;
    __syncthreads();
  }
  if (tid < SCAN_NB) bpre[tid] = sd[tid] - v;
  if (tid == SCAN_NB - 1) offs[N_NODES] = sd[tid];
}

__global__ __launch_bounds__(256) void apply_kernel(const int* __restrict__ counts,
                                                    const int* __restrict__ bpre,
                                                    int* __restrict__ offs) {
  __shared__ int sd[256];
  int tid = threadIdx.x;
  int i = blockIdx.x * 256 + tid;
  int v = (i < N_NODES) ? counts[i] : 0;
  sd[tid] = v;
  __syncthreads();
  for (int o = 1; o < 256; o <<= 1) {
    int add = (tid >= o) ? sd[tid - o] : 0;
    __syncthreads();
    sd[tid] += add;
    __syncthreads();
  }
  if (i < N_NODES) offs[i] = bpre[blockIdx.x] + sd[tid] - v;
}

__global__ __launch_bounds__(256) void initcur_kernel(const int* __restrict__ offs,
                                                      int* __restrict__ gcur1,
                                                      int* __restrict__ gcur2) {
  int t = blockIdx.x * 256 + threadIdx.x;
  if (t < NB1) gcur1[t] = offs[t << B1_SHIFT];
  if (t < NSUB) gcur2[t] = offs[t << SUB_SHIFT];
}

// ---------------- pass A: edges -> 49 L1 bucket regions (coalesced runs) ----------------

__global__ __launch_bounds__(256) void binA_kernel(const int* __restrict__ row,
                                                   const int* __restrict__ col,
                                                   const float* __restrict__ val,
                                                   int* __restrict__ gcur1,
                                                   ull* __restrict__ ebuf1) {
  __shared__ ull stage[CHUNK];
  __shared__ int hist[NB1], lofs[NB1 + 1], lcur[NB1], gbase[NB1];
  int tid = threadIdx.x;
  for (long base = (long)blockIdx.x * CHUNK; base < N_EDGES; base += (long)gridDim.x * CHUNK) {
    int cnt = (int)min((long)CHUNK, (long)N_EDGES - base);
    if (tid < NB1) hist[tid] = 0;
    __syncthreads();
    ull e[4]; int bk[4];
#pragma unroll
    for (int v = 0; v < 4; ++v) {
      int i = v * 256 + tid;
      bk[v] = -1;
      if (i < cnt) {
        long g = base + i;
        int r = row[g];
        e[v] = pack_edge(val[g], r, col[g]);
        bk[v] = r >> B1_SHIFT;
        atomicAdd(&hist[bk[v]], 1);
      }
    }
    __syncthreads();
    if (tid < 64) {
      int h = (tid < NB1) ? hist[tid] : 0;
      int x = h;
      for (int o = 1; o < 64; o <<= 1) {
        int y = __shfl_up(x, o);
        if (tid >= o) x += y;
      }
      if (tid < NB1) { lofs[tid] = x - h; lcur[tid] = x - h; }
      if (tid == 63) lofs[NB1] = x;  // == cnt
    }
    __syncthreads();
#pragma unroll
    for (int v = 0; v < 4; ++v) {
      if (bk[v] >= 0) {
        int pos = atomicAdd(&lcur[bk[v]], 1);
        stage[pos] = e[v];
      }
    }
    __syncthreads();
    if (tid < NB1) {
      int h = hist[tid];
      if (h > 0) gbase[tid] = atomicAdd(&gcur1[tid], h);
    }
    __syncthreads();
    for (int s = tid; s < cnt; s += 256) {
      int lo = 0, hi = NB1;
      while (hi - lo > 1) {
        int mid = (lo + hi) >> 1;
        if (lofs[mid] <= s) lo = mid; else hi = mid;
      }
      ebuf1[gbase[lo] + (s - lofs[lo])] = stage[s];
    }
    __syncthreads();
  }
}

// ---------------- pass B: L1 bucket -> 64 sub-bucket regions ----------------

__global__ __launch_bounds__(256) void binB_kernel(const ull* __restrict__ ebuf1,
                                                   const int* __restrict__ offs,
                                                   int* __restrict__ gcur2,
                                                   ull* __restrict__ edat) {
  __shared__ ull stage[CHUNK];
  __shared__ int hist[64], lofs[65], lcur[64], gbase[64];
  int tid = threadIdx.x;
  int b1 = blockIdx.x >> 3, w = blockIdx.x & 7;
  int rbeg = offs[b1 << B1_SHIFT];
  int rend = offs[min((b1 + 1) << B1_SHIFT, N_NODES)];
  for (int base = rbeg + w * CHUNK; base < rend; base += 8 * CHUNK) {
    int cnt = min(CHUNK, rend - base);
    if (tid < 64) hist[tid] = 0;
    __syncthreads();
    ull e[4]; int bk[4];
#pragma unroll
    for (int v = 0; v < 4; ++v) {
      int i = v * 256 + tid;
      bk[v] = -1;
      if (i < cnt) {
        e[v] = ebuf1[base + i];
        bk[v] = (edge_row(e[v]) >> SUB_SHIFT) - (b1 << 6);
        atomicAdd(&hist[bk[v]], 1);
      }
    }
    __syncthreads();
    if (tid < 64) {
      int h = hist[tid];
      int x = h;
      for (int o = 1; o < 64; o <<= 1) {
        int y = __shfl_up(x, o);
        if (tid >= o) x += y;
      }
      lofs[tid] = x - h;
      lcur[tid] = x - h;
      if (tid == 63) lofs[64] = x;  // == cnt
    }
    __syncthreads();
#pragma unroll
    for (int v = 0; v < 4; ++v) {
      if (bk[v] >= 0) {
        int pos = atomicAdd(&lcur[bk[v]], 1);
        stage[pos] = e[v];
      }
    }
    __syncthreads();
    if (tid < 64) {
      int h = hist[tid];
      if (h > 0) gbase[tid] = atomicAdd(&gcur2[(b1 << 6) + tid], h);
    }
    __syncthreads();
    for (int s = tid; s < cnt; s += 256) {
      int lo = 0, hi = 64;
      while (hi - lo > 1) {
        int mid = (lo + hi) >> 1;
        if (lofs[mid] <= s) lo = mid; else hi = mid;
      }
      edat[gbase[lo] + (s - lofs[lo])] = stage[s];
    }
    __syncthreads();
  }
}

// ---------------- pass C: exact row placement within each 32-row sub-bucket ----------------

__global__ __launch_bounds__(256) void binC_kernel(const int* __restrict__ offs,
                                                   ull* __restrict__ edat,
                                                   ull* __restrict__ ebuf1) {
  __shared__ int rcnt[32], rofs[32], rcur[32];
  int s = blockIdx.x, tid = threadIdx.x;
  int r0 = s << SUB_SHIFT;
  int beg = offs[r0], end = offs[min(r0 + 32, N_NODES)];
  int n = end - beg;
  if (tid < 32) rcnt[tid] = 0;
  __syncthreads();
  for (int i = tid; i < n; i += 256) {
    ull p = edat[beg + i];
    ebuf1[beg + i] = p;                    // scratch copy (region private to this WG)
    atomicAdd(&rcnt[edge_row(p) & 31], 1);
  }
  __syncthreads();
  if (tid < 32) {
    int h = rcnt[tid];
    int x = h;
    for (int o = 1; o < 32; o <<= 1) {
      int y = __shfl_up(x, o, 32);
      if (tid >= o) x += y;
    }
    rofs[tid] = x - h;
    rcur[tid] = x - h;
  }
  __syncthreads();
  for (int i = tid; i < n; i += 256) {
    ull p = ebuf1[beg + i];
    int pos = atomicAdd(&rcur[edge_row(p) & 31], 1);
    edat[beg + pos] = p;
  }
}

// ---------------- dense GEMM: C[nr,128] = A[nr,128] @ W[128,128] (+bias) ----------------

__device__ __forceinline__ void fma4(float4& acc, const float4& a,
                                     const float4& w0, const float4& w1,
                                     const float4& w2, const float4& w3) {
  acc.x = fmaf(a.x, w0.x, fmaf(a.y, w1.x, fmaf(a.z, w2.x, fmaf(a.w, w3.x, acc.x))));
  acc.y = fmaf(a.x, w0.y, fmaf(a.y, w1.y, fmaf(a.z, w2.y, fmaf(a.w, w3.y, acc.y))));
  acc.z = fmaf(a.x, w0.z, fmaf(a.y, w1.z, fmaf(a.z, w2.z, fmaf(a.w, w3.z, acc.z))));
  acc.w = fmaf(a.x, w0.w, fmaf(a.y, w1.w, fmaf(a.z, w2.w, fmaf(a.w, w3.w, acc.w))));
}

template <int OUT_BF16>
__global__ __launch_bounds__(256) void gemm128_kernel(const float* __restrict__ A,
                                                      const float* __restrict__ W,
                                                      const float* __restrict__ bias,
                                                      void* __restrict__ C,
                                                      int do_bias) {
  __shared__ float Ws[64 * 128];
  int tid = threadIdx.x;
  int c0 = (tid & 31) * 4;
  int rg = tid >> 5;
  long rbase = (long)blockIdx.x * 32 + rg * 4;
  const float* A0 = A + rbase * 128;
  float4* Ws4 = (float4*)Ws;

  float4 acc0 = {0, 0, 0, 0}, acc1 = {0, 0, 0, 0}, acc2 = {0, 0, 0, 0}, acc3 = {0, 0, 0, 0};

  for (int half = 0; half < 2; ++half) {
    const float4* Wsrc = (const float4*)(W + half * 64 * 128);
#pragma unroll
    for (int i = 0; i < 8; ++i) Ws4[tid + i * 256] = Wsrc[tid + i * 256];
    __syncthreads();
    const float* Ah = A0 + half * 64;
#pragma unroll 4
    for (int k = 0; k < 64; k += 4) {
      float4 w0 = *(const float4*)&Ws[(k + 0) * 128 + c0];
      float4 w1 = *(const float4*)&Ws[(k + 1) * 128 + c0];
      float4 w2 = *(const float4*)&Ws[(k + 2) * 128 + c0];
      float4 w3 = *(const float4*)&Ws[(k + 3) * 128 + c0];
      float4 a0 = *(const float4*)(Ah + 0 * 128 + k);
      float4 a1 = *(const float4*)(Ah + 1 * 128 + k);
      float4 a2 = *(const float4*)(Ah + 2 * 128 + k);
      float4 a3 = *(const float4*)(Ah + 3 * 128 + k);
      fma4(acc0, a0, w0, w1, w2, w3);
      fma4(acc1, a1, w0, w1, w2, w3);
      fma4(acc2, a2, w0, w1, w2, w3);
      fma4(acc3, a3, w0, w1, w2, w3);
    }
    __syncthreads();
  }

  float4 bv = {0, 0, 0, 0};
  if (do_bias) bv = *(const float4*)&bias[c0];
  acc0.x += bv.x; acc0.y += bv.y; acc0.z += bv.z; acc0.w += bv.w;
  acc1.x += bv.x; acc1.y += bv.y; acc1.z += bv.z; acc1.w += bv.w;
  acc2.x += bv.x; acc2.y += bv.y; acc2.z += bv.z; acc2.w += bv.w;
  acc3.x += bv.x; acc3.y += bv.y; acc3.z += bv.z; acc3.w += bv.w;

  if (OUT_BF16) {
    unsigned short* Cp = (unsigned short*)C + rbase * 128 + c0;
    ushort4 o0 = {f2bf(acc0.x), f2bf(acc0.y), f2bf(acc0.z), f2bf(acc0.w)};
    ushort4 o1 = {f2bf(acc1.x), f2bf(acc1.y), f2bf(acc1.z), f2bf(acc1.w)};
    ushort4 o2 = {f2bf(acc2.x), f2bf(acc2.y), f2bf(acc2.z), f2bf(acc2.w)};
    ushort4 o3 = {f2bf(acc3.x), f2bf(acc3.y), f2bf(acc3.z), f2bf(acc3.w)};
    *(ushort4*)(Cp + 0 * 128) = o0;
    *(ushort4*)(Cp + 1 * 128) = o1;
    *(ushort4*)(Cp + 2 * 128) = o2;
    *(ushort4*)(Cp + 3 * 128) = o3;
  } else {
    float* Cp = (float*)C + rbase * 128 + c0;
    *(float4*)(Cp + 0 * 128) = acc0;
    *(float4*)(Cp + 1 * 128) = acc1;
    *(float4*)(Cp + 2 * 128) = acc2;
    *(float4*)(Cp + 3 * 128) = acc3;
  }
}

// ---------------- CSR spmm (one wave per row, 2 feats/lane, bf16 gather) ----------------

__global__ __launch_bounds__(64) void spmm_row_kernel(const int* __restrict__ offs,
                                                      const ull* __restrict__ edat,
                                                      const unsigned short* __restrict__ a,
                                                      const float* __restrict__ bias,
                                                      unsigned short* __restrict__ h) {
  int r = blockIdx.x;
  int tid = threadIdx.x;
  int s = offs[r], e = offs[r + 1];
  float2 acc = {0.f, 0.f};
  for (int j = s; j < e; ++j) {
    ull p = edat[j];
    int c = edge_col(p);
    float v = edge_val(p);
    ushort2 av = *(const ushort2*)(a + (long)c * 128 + tid * 2);
    acc.x = fmaf(v, bf2f(av.x), acc.x);
    acc.y = fmaf(v, bf2f(av.y), acc.y);
  }
  float2 bv = *(const float2*)(bias + tid * 2);
  ushort2 o;
  o.x = f2bf(fmaxf(acc.x + bv.x, 0.f));
  o.y = f2bf(fmaxf(acc.y + bv.y, 0.f));
  *(ushort2*)(h + (long)r * 128 + tid * 2) = o;
}

__global__ __launch_bounds__(64) void spmm_sel_kernel(const int* __restrict__ offs,
                                                      const ull* __restrict__ edat,
                                                      const unsigned short* __restrict__ h1,
                                                      const int* __restrict__ index,
                                                      float* __restrict__ g2) {
  int b = blockIdx.x;
  int tid = threadIdx.x;
  int r = index[b];
  int s = offs[r], e = offs[r + 1];
  float2 acc = {0.f, 0.f};
  for (int j = s; j < e; ++j) {
    ull p = edat[j];
    int c = edge_col(p);
    float v = edge_val(p);
    ushort2 av = *(const ushort2*)(h1 + (long)c * 128 + tid * 2);
    acc.x = fmaf(v, bf2f(av.x), acc.x);
    acc.y = fmaf(v, bf2f(av.y), acc.y);
  }
  *(float2*)(g2 + (long)b * 128 + tid * 2) = acc;
}

// ---------------- final: z = concat(t, s) @ Wl + bl; log_softmax ----------------

__global__ __launch_bounds__(128) void final_kernel(const float* __restrict__ t,
                                                    const float* __restrict__ s,
                                                    const float* __restrict__ Wl,
                                                    const float* __restrict__ bl,
                                                    float* __restrict__ out) {
  int b = blockIdx.x * 128 + threadIdx.x;
  float z[16];
#pragma unroll
  for (int c = 0; c < 16; ++c) z[c] = bl[c];
  const float4* tb = (const float4*)(t + (long)b * 128);
#pragma unroll 4
  for (int k4 = 0; k4 < 32; ++k4) {
    float4 tv = tb[k4];
    const float* w = Wl + (k4 * 4) * 16;
#pragma unroll
    for (int c = 0; c < 16; ++c)
      z[c] += tv.x * w[c] + tv.y * w[16 + c] + tv.z * w[32 + c] + tv.w * w[48 + c];
  }
  const float4* sb = (const float4*)(s + (long)b * 64);
#pragma unroll 4
  for (int k4 = 0; k4 < 16; ++k4) {
    float4 sv = sb[k4];
    const float* w = Wl + (128 + k4 * 4) * 16;
#pragma unroll
    for (int c = 0; c < 16; ++c)
      z[c] += sv.x * w[c] + sv.y * w[16 + c] + sv.z * w[32 + c] + sv.w * w[48 + c];
  }
  float m = z[0];
#pragma unroll
  for (int c = 1; c < 16; ++c) m = fmaxf(m, z[c]);
  float sum = 0.f;
#pragma unroll
  for (int c = 0; c < 16; ++c) sum += expf(z[c] - m);
  float lse = m + logf(sum);
  float* ob = out + (long)b * 16;
#pragma unroll
  for (int c = 0; c < 16; ++c) ob[c] = z[c] - lse;
}

// ---------------- launch ----------------

extern "C" void kernel_launch(void* const* d_in, const int* in_sizes, int n_in,
                              void* d_out, int out_size, void* d_ws, size_t ws_size,
                              hipStream_t stream) {
  const float* s_in  = (const float*)d_in[0];
  const float* x     = (const float*)d_in[1];
  const int*   row   = (const int*)d_in[2];
  const int*   col   = (const int*)d_in[3];
  const float* val   = (const float*)d_in[4];
  const int*   index = (const int*)d_in[5];
  const float* W1    = (const float*)d_in[6];
  const float* b1    = (const float*)d_in[7];
  const float* W2    = (const float*)d_in[8];
  const float* b2    = (const float*)d_in[9];
  const float* Wl    = (const float*)d_in[10];
  const float* bl    = (const float*)d_in[11];
  float* out = (float*)d_out;

  // workspace carve (~86 MB), 8B-aligned first
  ull* edat  = (ull*)d_ws;                                           // [1.6M] final CSR edges
  ull* ebuf1 = edat + N_EDGES;                                       // [1.6M] L1-bucketed temp
  unsigned short* a  = (unsigned short*)(ebuf1 + N_EDGES);           // xW1 bf16   [100000,128]
  unsigned short* h1 = a + (size_t)N_NODES * 128;                    // layer1 bf16[100000,128]
  float* g2   = (float*)(h1 + (size_t)N_NODES * 128);                // sel spmm   [8192,128]
  float* tmat = g2 + (size_t)BB * 128;                               // g2@W2+b2   [8192,128]
  int* counts = (int*)(tmat + (size_t)BB * 128);                     // [100000]
  int* offs   = counts + N_NODES;                                    // [100001]
  int* bsum   = offs + (N_NODES + 1);                                // [391]
  int* bpre   = bsum + SCAN_NB;                                      // [391]
  int* gcur1  = bpre + SCAN_NB;                                      // [49]
  int* gcur2  = gcur1 + NB1;                                         // [3125]

  hipMemsetAsync(counts, 0, N_NODES * sizeof(int), stream);
  hist_kernel<<<4096, 256, 0, stream>>>(row, counts);
  partial_kernel<<<SCAN_NB, 256, 0, stream>>>(counts, bsum);
  scanp_kernel<<<1, 512, 0, stream>>>(bsum, bpre, offs);
  apply_kernel<<<SCAN_NB, 256, 0, stream>>>(counts, bpre, offs);
  initcur_kernel<<<(NSUB + 255) / 256, 256, 0, stream>>>(offs, gcur1, gcur2);

  binA_kernel<<<512, 256, 0, stream>>>(row, col, val, gcur1, ebuf1);
  binB_kernel<<<NB1 * 8, 256, 0, stream>>>(ebuf1, offs, gcur2, edat);
  binC_kernel<<<NSUB, 256, 0, stream>>>(offs, edat, ebuf1);

  gemm128_kernel<1><<<N_NODES / 32, 256, 0, stream>>>(x, W1, nullptr, a, 0);
  spmm_row_kernel<<<N_NODES, 64, 0, stream>>>(offs, edat, a, b1, h1);
  spmm_sel_kernel<<<BB, 64, 0, stream>>>(offs, edat, h1, index, g2);
  gemm128_kernel<0><<<BB / 32, 256, 0, stream>>>(g2, W2, b2, tmat, 1);
  final_kernel<<<BB / 128, 128, 0, stream>>>(tmat, s_in, Wl, bl, out);
}

// Round 4
// 430.992 us; speedup vs baseline: 1.2035x; 1.0841x over previous
//
#include <hip/hip_runtime.h>
#include <math.h>

#define N_NODES 100000
#define N_EDGES 1600000
#define NFEAT 128
#define NHID 128
#define NS 64
#define NCLASS 16
#define BB 8192

#define SCAN_NB 391   // ceil(N_NODES / 256)

// binned CSR build geometry
#define B1_SHIFT 11               // 2048 rows per L1 bucket
#define NB1 49                    // ceil(100000 / 2048)
#define SUB_SHIFT 5               // 32 rows per sub-bucket
#define NSUB 3125                 // 100000 / 32
#define CHUNK 1024                // edges per block-iteration in bin passes

typedef unsigned long long ull;

// ---------------- bf16 helpers ----------------

__device__ __forceinline__ unsigned short f2bf(float f) {
  unsigned int u = __float_as_uint(f);
  return (unsigned short)((u + 0x7fffu + ((u >> 16) & 1u)) >> 16);  // RNE
}
__device__ __forceinline__ float bflo(unsigned int u) {  // low bf16 of packed uint
  return __uint_as_float(u << 16);
}
__device__ __forceinline__ float bfhi(unsigned int u) {  // high bf16 of packed uint
  return __uint_as_float(u & 0xffff0000u);
}
__device__ __forceinline__ unsigned int packbf2(float lo, float hi) {
  return (unsigned int)f2bf(lo) | ((unsigned int)f2bf(hi) << 16);
}

// ---------------- edge packing: [63:34]=val[31:2], [33:17]=row, [16:0]=col ----------------

__device__ __forceinline__ ull pack_edge(float v, int r, int c) {
  return ((ull)(__float_as_uint(v) >> 2) << 34) | ((ull)(unsigned)r << 17) | (unsigned)c;
}
__device__ __forceinline__ int edge_col(ull p) { return (int)(p & 0x1FFFFu); }
__device__ __forceinline__ int edge_row(ull p) { return (int)((unsigned)(p >> 17) & 0x1FFFFu); }
__device__ __forceinline__ float edge_val(ull p) {
  return __uint_as_float(((unsigned)(p >> 34)) << 2);
}

// ---------------- row histogram + offs scan ----------------

__global__ __launch_bounds__(256) void hist_kernel(const int* __restrict__ row,
                                                   int* __restrict__ counts) {
  int i = blockIdx.x * blockDim.x + threadIdx.x;
  int stride = gridDim.x * blockDim.x;
  for (; i < N_EDGES; i += stride) atomicAdd(&counts[row[i]], 1);
}

__global__ __launch_bounds__(256) void partial_kernel(const int* __restrict__ counts,
                                                      int* __restrict__ bsum) {
  __shared__ int sd[256];
  int i = blockIdx.x * 256 + threadIdx.x;
  sd[threadIdx.x] = (i < N_NODES) ? counts[i] : 0;
  __syncthreads();
  for (int o = 128; o > 0; o >>= 1) {
    if (threadIdx.x < o) sd[threadIdx.x] += sd[threadIdx.x + o];
    __syncthreads();
  }
  if (threadIdx.x == 0) bsum[blockIdx.x] = sd[0];
}

__global__ __launch_bounds__(512) void scanp_kernel(const int* __restrict__ bsum,
                                                    int* __restrict__ bpre,
                                                    int* __restrict__ offs) {
  __shared__ int sd[512];
  int tid = threadIdx.x;
  int v = (tid < SCAN_NB) ? bsum[tid] : 0;
  sd[tid] = v;
  __syncthreads();
  for (int o = 1; o < 512; o <<= 1) {
    int add = (tid >= o) ? sd[tid - o] : 0;
    __syncthreads();
    sd[tid] += add;
    __syncthreads();
  }
  if (tid < SCAN_NB) bpre[tid] = sd[tid] - v;
  if (tid == SCAN_NB - 1) offs[N_NODES] = sd[tid];
}

__global__ __launch_bounds__(256) void apply_kernel(const int* __restrict__ counts,
                                                    const int* __restrict__ bpre,
                                                    int* __restrict__ offs) {
  __shared__ int sd[256];
  int tid = threadIdx.x;
  int i = blockIdx.x * 256 + tid;
  int v = (i < N_NODES) ? counts[i] : 0;
  sd[tid] = v;
  __syncthreads();
  for (int o = 1; o < 256; o <<= 1) {
    int add = (tid >= o) ? sd[tid - o] : 0;
    __syncthreads();
    sd[tid] += add;
    __syncthreads();
  }
  if (i < N_NODES) offs[i] = bpre[blockIdx.x] + sd[tid] - v;
}

__global__ __launch_bounds__(256) void initcur_kernel(const int* __restrict__ offs,
                                                      int* __restrict__ gcur1,
                                                      int* __restrict__ gcur2) {
  int t = blockIdx.x * 256 + threadIdx.x;
  if (t < NB1) gcur1[t] = offs[t << B1_SHIFT];
  if (t < NSUB) gcur2[t] = offs[t << SUB_SHIFT];
}

// ---------------- pass A: edges -> 49 L1 bucket regions (coalesced runs) ----------------

__global__ __launch_bounds__(256) void binA_kernel(const int* __restrict__ row,
                                                   const int* __restrict__ col,
                                                   const float* __restrict__ val,
                                                   int* __restrict__ gcur1,
                                                   ull* __restrict__ ebuf1) {
  __shared__ ull stage[CHUNK];
  __shared__ int hist[NB1], lofs[NB1 + 1], lcur[NB1], gbase[NB1];
  int tid = threadIdx.x;
  for (long base = (long)blockIdx.x * CHUNK; base < N_EDGES; base += (long)gridDim.x * CHUNK) {
    int cnt = (int)min((long)CHUNK, (long)N_EDGES - base);
    if (tid < NB1) hist[tid] = 0;
    __syncthreads();
    ull e[4]; int bk[4];
#pragma unroll
    for (int v = 0; v < 4; ++v) {
      int i = v * 256 + tid;
      bk[v] = -1;
      if (i < cnt) {
        long g = base + i;
        int r = row[g];
        e[v] = pack_edge(val[g], r, col[g]);
        bk[v] = r >> B1_SHIFT;
        atomicAdd(&hist[bk[v]], 1);
      }
    }
    __syncthreads();
    if (tid < 64) {
      int h = (tid < NB1) ? hist[tid] : 0;
      int x = h;
      for (int o = 1; o < 64; o <<= 1) {
        int y = __shfl_up(x, o);
        if (tid >= o) x += y;
      }
      if (tid < NB1) { lofs[tid] = x - h; lcur[tid] = x - h; }
      if (tid == 63) lofs[NB1] = x;  // == cnt
    }
    __syncthreads();
#pragma unroll
    for (int v = 0; v < 4; ++v) {
      if (bk[v] >= 0) {
        int pos = atomicAdd(&lcur[bk[v]], 1);
        stage[pos] = e[v];
      }
    }
    __syncthreads();
    if (tid < NB1) {
      int h = hist[tid];
      if (h > 0) gbase[tid] = atomicAdd(&gcur1[tid], h);
    }
    __syncthreads();
    for (int s = tid; s < cnt; s += 256) {
      int lo = 0, hi = NB1;
      while (hi - lo > 1) {
        int mid = (lo + hi) >> 1;
        if (lofs[mid] <= s) lo = mid; else hi = mid;
      }
      ebuf1[gbase[lo] + (s - lofs[lo])] = stage[s];
    }
    __syncthreads();
  }
}

// ---------------- pass B: L1 bucket -> 64 sub-bucket regions ----------------

__global__ __launch_bounds__(256) void binB_kernel(const ull* __restrict__ ebuf1,
                                                   const int* __restrict__ offs,
                                                   int* __restrict__ gcur2,
                                                   ull* __restrict__ edat) {
  __shared__ ull stage[CHUNK];
  __shared__ int hist[64], lofs[65], lcur[64], gbase[64];
  int tid = threadIdx.x;
  int b1 = blockIdx.x >> 3, w = blockIdx.x & 7;
  int rbeg = offs[b1 << B1_SHIFT];
  int rend = offs[min((b1 + 1) << B1_SHIFT, N_NODES)];
  for (int base = rbeg + w * CHUNK; base < rend; base += 8 * CHUNK) {
    int cnt = min(CHUNK, rend - base);
    if (tid < 64) hist[tid] = 0;
    __syncthreads();
    ull e[4]; int bk[4];
#pragma unroll
    for (int v = 0; v < 4; ++v) {
      int i = v * 256 + tid;
      bk[v] = -1;
      if (i < cnt) {
        e[v] = ebuf1[base + i];
        bk[v] = (edge_row(e[v]) >> SUB_SHIFT) - (b1 << 6);
        atomicAdd(&hist[bk[v]], 1);
      }
    }
    __syncthreads();
    if (tid < 64) {
      int h = hist[tid];
      int x = h;
      for (int o = 1; o < 64; o <<= 1) {
        int y = __shfl_up(x, o);
        if (tid >= o) x += y;
      }
      lofs[tid] = x - h;
      lcur[tid] = x - h;
      if (tid == 63) lofs[64] = x;  // == cnt
    }
    __syncthreads();
#pragma unroll
    for (int v = 0; v < 4; ++v) {
      if (bk[v] >= 0) {
        int pos = atomicAdd(&lcur[bk[v]], 1);
        stage[pos] = e[v];
      }
    }
    __syncthreads();
    if (tid < 64) {
      int h = hist[tid];
      if (h > 0) gbase[tid] = atomicAdd(&gcur2[(b1 << 6) + tid], h);
    }
    __syncthreads();
    for (int s = tid; s < cnt; s += 256) {
      int lo = 0, hi = 64;
      while (hi - lo > 1) {
        int mid = (lo + hi) >> 1;
        if (lofs[mid] <= s) lo = mid; else hi = mid;
      }
      edat[gbase[lo] + (s - lofs[lo])] = stage[s];
    }
    __syncthreads();
  }
}

// ---------------- pass C: exact row placement within each 32-row sub-bucket ----------------

__global__ __launch_bounds__(256) void binC_kernel(const int* __restrict__ offs,
                                                   ull* __restrict__ edat,
                                                   ull* __restrict__ ebuf1) {
  __shared__ int rcnt[32], rcur[32];
  int s = blockIdx.x, tid = threadIdx.x;
  int r0 = s << SUB_SHIFT;
  int beg = offs[r0], end = offs[min(r0 + 32, N_NODES)];
  int n = end - beg;
  if (tid < 32) rcnt[tid] = 0;
  __syncthreads();
  for (int i = tid; i < n; i += 256) {
    ull p = edat[beg + i];
    ebuf1[beg + i] = p;                    // scratch copy (region private to this WG)
    atomicAdd(&rcnt[edge_row(p) & 31], 1);
  }
  __syncthreads();
  if (tid < 32) {
    int h = rcnt[tid];
    int x = h;
    for (int o = 1; o < 32; o <<= 1) {
      int y = __shfl_up(x, o, 32);
      if (tid >= o) x += y;
    }
    rcur[tid] = x - h;
  }
  __syncthreads();
  for (int i = tid; i < n; i += 256) {
    ull p = ebuf1[beg + i];
    int pos = atomicAdd(&rcur[edge_row(p) & 31], 1);
    edat[beg + pos] = p;
  }
}

// ---------------- needed-row mask: cols of edges of the 8192 selected rows ----------------

__global__ __launch_bounds__(256) void mask_kernel(const int* __restrict__ offs,
                                                   const ull* __restrict__ edat,
                                                   const int* __restrict__ index,
                                                   int* __restrict__ flag) {
  int t = blockIdx.x * 256 + threadIdx.x;  // 8192 threads exactly
  int r = index[t];
  int s = offs[r], e = offs[r + 1];
  for (int j = s; j < e; ++j) flag[edge_col(edat[j])] = 1;
}

// ---------------- dense GEMM: C[nr,128] = A[nr,128] @ W[128,128] (+bias) ----------------

__device__ __forceinline__ void fma4(float4& acc, const float4& a,
                                     const float4& w0, const float4& w1,
                                     const float4& w2, const float4& w3) {
  acc.x = fmaf(a.x, w0.x, fmaf(a.y, w1.x, fmaf(a.z, w2.x, fmaf(a.w, w3.x, acc.x))));
  acc.y = fmaf(a.x, w0.y, fmaf(a.y, w1.y, fmaf(a.z, w2.y, fmaf(a.w, w3.y, acc.y))));
  acc.z = fmaf(a.x, w0.z, fmaf(a.y, w1.z, fmaf(a.z, w2.z, fmaf(a.w, w3.z, acc.z))));
  acc.w = fmaf(a.x, w0.w, fmaf(a.y, w1.w, fmaf(a.z, w2.w, fmaf(a.w, w3.w, acc.w))));
}

template <int OUT_BF16>
__global__ __launch_bounds__(256) void gemm128_kernel(const float* __restrict__ A,
                                                      const float* __restrict__ W,
                                                      const float* __restrict__ bias,
                                                      void* __restrict__ C,
                                                      int do_bias) {
  __shared__ float Ws[64 * 128];
  int tid = threadIdx.x;
  int c0 = (tid & 31) * 4;
  int rg = tid >> 5;
  long rbase = (long)blockIdx.x * 32 + rg * 4;
  const float* A0 = A + rbase * 128;
  float4* Ws4 = (float4*)Ws;

  float4 acc0 = {0, 0, 0, 0}, acc1 = {0, 0, 0, 0}, acc2 = {0, 0, 0, 0}, acc3 = {0, 0, 0, 0};

  for (int half = 0; half < 2; ++half) {
    const float4* Wsrc = (const float4*)(W + half * 64 * 128);
#pragma unroll
    for (int i = 0; i < 8; ++i) Ws4[tid + i * 256] = Wsrc[tid + i * 256];
    __syncthreads();
    const float* Ah = A0 + half * 64;
#pragma unroll 4
    for (int k = 0; k < 64; k += 4) {
      float4 w0 = *(const float4*)&Ws[(k + 0) * 128 + c0];
      float4 w1 = *(const float4*)&Ws[(k + 1) * 128 + c0];
      float4 w2 = *(const float4*)&Ws[(k + 2) * 128 + c0];
      float4 w3 = *(const float4*)&Ws[(k + 3) * 128 + c0];
      float4 a0 = *(const float4*)(Ah + 0 * 128 + k);
      float4 a1 = *(const float4*)(Ah + 1 * 128 + k);
      float4 a2 = *(const float4*)(Ah + 2 * 128 + k);
      float4 a3 = *(const float4*)(Ah + 3 * 128 + k);
      fma4(acc0, a0, w0, w1, w2, w3);
      fma4(acc1, a1, w0, w1, w2, w3);
      fma4(acc2, a2, w0, w1, w2, w3);
      fma4(acc3, a3, w0, w1, w2, w3);
    }
    __syncthreads();
  }

  float4 bv = {0, 0, 0, 0};
  if (do_bias) bv = *(const float4*)&bias[c0];
  acc0.x += bv.x; acc0.y += bv.y; acc0.z += bv.z; acc0.w += bv.w;
  acc1.x += bv.x; acc1.y += bv.y; acc1.z += bv.z; acc1.w += bv.w;
  acc2.x += bv.x; acc2.y += bv.y; acc2.z += bv.z; acc2.w += bv.w;
  acc3.x += bv.x; acc3.y += bv.y; acc3.z += bv.z; acc3.w += bv.w;

  if (OUT_BF16) {
    unsigned short* Cp = (unsigned short*)C + rbase * 128 + c0;
    ushort4 o0 = {f2bf(acc0.x), f2bf(acc0.y), f2bf(acc0.z), f2bf(acc0.w)};
    ushort4 o1 = {f2bf(acc1.x), f2bf(acc1.y), f2bf(acc1.z), f2bf(acc1.w)};
    ushort4 o2 = {f2bf(acc2.x), f2bf(acc2.y), f2bf(acc2.z), f2bf(acc2.w)};
    ushort4 o3 = {f2bf(acc3.x), f2bf(acc3.y), f2bf(acc3.z), f2bf(acc3.w)};
    *(ushort4*)(Cp + 0 * 128) = o0;
    *(ushort4*)(Cp + 1 * 128) = o1;
    *(ushort4*)(Cp + 2 * 128) = o2;
    *(ushort4*)(Cp + 3 * 128) = o3;
  } else {
    float* Cp = (float*)C + rbase * 128 + c0;
    *(float4*)(Cp + 0 * 128) = acc0;
    *(float4*)(Cp + 1 * 128) = acc1;
    *(float4*)(Cp + 2 * 128) = acc2;
    *(float4*)(Cp + 3 * 128) = acc3;
  }
}

// ---------------- CSR spmm: 4 waves/block, 1 row/wave, 4 edge-groups x 16 lanes x 8 feats ----

__global__ __launch_bounds__(256) void spmm_row_kernel(const int* __restrict__ offs,
                                                       const ull* __restrict__ edat,
                                                       const unsigned short* __restrict__ a,
                                                       const float* __restrict__ bias,
                                                       unsigned short* __restrict__ h,
                                                       const int* __restrict__ flag) {
  int wave = threadIdx.x >> 6;
  int lane = threadIdx.x & 63;
  int r = blockIdx.x * 4 + wave;           // grid = 25000, exact
  if (!flag[r]) return;                    // h1 row never read downstream
  int g = lane >> 4, l = lane & 15;
  int s = offs[r], e = offs[r + 1];
  float acc[8] = {0.f, 0.f, 0.f, 0.f, 0.f, 0.f, 0.f, 0.f};
  for (int j = s + g; j < e; j += 4) {
    ull p = edat[j];
    float v = edge_val(p);
    uint4 u = *(const uint4*)(a + (long)edge_col(p) * 128 + l * 8);
    acc[0] = fmaf(v, bflo(u.x), acc[0]);
    acc[1] = fmaf(v, bfhi(u.x), acc[1]);
    acc[2] = fmaf(v, bflo(u.y), acc[2]);
    acc[3] = fmaf(v, bfhi(u.y), acc[3]);
    acc[4] = fmaf(v, bflo(u.z), acc[4]);
    acc[5] = fmaf(v, bfhi(u.z), acc[5]);
    acc[6] = fmaf(v, bflo(u.w), acc[6]);
    acc[7] = fmaf(v, bfhi(u.w), acc[7]);
  }
#pragma unroll
  for (int k = 0; k < 8; ++k) {
    acc[k] += __shfl_xor(acc[k], 16);
    acc[k] += __shfl_xor(acc[k], 32);
  }
  if (g == 0) {
    float4 b0 = *(const float4*)(bias + l * 8);
    float4 b1 = *(const float4*)(bias + l * 8 + 4);
    uint4 o;
    o.x = packbf2(fmaxf(acc[0] + b0.x, 0.f), fmaxf(acc[1] + b0.y, 0.f));
    o.y = packbf2(fmaxf(acc[2] + b0.z, 0.f), fmaxf(acc[3] + b0.w, 0.f));
    o.z = packbf2(fmaxf(acc[4] + b1.x, 0.f), fmaxf(acc[5] + b1.y, 0.f));
    o.w = packbf2(fmaxf(acc[6] + b1.z, 0.f), fmaxf(acc[7] + b1.w, 0.f));
    *(uint4*)(h + (long)r * 128 + l * 8) = o;
  }
}

__global__ __launch_bounds__(256) void spmm_sel_kernel(const int* __restrict__ offs,
                                                       const ull* __restrict__ edat,
                                                       const unsigned short* __restrict__ h1,
                                                       const int* __restrict__ index,
                                                       float* __restrict__ g2) {
  int wave = threadIdx.x >> 6;
  int lane = threadIdx.x & 63;
  int b = blockIdx.x * 4 + wave;           // grid = 2048, exact
  int g = lane >> 4, l = lane & 15;
  int r = index[b];
  int s = offs[r], e = offs[r + 1];
  float acc[8] = {0.f, 0.f, 0.f, 0.f, 0.f, 0.f, 0.f, 0.f};
  for (int j = s + g; j < e; j += 4) {
    ull p = edat[j];
    float v = edge_val(p);
    uint4 u = *(const uint4*)(h1 + (long)edge_col(p) * 128 + l * 8);
    acc[0] = fmaf(v, bflo(u.x), acc[0]);
    acc[1] = fmaf(v, bfhi(u.x), acc[1]);
    acc[2] = fmaf(v, bflo(u.y), acc[2]);
    acc[3] = fmaf(v, bfhi(u.y), acc[3]);
    acc[4] = fmaf(v, bflo(u.z), acc[4]);
    acc[5] = fmaf(v, bfhi(u.z), acc[5]);
    acc[6] = fmaf(v, bflo(u.w), acc[6]);
    acc[7] = fmaf(v, bfhi(u.w), acc[7]);
  }
#pragma unroll
  for (int k = 0; k < 8; ++k) {
    acc[k] += __shfl_xor(acc[k], 16);
    acc[k] += __shfl_xor(acc[k], 32);
  }
  if (g == 0) {
    float* op = g2 + (long)b * 128 + l * 8;
    *(float4*)(op + 0) = make_float4(acc[0], acc[1], acc[2], acc[3]);
    *(float4*)(op + 4) = make_float4(acc[4], acc[5], acc[6], acc[7]);
  }
}

// ---------------- final: z = concat(t, s) @ Wl + bl; log_softmax ----------------

__global__ __launch_bounds__(128) void final_kernel(const float* __restrict__ t,
                                                    const float* __restrict__ s,
                                                    const float* __restrict__ Wl,
                                                    const float* __restrict__ bl,
                                                    float* __restrict__ out) {
  int b = blockIdx.x * 128 + threadIdx.x;
  float z[16];
#pragma unroll
  for (int c = 0; c < 16; ++c) z[c] = bl[c];
  const float4* tb = (const float4*)(t + (long)b * 128);
#pragma unroll 4
  for (int k4 = 0; k4 < 32; ++k4) {
    float4 tv = tb[k4];
    const float* w = Wl + (k4 * 4) * 16;
#pragma unroll
    for (int c = 0; c < 16; ++c)
      z[c] += tv.x * w[c] + tv.y * w[16 + c] + tv.z * w[32 + c] + tv.w * w[48 + c];
  }
  const float4* sb = (const float4*)(s + (long)b * 64);
#pragma unroll 4
  for (int k4 = 0; k4 < 16; ++k4) {
    float4 sv = sb[k4];
    const float* w = Wl + (128 + k4 * 4) * 16;
#pragma unroll
    for (int c = 0; c < 16; ++c)
      z[c] += sv.x * w[c] + sv.y * w[16 + c] + sv.z * w[32 + c] + sv.w * w[48 + c];
  }
  float m = z[0];
#pragma unroll
  for (int c = 1; c < 16; ++c) m = fmaxf(m, z[c]);
  float sum = 0.f;
#pragma unroll
  for (int c = 0; c < 16; ++c) sum += expf(z[c] - m);
  float lse = m + logf(sum);
  float* ob = out + (long)b * 16;
#pragma unroll
  for (int c = 0; c < 16; ++c) ob[c] = z[c] - lse;
}

// ---------------- launch ----------------

extern "C" void kernel_launch(void* const* d_in, const int* in_sizes, int n_in,
                              void* d_out, int out_size, void* d_ws, size_t ws_size,
                              hipStream_t stream) {
  const float* s_in  = (const float*)d_in[0];
  const float* x     = (const float*)d_in[1];
  const int*   row   = (const int*)d_in[2];
  const int*   col   = (const int*)d_in[3];
  const float* val   = (const float*)d_in[4];
  const int*   index = (const int*)d_in[5];
  const float* W1    = (const float*)d_in[6];
  const float* b1    = (const float*)d_in[7];
  const float* W2    = (const float*)d_in[8];
  const float* b2    = (const float*)d_in[9];
  const float* Wl    = (const float*)d_in[10];
  const float* bl    = (const float*)d_in[11];
  float* out = (float*)d_out;

  // workspace carve (~87 MB), 8B-aligned first
  ull* edat  = (ull*)d_ws;                                           // [1.6M] final CSR edges
  ull* ebuf1 = edat + N_EDGES;                                       // [1.6M] L1-bucketed temp
  unsigned short* a  = (unsigned short*)(ebuf1 + N_EDGES);           // xW1 bf16   [100000,128]
  unsigned short* h1 = a + (size_t)N_NODES * 128;                    // layer1 bf16[100000,128]
  float* g2   = (float*)(h1 + (size_t)N_NODES * 128);                // sel spmm   [8192,128]
  float* tmat = g2 + (size_t)BB * 128;                               // g2@W2+b2   [8192,128]
  int* counts = (int*)(tmat + (size_t)BB * 128);                     // [100000]
  int* flag   = counts + N_NODES;                                    // [100000] needed-row mask
  int* offs   = flag + N_NODES;                                      // [100001]
  int* bsum   = offs + (N_NODES + 1);                                // [391]
  int* bpre   = bsum + SCAN_NB;                                      // [391]
  int* gcur1  = bpre + SCAN_NB;                                      // [49]
  int* gcur2  = gcur1 + NB1;                                         // [3125]

  hipMemsetAsync(counts, 0, 2 * N_NODES * sizeof(int), stream);  // counts + flag
  hist_kernel<<<4096, 256, 0, stream>>>(row, counts);
  partial_kernel<<<SCAN_NB, 256, 0, stream>>>(counts, bsum);
  scanp_kernel<<<1, 512, 0, stream>>>(bsum, bpre, offs);
  apply_kernel<<<SCAN_NB, 256, 0, stream>>>(counts, bpre, offs);
  initcur_kernel<<<(NSUB + 255) / 256, 256, 0, stream>>>(offs, gcur1, gcur2);

  binA_kernel<<<512, 256, 0, stream>>>(row, col, val, gcur1, ebuf1);
  binB_kernel<<<NB1 * 8, 256, 0, stream>>>(ebuf1, offs, gcur2, edat);
  binC_kernel<<<NSUB, 256, 0, stream>>>(offs, edat, ebuf1);
  mask_kernel<<<BB / 256, 256, 0, stream>>>(offs, edat, index, flag);

  gemm128_kernel<1><<<N_NODES / 32, 256, 0, stream>>>(x, W1, nullptr, a, 0);
  spmm_row_kernel<<<N_NODES / 4, 256, 0, stream>>>(offs, edat, a, b1, h1, flag);
  spmm_sel_kernel<<<BB / 4, 256, 0, stream>>>(offs, edat, h1, index, g2);
  gemm128_kernel<0><<<BB / 32, 256, 0, stream>>>(g2, W2, b2, tmat, 1);
  final_kernel<<<BB / 128, 128, 0, stream>>>(tmat, s_in, Wl, bl, out);
}

// Round 7
// 387.095 us; speedup vs baseline: 1.3400x; 1.1134x over previous
//
#include <hip/hip_runtime.h>
#include <math.h>

#define N_NODES 100000
#define N_EDGES 1600000
#define NFEAT 128
#define NHID 128
#define NS 64
#define NCLASS 16
#define BB 8192

#define SCAN_NB 391   // ceil(N_NODES / 256)

// binned CSR build geometry
#define B1_SHIFT 11               // 2048 rows per L1 bucket
#define NB1 49                    // ceil(100000 / 2048)
#define SUB_SHIFT 5               // 32 rows per sub-bucket
#define NSUB 3125                 // 100000 / 32
#define CHUNK 1024                // edges per block-iteration in bin passes

typedef unsigned long long ull;
typedef unsigned int uint;

// ---------------- bf16 helpers ----------------

__device__ __forceinline__ unsigned short f2bf(float f) {
  unsigned int u = __float_as_uint(f);
  return (unsigned short)((u + 0x7fffu + ((u >> 16) & 1u)) >> 16);  // RNE
}
__device__ __forceinline__ float bflo(unsigned int u) {  // low bf16 of packed uint
  return __uint_as_float(u << 16);
}
__device__ __forceinline__ float bfhi(unsigned int u) {  // high bf16 of packed uint
  return __uint_as_float(u & 0xffff0000u);
}
__device__ __forceinline__ unsigned int packbf2(float lo, float hi) {
  return (unsigned int)f2bf(lo) | ((unsigned int)f2bf(hi) << 16);
}

// ---------------- edge packing: [63:34]=val[31:2], [33:17]=row, [16:0]=col ----------------

__device__ __forceinline__ ull pack_edge(float v, int r, int c) {
  return ((ull)(__float_as_uint(v) >> 2) << 34) | ((ull)(unsigned)r << 17) | (unsigned)c;
}
__device__ __forceinline__ int edge_col(ull p) { return (int)(p & 0x1FFFFu); }
__device__ __forceinline__ int edge_row(ull p) { return (int)((unsigned)(p >> 17) & 0x1FFFFu); }
__device__ __forceinline__ float edge_val(ull p) {
  return __uint_as_float(((unsigned)(p >> 34)) << 2);
}

// ---------------- row histogram + offs scan ----------------

__global__ __launch_bounds__(256) void hist_kernel(const int* __restrict__ row,
                                                   int* __restrict__ counts) {
  int i = blockIdx.x * blockDim.x + threadIdx.x;
  int stride = gridDim.x * blockDim.x;
  for (; i < N_EDGES; i += stride) atomicAdd(&counts[row[i]], 1);
}

__global__ __launch_bounds__(256) void partial_kernel(const int* __restrict__ counts,
                                                      int* __restrict__ bsum) {
  __shared__ int sd[256];
  int i = blockIdx.x * 256 + threadIdx.x;
  sd[threadIdx.x] = (i < N_NODES) ? counts[i] : 0;
  __syncthreads();
  for (int o = 128; o > 0; o >>= 1) {
    if (threadIdx.x < o) sd[threadIdx.x] += sd[threadIdx.x + o];
    __syncthreads();
  }
  if (threadIdx.x == 0) bsum[blockIdx.x] = sd[0];
}

__global__ __launch_bounds__(512) void scanp_kernel(const int* __restrict__ bsum,
                                                    int* __restrict__ bpre,
                                                    int* __restrict__ offs) {
  __shared__ int sd[512];
  int tid = threadIdx.x;
  int v = (tid < SCAN_NB) ? bsum[tid] : 0;
  sd[tid] = v;
  __syncthreads();
  for (int o = 1; o < 512; o <<= 1) {
    int add = (tid >= o) ? sd[tid - o] : 0;
    __syncthreads();
    sd[tid] += add;
    __syncthreads();
  }
  if (tid < SCAN_NB) bpre[tid] = sd[tid] - v;
  if (tid == SCAN_NB - 1) offs[N_NODES] = sd[tid];
}

__global__ __launch_bounds__(256) void apply_kernel(const int* __restrict__ counts,
                                                    const int* __restrict__ bpre,
                                                    int* __restrict__ offs) {
  __shared__ int sd[256];
  int tid = threadIdx.x;
  int i = blockIdx.x * 256 + tid;
  int v = (i < N_NODES) ? counts[i] : 0;
  sd[tid] = v;
  __syncthreads();
  for (int o = 1; o < 256; o <<= 1) {
    int add = (tid >= o) ? sd[tid - o] : 0;
    __syncthreads();
    sd[tid] += add;
    __syncthreads();
  }
  if (i < N_NODES) offs[i] = bpre[blockIdx.x] + sd[tid] - v;
}

__global__ __launch_bounds__(256) void initcur_kernel(const int* __restrict__ offs,
                                                      int* __restrict__ gcur1,
                                                      int* __restrict__ gcur2) {
  int t = blockIdx.x * 256 + threadIdx.x;
  if (t < NB1) gcur1[t] = offs[t << B1_SHIFT];
  if (t < NSUB) gcur2[t] = offs[t << SUB_SHIFT];
}

// ---------------- pass A: edges -> 49 L1 bucket regions (coalesced runs) ----------------

__global__ __launch_bounds__(256) void binA_kernel(const int* __restrict__ row,
                                                   const int* __restrict__ col,
                                                   const float* __restrict__ val,
                                                   int* __restrict__ gcur1,
                                                   ull* __restrict__ ebuf1) {
  __shared__ ull stage[CHUNK];
  __shared__ int hist[NB1], lofs[NB1 + 1], lcur[NB1], gbase[NB1];
  int tid = threadIdx.x;
  for (long base = (long)blockIdx.x * CHUNK; base < N_EDGES; base += (long)gridDim.x * CHUNK) {
    int cnt = (int)min((long)CHUNK, (long)N_EDGES - base);
    if (tid < NB1) hist[tid] = 0;
    __syncthreads();
    ull e[4]; int bk[4];
#pragma unroll
    for (int v = 0; v < 4; ++v) {
      int i = v * 256 + tid;
      bk[v] = -1;
      if (i < cnt) {
        long g = base + i;
        int r = row[g];
        e[v] = pack_edge(val[g], r, col[g]);
        bk[v] = r >> B1_SHIFT;
        atomicAdd(&hist[bk[v]], 1);
      }
    }
    __syncthreads();
    if (tid < 64) {
      int h = (tid < NB1) ? hist[tid] : 0;
      int x = h;
      for (int o = 1; o < 64; o <<= 1) {
        int y = __shfl_up(x, o);
        if (tid >= o) x += y;
      }
      if (tid < NB1) { lofs[tid] = x - h; lcur[tid] = x - h; }
      if (tid == 63) lofs[NB1] = x;  // == cnt
    }
    __syncthreads();
#pragma unroll
    for (int v = 0; v < 4; ++v) {
      if (bk[v] >= 0) {
        int pos = atomicAdd(&lcur[bk[v]], 1);
        stage[pos] = e[v];
      }
    }
    __syncthreads();
    if (tid < NB1) {
      int h = hist[tid];
      if (h > 0) gbase[tid] = atomicAdd(&gcur1[tid], h);
    }
    __syncthreads();
    for (int s = tid; s < cnt; s += 256) {
      int lo = 0, hi = NB1;
      while (hi - lo > 1) {
        int mid = (lo + hi) >> 1;
        if (lofs[mid] <= s) lo = mid; else hi = mid;
      }
      ebuf1[gbase[lo] + (s - lofs[lo])] = stage[s];
    }
    __syncthreads();
  }
}

// ---------------- pass B: L1 bucket -> 64 sub-bucket regions ----------------

__global__ __launch_bounds__(256) void binB_kernel(const ull* __restrict__ ebuf1,
                                                   const int* __restrict__ offs,
                                                   int* __restrict__ gcur2,
                                                   ull* __restrict__ edat) {
  __shared__ ull stage[CHUNK];
  __shared__ int hist[64], lofs[65], lcur[64], gbase[64];
  int tid = threadIdx.x;
  int b1 = blockIdx.x >> 3, w = blockIdx.x & 7;
  int rbeg = offs[b1 << B1_SHIFT];
  int rend = offs[min((b1 + 1) << B1_SHIFT, N_NODES)];
  for (int base = rbeg + w * CHUNK; base < rend; base += 8 * CHUNK) {
    int cnt = min(CHUNK, rend - base);
    if (tid < 64) hist[tid] = 0;
    __syncthreads();
    ull e[4]; int bk[4];
#pragma unroll
    for (int v = 0; v < 4; ++v) {
      int i = v * 256 + tid;
      bk[v] = -1;
      if (i < cnt) {
        e[v] = ebuf1[base + i];
        bk[v] = (edge_row(e[v]) >> SUB_SHIFT) - (b1 << 6);
        atomicAdd(&hist[bk[v]], 1);
      }
    }
    __syncthreads();
    if (tid < 64) {
      int h = hist[tid];
      int x = h;
      for (int o = 1; o < 64; o <<= 1) {
        int y = __shfl_up(x, o);
        if (tid >= o) x += y;
      }
      lofs[tid] = x - h;
      lcur[tid] = x - h;
      if (tid == 63) lofs[64] = x;  // == cnt
    }
    __syncthreads();
#pragma unroll
    for (int v = 0; v < 4; ++v) {
      if (bk[v] >= 0) {
        int pos = atomicAdd(&lcur[bk[v]], 1);
        stage[pos] = e[v];
      }
    }
    __syncthreads();
    if (tid < 64) {
      int h = hist[tid];
      if (h > 0) gbase[tid] = atomicAdd(&gcur2[(b1 << 6) + tid], h);
    }
    __syncthreads();
    for (int s = tid; s < cnt; s += 256) {
      int lo = 0, hi = 64;
      while (hi - lo > 1) {
        int mid = (lo + hi) >> 1;
        if (lofs[mid] <= s) lo = mid; else hi = mid;
      }
      edat[gbase[lo] + (s - lofs[lo])] = stage[s];
    }
    __syncthreads();
  }
}

// ---------------- pass C: exact row placement within each 32-row sub-bucket ----------------

__global__ __launch_bounds__(256) void binC_kernel(const int* __restrict__ offs,
                                                   ull* __restrict__ edat,
                                                   ull* __restrict__ ebuf1) {
  __shared__ int rcnt[32], rcur[32];
  int s = blockIdx.x, tid = threadIdx.x;
  int r0 = s << SUB_SHIFT;
  int beg = offs[r0], end = offs[min(r0 + 32, N_NODES)];
  int n = end - beg;
  if (tid < 32) rcnt[tid] = 0;
  __syncthreads();
  for (int i = tid; i < n; i += 256) {
    ull p = edat[beg + i];
    ebuf1[beg + i] = p;                    // scratch copy (region private to this WG)
    atomicAdd(&rcnt[edge_row(p) & 31], 1);
  }
  __syncthreads();
  if (tid < 32) {
    int h = rcnt[tid];
    int x = h;
    for (int o = 1; o < 32; o <<= 1) {
      int y = __shfl_up(x, o, 32);
      if (tid >= o) x += y;
    }
    rcur[tid] = x - h;
  }
  __syncthreads();
  for (int i = tid; i < n; i += 256) {
    ull p = ebuf1[beg + i];
    int pos = atomicAdd(&rcur[edge_row(p) & 31], 1);
    edat[beg + pos] = p;
  }
}

// ---------------- needed-row mask: cols of edges of the 8192 selected rows ----------------

__global__ __launch_bounds__(256) void mask_kernel(const int* __restrict__ offs,
                                                   const ull* __restrict__ edat,
                                                   const int* __restrict__ index,
                                                   int* __restrict__ flag) {
  int t = blockIdx.x * 256 + threadIdx.x;  // 8192 threads exactly
  int r = index[t];
  int s = offs[r], e = offs[r + 1];
  for (int j = s; j < e; ++j) flag[edge_col(edat[j])] = 1;
}

// ---------------- weight convert: W fp32 [k][n] -> Wt bf16-packed uint [n][k/2] ----------

__global__ __launch_bounds__(256) void wconv_kernel(const float* __restrict__ W,
                                                    uint* __restrict__ Wt) {
  int idx = blockIdx.x * 256 + threadIdx.x;   // 8192 exactly (grid 32)
  int n = idx >> 6, kc = idx & 63;
  float lo = W[(2 * kc) * 128 + n];
  float hi = W[(2 * kc + 1) * 128 + n];
  Wt[idx] = packbf2(lo, hi);
}

// ---------------- MFMA GEMM: C[nr,128] = A[nr,128] @ W[128,128] (+bias) ----------------
// block = 256 threads (4 waves), tile M=64 x N=128, K=128 entirely in LDS.
// A staged fp32->bf16; Wt pre-converted bf16 [n][k]. LDS row stride 68 uints
// (16B-aligned, bank offset 4 -> 2-way conflict = free). Per wave: 4 row-tiles
// x 2 col-tiles of mfma_f32_16x16x32_bf16 over 4 K-steps.
// A frag: A[m=lane&15][k=quad*8+j]; B frag: B[n=lane&15][k=quad*8+j] (W^T layout);
// C/D layout (m89/m91-verified): col = lane&15, row = (lane>>4)*4 + reg.

typedef __attribute__((ext_vector_type(8))) __bf16 bf16x8;
typedef __attribute__((ext_vector_type(4))) float f32x4;
union FragU { uint4 u; bf16x8 b; };

#define LDSTR 68   // uints per 128-feat row in LDS

template <int OUT_BF16>
__global__ __launch_bounds__(256) void mfma_gemm_kernel(const float* __restrict__ A,
                                                        const uint* __restrict__ Wt_g,
                                                        const float* __restrict__ bias,
                                                        void* __restrict__ C,
                                                        int nrows) {
  __shared__ uint As_s[64 * LDSTR];    // 17.4 KB
  __shared__ uint Wt_s[128 * LDSTR];   // 34.8 KB
  int tid = threadIdx.x;
  int rbase = blockIdx.x * 64;

  // stage Wt: 8192 uints, uint2 per iteration
  {
    const uint2* src = (const uint2*)Wt_g;
#pragma unroll
    for (int i = 0; i < 16; ++i) {
      int j = i * 256 + tid;               // uint2 index, 0..4095
      int n = j >> 5, c2 = (j & 31) * 2;
      uint2 v = src[j];
      Wt_s[n * LDSTR + c2] = v.x;
      Wt_s[n * LDSTR + c2 + 1] = v.y;
    }
  }
  // stage A tile: 64 rows x 128 fp32 -> bf16 packed (one float4 -> 2 uints)
  {
    const float4* src = (const float4*)(A + (long)rbase * 128);
#pragma unroll
    for (int i = 0; i < 8; ++i) {
      int f = i * 256 + tid;               // float4 index, 0..2047
      int m = f >> 5;
      float4 v = (rbase + m < nrows) ? src[f] : make_float4(0.f, 0.f, 0.f, 0.f);
      int c = (f & 31) * 2;                // uint col (0..62 step 2)
      As_s[m * LDSTR + c]     = packbf2(v.x, v.y);
      As_s[m * LDSTR + c + 1] = packbf2(v.z, v.w);
    }
  }
  __syncthreads();

  int w = tid >> 6, lane = tid & 63;
  int quad = lane >> 4, lr = lane & 15;
  int n0 = w * 32;

  f32x4 acc[4][2];
#pragma unroll
  for (int mt = 0; mt < 4; ++mt)
#pragma unroll
    for (int nt = 0; nt < 2; ++nt) acc[mt][nt] = (f32x4){0.f, 0.f, 0.f, 0.f};

#pragma unroll
  for (int kk = 0; kk < 4; ++kk) {
    int kc = kk * 16 + quad * 4;
    FragU fb0, fb1;
    fb0.u = *(const uint4*)&Wt_s[(n0 + lr) * LDSTR + kc];
    fb1.u = *(const uint4*)&Wt_s[(n0 + 16 + lr) * LDSTR + kc];
#pragma unroll
    for (int mt = 0; mt < 4; ++mt) {
      FragU fa;
      fa.u = *(const uint4*)&As_s[(mt * 16 + lr) * LDSTR + kc];
      acc[mt][0] = __builtin_amdgcn_mfma_f32_16x16x32_bf16(fa.b, fb0.b, acc[mt][0], 0, 0, 0);
      acc[mt][1] = __builtin_amdgcn_mfma_f32_16x16x32_bf16(fa.b, fb1.b, acc[mt][1], 0, 0, 0);
    }
  }

#pragma unroll
  for (int mt = 0; mt < 4; ++mt) {
#pragma unroll
    for (int nt = 0; nt < 2; ++nt) {
      int col = n0 + nt * 16 + lr;
      float bv = OUT_BF16 ? 0.f : bias[col];
#pragma unroll
      for (int r = 0; r < 4; ++r) {
        int row = rbase + mt * 16 + quad * 4 + r;
        if (row < nrows) {
          if (OUT_BF16)
            ((unsigned short*)C)[(long)row * 128 + col] = f2bf(acc[mt][nt][r]);
          else
            ((float*)C)[(long)row * 128 + col] = acc[mt][nt][r] + bv;
        }
      }
    }
  }
}

// ---------------- CSR spmm: 4 waves/block, 1 row/wave, 4 edge-groups x 16 lanes x 8 feats ----

__global__ __launch_bounds__(256) void spmm_row_kernel(const int* __restrict__ offs,
                                                       const ull* __restrict__ edat,
                                                       const unsigned short* __restrict__ a,
                                                       const float* __restrict__ bias,
                                                       unsigned short* __restrict__ h,
                                                       const int* __restrict__ flag) {
  int wave = threadIdx.x >> 6;
  int lane = threadIdx.x & 63;
  int r = blockIdx.x * 4 + wave;           // grid = 25000, exact
  if (!flag[r]) return;                    // h1 row never read downstream
  int g = lane >> 4, l = lane & 15;
  int s = offs[r], e = offs[r + 1];
  float acc[8] = {0.f, 0.f, 0.f, 0.f, 0.f, 0.f, 0.f, 0.f};
  for (int j = s + g; j < e; j += 4) {
    ull p = edat[j];
    float v = edge_val(p);
    uint4 u = *(const uint4*)(a + (long)edge_col(p) * 128 + l * 8);
    acc[0] = fmaf(v, bflo(u.x), acc[0]);
    acc[1] = fmaf(v, bfhi(u.x), acc[1]);
    acc[2] = fmaf(v, bflo(u.y), acc[2]);
    acc[3] = fmaf(v, bfhi(u.y), acc[3]);
    acc[4] = fmaf(v, bflo(u.z), acc[4]);
    acc[5] = fmaf(v, bfhi(u.z), acc[5]);
    acc[6] = fmaf(v, bflo(u.w), acc[6]);
    acc[7] = fmaf(v, bfhi(u.w), acc[7]);
  }
#pragma unroll
  for (int k = 0; k < 8; ++k) {
    acc[k] += __shfl_xor(acc[k], 16);
    acc[k] += __shfl_xor(acc[k], 32);
  }
  if (g == 0) {
    float4 b0 = *(const float4*)(bias + l * 8);
    float4 b1 = *(const float4*)(bias + l * 8 + 4);
    uint4 o;
    o.x = packbf2(fmaxf(acc[0] + b0.x, 0.f), fmaxf(acc[1] + b0.y, 0.f));
    o.y = packbf2(fmaxf(acc[2] + b0.z, 0.f), fmaxf(acc[3] + b0.w, 0.f));
    o.z = packbf2(fmaxf(acc[4] + b1.x, 0.f), fmaxf(acc[5] + b1.y, 0.f));
    o.w = packbf2(fmaxf(acc[6] + b1.z, 0.f), fmaxf(acc[7] + b1.w, 0.f));
    *(uint4*)(h + (long)r * 128 + l * 8) = o;
  }
}

__global__ __launch_bounds__(256) void spmm_sel_kernel(const int* __restrict__ offs,
                                                       const ull* __restrict__ edat,
                                                       const unsigned short* __restrict__ h1,
                                                       const int* __restrict__ index,
                                                       float* __restrict__ g2) {
  int wave = threadIdx.x >> 6;
  int lane = threadIdx.x & 63;
  int b = blockIdx.x * 4 + wave;           // grid = 2048, exact
  int g = lane >> 4, l = lane & 15;
  int r = index[b];
  int s = offs[r], e = offs[r + 1];
  float acc[8] = {0.f, 0.f, 0.f, 0.f, 0.f, 0.f, 0.f, 0.f};
  for (int j = s + g; j < e; j += 4) {
    ull p = edat[j];
    float v = edge_val(p);
    uint4 u = *(const uint4*)(h1 + (long)edge_col(p) * 128 + l * 8);
    acc[0] = fmaf(v, bflo(u.x), acc[0]);
    acc[1] = fmaf(v, bfhi(u.x), acc[1]);
    acc[2] = fmaf(v, bflo(u.y), acc[2]);
    acc[3] = fmaf(v, bfhi(u.y), acc[3]);
    acc[4] = fmaf(v, bflo(u.z), acc[4]);
    acc[5] = fmaf(v, bfhi(u.z), acc[5]);
    acc[6] = fmaf(v, bflo(u.w), acc[6]);
    acc[7] = fmaf(v, bfhi(u.w), acc[7]);
  }
#pragma unroll
  for (int k = 0; k < 8; ++k) {
    acc[k] += __shfl_xor(acc[k], 16);
    acc[k] += __shfl_xor(acc[k], 32);
  }
  if (g == 0) {
    float* op = g2 + (long)b * 128 + l * 8;
    *(float4*)(op + 0) = make_float4(acc[0], acc[1], acc[2], acc[3]);
    *(float4*)(op + 4) = make_float4(acc[4], acc[5], acc[6], acc[7]);
  }
}

// ---------------- final: z = concat(t, s) @ Wl + bl; log_softmax ----------------

__global__ __launch_bounds__(128) void final_kernel(const float* __restrict__ t,
                                                    const float* __restrict__ s,
                                                    const float* __restrict__ Wl,
                                                    const float* __restrict__ bl,
                                                    float* __restrict__ out) {
  int b = blockIdx.x * 128 + threadIdx.x;
  float z[16];
#pragma unroll
  for (int c = 0; c < 16; ++c) z[c] = bl[c];
  const float4* tb = (const float4*)(t + (long)b * 128);
#pragma unroll 4
  for (int k4 = 0; k4 < 32; ++k4) {
    float4 tv = tb[k4];
    const float* w = Wl + (k4 * 4) * 16;
#pragma unroll
    for (int c = 0; c < 16; ++c)
      z[c] += tv.x * w[c] + tv.y * w[16 + c] + tv.z * w[32 + c] + tv.w * w[48 + c];
  }
  const float4* sb = (const float4*)(s + (long)b * 64);
#pragma unroll 4
  for (int k4 = 0; k4 < 16; ++k4) {
    float4 sv = sb[k4];
    const float* w = Wl + (128 + k4 * 4) * 16;
#pragma unroll
    for (int c = 0; c < 16; ++c)
      z[c] += sv.x * w[c] + sv.y * w[16 + c] + sv.z * w[32 + c] + sv.w * w[48 + c];
  }
  float m = z[0];
#pragma unroll
  for (int c = 1; c < 16; ++c) m = fmaxf(m, z[c]);
  float sum = 0.f;
#pragma unroll
  for (int c = 0; c < 16; ++c) sum += expf(z[c] - m);
  float lse = m + logf(sum);
  float* ob = out + (long)b * 16;
#pragma unroll
  for (int c = 0; c < 16; ++c) ob[c] = z[c] - lse;
}

// ---------------- launch ----------------

extern "C" void kernel_launch(void* const* d_in, const int* in_sizes, int n_in,
                              void* d_out, int out_size, void* d_ws, size_t ws_size,
                              hipStream_t stream) {
  const float* s_in  = (const float*)d_in[0];
  const float* x     = (const float*)d_in[1];
  const int*   row   = (const int*)d_in[2];
  const int*   col   = (const int*)d_in[3];
  const float* val   = (const float*)d_in[4];
  const int*   index = (const int*)d_in[5];
  const float* W1    = (const float*)d_in[6];
  const float* b1    = (const float*)d_in[7];
  const float* W2    = (const float*)d_in[8];
  const float* b2    = (const float*)d_in[9];
  const float* Wl    = (const float*)d_in[10];
  const float* bl    = (const float*)d_in[11];
  float* out = (float*)d_out;

  // workspace carve (~87 MB), 8B-aligned first
  ull* edat  = (ull*)d_ws;                                           // [1.6M] final CSR edges
  ull* ebuf1 = edat + N_EDGES;                                       // [1.6M] L1-bucketed temp
  unsigned short* a  = (unsigned short*)(ebuf1 + N_EDGES);           // xW1 bf16   [100000,128]
  unsigned short* h1 = a + (size_t)N_NODES * 128;                    // layer1 bf16[100000,128]
  float* g2   = (float*)(h1 + (size_t)N_NODES * 128);                // sel spmm   [8192,128]
  float* tmat = g2 + (size_t)BB * 128;                               // g2@W2+b2   [8192,128]
  int* counts = (int*)(tmat + (size_t)BB * 128);                     // [100000]
  int* flag   = counts + N_NODES;                                    // [100000] needed-row mask
  int* offs   = flag + N_NODES;                                      // [100001]
  int* bsum   = offs + (N_NODES + 1);                                // [391]
  int* bpre   = bsum + SCAN_NB;                                      // [391]
  int* gcur1  = bpre + SCAN_NB;                                      // [49]
  int* gcur2  = gcur1 + NB1;                                         // [3125]
  uint* Wt1   = (uint*)(gcur2 + NSUB);                               // [8192] W1 bf16 [n][k]
  uint* Wt2   = Wt1 + 8192;                                          // [8192] W2 bf16 [n][k]

  hipMemsetAsync(counts, 0, 2 * N_NODES * sizeof(int), stream);  // counts + flag
  hist_kernel<<<4096, 256, 0, stream>>>(row, counts);
  partial_kernel<<<SCAN_NB, 256, 0, stream>>>(counts, bsum);
  scanp_kernel<<<1, 512, 0, stream>>>(bsum, bpre, offs);
  apply_kernel<<<SCAN_NB, 256, 0, stream>>>(counts, bpre, offs);
  initcur_kernel<<<(NSUB + 255) / 256, 256, 0, stream>>>(offs, gcur1, gcur2);

  binA_kernel<<<512, 256, 0, stream>>>(row, col, val, gcur1, ebuf1);
  binB_kernel<<<NB1 * 8, 256, 0, stream>>>(ebuf1, offs, gcur2, edat);
  binC_kernel<<<NSUB, 256, 0, stream>>>(offs, edat, ebuf1);
  mask_kernel<<<BB / 256, 256, 0, stream>>>(offs, edat, index, flag);

  wconv_kernel<<<32, 256, 0, stream>>>(W1, Wt1);
  wconv_kernel<<<32, 256, 0, stream>>>(W2, Wt2);

  mfma_gemm_kernel<1><<<(N_NODES + 63) / 64, 256, 0, stream>>>(x, Wt1, nullptr, a, N_NODES);
  spmm_row_kernel<<<N_NODES / 4, 256, 0, stream>>>(offs, edat, a, b1, h1, flag);
  spmm_sel_kernel<<<BB / 4, 256, 0, stream>>>(offs, edat, h1, index, g2);
  mfma_gemm_kernel<0><<<BB / 64, 256, 0, stream>>>(g2, Wt2, b2, tmat, BB);
  final_kernel<<<BB / 128, 128, 0, stream>>>(tmat, s_in, Wl, bl, out);
}

// Round 8
// 350.156 us; speedup vs baseline: 1.4814x; 1.1055x over previous
//
#include <hip/hip_runtime.h>
#include <math.h>

#define N_NODES 100000
#define N_EDGES 1600000
#define NFEAT 128
#define NHID 128
#define NS 64
#define NCLASS 16
#define BB 8192

// binned CSR build geometry
#define B1_SHIFT 11               // 2048 rows per L1 bucket
#define NB1 49                    // ceil(100000 / 2048)
#define SUB_SHIFT 5               // 32 rows per sub-bucket
#define NSUB 3125                 // 100000 / 32
#define CHUNK 1024                // edges per block-iteration in bin passes
#define HWG 256                   // histogram workgroups
#define SUB_NB 13                 // ceil(NSUB / 256)

typedef unsigned long long ull;
typedef unsigned int uint;

// ---------------- bf16 helpers ----------------

__device__ __forceinline__ unsigned short f2bf(float f) {
  unsigned int u = __float_as_uint(f);
  return (unsigned short)((u + 0x7fffu + ((u >> 16) & 1u)) >> 16);  // RNE
}
__device__ __forceinline__ float bflo(unsigned int u) {  // low bf16 of packed uint
  return __uint_as_float(u << 16);
}
__device__ __forceinline__ float bfhi(unsigned int u) {  // high bf16 of packed uint
  return __uint_as_float(u & 0xffff0000u);
}
__device__ __forceinline__ unsigned int packbf2(float lo, float hi) {
  return (unsigned int)f2bf(lo) | ((unsigned int)f2bf(hi) << 16);
}

// ---------------- edge packing: [63:34]=val[31:2], [33:17]=row, [16:0]=col ----------------

__device__ __forceinline__ ull pack_edge(float v, int r, int c) {
  return ((ull)(__float_as_uint(v) >> 2) << 34) | ((ull)(unsigned)r << 17) | (unsigned)c;
}
__device__ __forceinline__ int edge_col(ull p) { return (int)(p & 0x1FFFFu); }
__device__ __forceinline__ int edge_row(ull p) { return (int)((unsigned)(p >> 17) & 0x1FFFFu); }
__device__ __forceinline__ float edge_val(ull p) {
  return __uint_as_float(((unsigned)(p >> 34)) << 2);
}

// ---------------- sub-bucket histogram (3125 bins, LDS-privatized) ----------------

__global__ __launch_bounds__(256) void histsub_kernel(const int* __restrict__ row,
                                                      int* __restrict__ part_hist) {
  __shared__ int lh[NSUB];
  int tid = threadIdx.x;
  for (int i = tid; i < NSUB; i += 256) lh[i] = 0;
  __syncthreads();
  for (long i = (long)blockIdx.x * 256 + tid; i < N_EDGES; i += (long)HWG * 256)
    atomicAdd(&lh[row[i] >> SUB_SHIFT], 1);
  __syncthreads();
  int* dst = part_hist + blockIdx.x * NSUB;
  for (int i = tid; i < NSUB; i += 256) dst[i] = lh[i];
}

__global__ __launch_bounds__(256) void reduce_kernel(const int* __restrict__ part_hist,
                                                     int* __restrict__ subcnt) {
  int b = blockIdx.x * 256 + threadIdx.x;
  if (b >= NSUB) return;
  int s = 0;
  for (int w = 0; w < HWG; ++w) s += part_hist[w * NSUB + b];
  subcnt[b] = s;
}

// ---------------- scan of 3125 sub-bucket counts -> sub_offs ----------------

__global__ __launch_bounds__(256) void partial2_kernel(const int* __restrict__ subcnt,
                                                       int* __restrict__ bsum) {
  __shared__ int sd[256];
  int i = blockIdx.x * 256 + threadIdx.x;
  sd[threadIdx.x] = (i < NSUB) ? subcnt[i] : 0;
  __syncthreads();
  for (int o = 128; o > 0; o >>= 1) {
    if (threadIdx.x < o) sd[threadIdx.x] += sd[threadIdx.x + o];
    __syncthreads();
  }
  if (threadIdx.x == 0) bsum[blockIdx.x] = sd[0];
}

__global__ __launch_bounds__(64) void scanp2_kernel(const int* __restrict__ bsum,
                                                    int* __restrict__ bpre,
                                                    int* __restrict__ sub_offs) {
  int tid = threadIdx.x;
  int v = (tid < SUB_NB) ? bsum[tid] : 0;
  int x = v;
  for (int o = 1; o < 64; o <<= 1) {
    int y = __shfl_up(x, o);
    if (tid >= o) x += y;
  }
  if (tid < SUB_NB) bpre[tid] = x - v;
  if (tid == SUB_NB - 1) sub_offs[NSUB] = x;   // total = N_EDGES
}

__global__ __launch_bounds__(256) void apply2_kernel(const int* __restrict__ subcnt,
                                                     const int* __restrict__ bpre,
                                                     int* __restrict__ sub_offs) {
  __shared__ int sd[256];
  int tid = threadIdx.x;
  int i = blockIdx.x * 256 + tid;
  int v = (i < NSUB) ? subcnt[i] : 0;
  sd[tid] = v;
  __syncthreads();
  for (int o = 1; o < 256; o <<= 1) {
    int add = (tid >= o) ? sd[tid - o] : 0;
    __syncthreads();
    sd[tid] += add;
    __syncthreads();
  }
  if (i < NSUB) sub_offs[i] = bpre[blockIdx.x] + sd[tid] - v;
}

__global__ __launch_bounds__(256) void initcur_kernel(const int* __restrict__ sub_offs,
                                                      int* __restrict__ gcur1,
                                                      int* __restrict__ gcur2) {
  int t = blockIdx.x * 256 + threadIdx.x;
  if (t < NB1) gcur1[t] = sub_offs[t << 6];
  if (t < NSUB) gcur2[t] = sub_offs[t];
}

// ---------------- pass A: edges -> 49 L1 bucket regions (coalesced runs) ----------------

__global__ __launch_bounds__(256) void binA_kernel(const int* __restrict__ row,
                                                   const int* __restrict__ col,
                                                   const float* __restrict__ val,
                                                   int* __restrict__ gcur1,
                                                   ull* __restrict__ ebuf1) {
  __shared__ ull stage[CHUNK];
  __shared__ int hist[NB1], lofs[NB1 + 1], lcur[NB1], gbase[NB1];
  int tid = threadIdx.x;
  for (long base = (long)blockIdx.x * CHUNK; base < N_EDGES; base += (long)gridDim.x * CHUNK) {
    int cnt = (int)min((long)CHUNK, (long)N_EDGES - base);
    if (tid < NB1) hist[tid] = 0;
    __syncthreads();
    ull e[4]; int bk[4];
#pragma unroll
    for (int v = 0; v < 4; ++v) {
      int i = v * 256 + tid;
      bk[v] = -1;
      if (i < cnt) {
        long g = base + i;
        int r = row[g];
        e[v] = pack_edge(val[g], r, col[g]);
        bk[v] = r >> B1_SHIFT;
        atomicAdd(&hist[bk[v]], 1);
      }
    }
    __syncthreads();
    if (tid < 64) {
      int h = (tid < NB1) ? hist[tid] : 0;
      int x = h;
      for (int o = 1; o < 64; o <<= 1) {
        int y = __shfl_up(x, o);
        if (tid >= o) x += y;
      }
      if (tid < NB1) { lofs[tid] = x - h; lcur[tid] = x - h; }
      if (tid == 63) lofs[NB1] = x;  // == cnt
    }
    __syncthreads();
#pragma unroll
    for (int v = 0; v < 4; ++v) {
      if (bk[v] >= 0) {
        int pos = atomicAdd(&lcur[bk[v]], 1);
        stage[pos] = e[v];
      }
    }
    __syncthreads();
    if (tid < NB1) {
      int h = hist[tid];
      if (h > 0) gbase[tid] = atomicAdd(&gcur1[tid], h);
    }
    __syncthreads();
    for (int s = tid; s < cnt; s += 256) {
      int lo = 0, hi = NB1;
      while (hi - lo > 1) {
        int mid = (lo + hi) >> 1;
        if (lofs[mid] <= s) lo = mid; else hi = mid;
      }
      ebuf1[gbase[lo] + (s - lofs[lo])] = stage[s];
    }
    __syncthreads();
  }
}

// ---------------- pass B: L1 bucket -> 64 sub-bucket regions ----------------

__global__ __launch_bounds__(256) void binB_kernel(const ull* __restrict__ ebuf1,
                                                   const int* __restrict__ sub_offs,
                                                   int* __restrict__ gcur2,
                                                   ull* __restrict__ edat) {
  __shared__ ull stage[CHUNK];
  __shared__ int hist[64], lofs[65], lcur[64], gbase[64];
  int tid = threadIdx.x;
  int b1 = blockIdx.x >> 3, w = blockIdx.x & 7;
  int rbeg = sub_offs[b1 << 6];
  int rend = sub_offs[min((b1 + 1) << 6, NSUB)];
  for (int base = rbeg + w * CHUNK; base < rend; base += 8 * CHUNK) {
    int cnt = min(CHUNK, rend - base);
    if (tid < 64) hist[tid] = 0;
    __syncthreads();
    ull e[4]; int bk[4];
#pragma unroll
    for (int v = 0; v < 4; ++v) {
      int i = v * 256 + tid;
      bk[v] = -1;
      if (i < cnt) {
        e[v] = ebuf1[base + i];
        bk[v] = (edge_row(e[v]) >> SUB_SHIFT) - (b1 << 6);
        atomicAdd(&hist[bk[v]], 1);
      }
    }
    __syncthreads();
    if (tid < 64) {
      int h = hist[tid];
      int x = h;
      for (int o = 1; o < 64; o <<= 1) {
        int y = __shfl_up(x, o);
        if (tid >= o) x += y;
      }
      lofs[tid] = x - h;
      lcur[tid] = x - h;
      if (tid == 63) lofs[64] = x;  // == cnt
    }
    __syncthreads();
#pragma unroll
    for (int v = 0; v < 4; ++v) {
      if (bk[v] >= 0) {
        int pos = atomicAdd(&lcur[bk[v]], 1);
        stage[pos] = e[v];
      }
    }
    __syncthreads();
    if (tid < 64) {
      int h = hist[tid];
      if (h > 0) gbase[tid] = atomicAdd(&gcur2[(b1 << 6) + tid], h);
    }
    __syncthreads();
    for (int s = tid; s < cnt; s += 256) {
      int lo = 0, hi = 64;
      while (hi - lo > 1) {
        int mid = (lo + hi) >> 1;
        if (lofs[mid] <= s) lo = mid; else hi = mid;
      }
      edat[gbase[lo] + (s - lofs[lo])] = stage[s];
    }
    __syncthreads();
  }
}

// ---- pass C: exact row placement within each 32-row sub-bucket; emits row-level offs ----

__global__ __launch_bounds__(256) void binC_kernel(const int* __restrict__ sub_offs,
                                                   ull* __restrict__ edat,
                                                   ull* __restrict__ ebuf1,
                                                   int* __restrict__ offs) {
  __shared__ int rcnt[32], rofs[32], rcur[32];
  int s = blockIdx.x, tid = threadIdx.x;
  int r0 = s << SUB_SHIFT;
  int beg = sub_offs[s], end = sub_offs[s + 1];
  int n = end - beg;
  if (tid < 32) rcnt[tid] = 0;
  __syncthreads();
  for (int i = tid; i < n; i += 256) {
    ull p = edat[beg + i];
    ebuf1[beg + i] = p;                    // scratch copy (region private to this WG)
    atomicAdd(&rcnt[edge_row(p) & 31], 1);
  }
  __syncthreads();
  if (tid < 32) {
    int h = rcnt[tid];
    int x = h;
    for (int o = 1; o < 32; o <<= 1) {
      int y = __shfl_up(x, o, 32);
      if (tid >= o) x += y;
    }
    rofs[tid] = x - h;
    rcur[tid] = x - h;
    offs[r0 + tid] = beg + x - h;          // row-level CSR offsets, for free
    if (s == NSUB - 1 && tid == 31) offs[N_NODES] = end;
  }
  __syncthreads();
  for (int i = tid; i < n; i += 256) {
    ull p = ebuf1[beg + i];
    int pos = atomicAdd(&rcur[edge_row(p) & 31], 1);
    edat[beg + pos] = p;
  }
}

// ---------------- needed-row mask: cols of edges of the 8192 selected rows ----------------

__global__ __launch_bounds__(256) void mask_kernel(const int* __restrict__ offs,
                                                   const ull* __restrict__ edat,
                                                   const int* __restrict__ index,
                                                   int* __restrict__ flag) {
  int t = blockIdx.x * 256 + threadIdx.x;  // 8192 threads exactly
  int r = index[t];
  int s = offs[r], e = offs[r + 1];
  for (int j = s; j < e; ++j) flag[edge_col(edat[j])] = 1;
}

// ---------------- weight convert: W fp32 [k][n] -> Wt bf16-packed uint [n][k/2] ----------

__global__ __launch_bounds__(256) void wconv_kernel(const float* __restrict__ W,
                                                    uint* __restrict__ Wt) {
  int idx = blockIdx.x * 256 + threadIdx.x;   // 8192 exactly (grid 32)
  int n = idx >> 6, kc = idx & 63;
  float lo = W[(2 * kc) * 128 + n];
  float hi = W[(2 * kc + 1) * 128 + n];
  Wt[idx] = packbf2(lo, hi);
}

// ---------------- MFMA GEMM: C[nr,128] = A[nr,128] @ W[128,128] (+bias) ----------------
// block = 256 threads (4 waves), tile M=64 x N=128, K=128 entirely in LDS.
// A staged fp32->bf16; Wt pre-converted bf16 [n][k]. LDS row stride 68 uints.
// A frag: A[m=lane&15][k=quad*8+j]; B frag: B[n=lane&15][k=quad*8+j] (W^T layout);
// C/D layout: col = lane&15, row = (lane>>4)*4 + reg.

typedef __attribute__((ext_vector_type(8))) __bf16 bf16x8;
typedef __attribute__((ext_vector_type(4))) float f32x4;
union FragU { uint4 u; bf16x8 b; };

#define LDSTR 68   // uints per 128-feat row in LDS

template <int OUT_BF16>
__global__ __launch_bounds__(256) void mfma_gemm_kernel(const float* __restrict__ A,
                                                        const uint* __restrict__ Wt_g,
                                                        const float* __restrict__ bias,
                                                        void* __restrict__ C,
                                                        int nrows) {
  __shared__ uint As_s[64 * LDSTR];    // 17.4 KB
  __shared__ uint Wt_s[128 * LDSTR];   // 34.8 KB
  int tid = threadIdx.x;
  int rbase = blockIdx.x * 64;

  // stage Wt: 8192 uints, uint2 per iteration
  {
    const uint2* src = (const uint2*)Wt_g;
#pragma unroll
    for (int i = 0; i < 16; ++i) {
      int j = i * 256 + tid;               // uint2 index, 0..4095
      int n = j >> 5, c2 = (j & 31) * 2;
      uint2 v = src[j];
      Wt_s[n * LDSTR + c2] = v.x;
      Wt_s[n * LDSTR + c2 + 1] = v.y;
    }
  }
  // stage A tile: 64 rows x 128 fp32 -> bf16 packed (one float4 -> 2 uints)
  {
    const float4* src = (const float4*)(A + (long)rbase * 128);
#pragma unroll
    for (int i = 0; i < 8; ++i) {
      int f = i * 256 + tid;               // float4 index, 0..2047
      int m = f >> 5;
      float4 v = (rbase + m < nrows) ? src[f] : make_float4(0.f, 0.f, 0.f, 0.f);
      int c = (f & 31) * 2;                // uint col (0..62 step 2)
      As_s[m * LDSTR + c]     = packbf2(v.x, v.y);
      As_s[m * LDSTR + c + 1] = packbf2(v.z, v.w);
    }
  }
  __syncthreads();

  int w = tid >> 6, lane = tid & 63;
  int quad = lane >> 4, lr = lane & 15;
  int n0 = w * 32;

  f32x4 acc[4][2];
#pragma unroll
  for (int mt = 0; mt < 4; ++mt)
#pragma unroll
    for (int nt = 0; nt < 2; ++nt) acc[mt][nt] = (f32x4){0.f, 0.f, 0.f, 0.f};

#pragma unroll
  for (int kk = 0; kk < 4; ++kk) {
    int kc = kk * 16 + quad * 4;
    FragU fb0, fb1;
    fb0.u = *(const uint4*)&Wt_s[(n0 + lr) * LDSTR + kc];
    fb1.u = *(const uint4*)&Wt_s[(n0 + 16 + lr) * LDSTR + kc];
#pragma unroll
    for (int mt = 0; mt < 4; ++mt) {
      FragU fa;
      fa.u = *(const uint4*)&As_s[(mt * 16 + lr) * LDSTR + kc];
      acc[mt][0] = __builtin_amdgcn_mfma_f32_16x16x32_bf16(fa.b, fb0.b, acc[mt][0], 0, 0, 0);
      acc[mt][1] = __builtin_amdgcn_mfma_f32_16x16x32_bf16(fa.b, fb1.b, acc[mt][1], 0, 0, 0);
    }
  }

#pragma unroll
  for (int mt = 0; mt < 4; ++mt) {
#pragma unroll
    for (int nt = 0; nt < 2; ++nt) {
      int col = n0 + nt * 16 + lr;
      float bv = OUT_BF16 ? 0.f : bias[col];
#pragma unroll
      for (int r = 0; r < 4; ++r) {
        int row = rbase + mt * 16 + quad * 4 + r;
        if (row < nrows) {
          if (OUT_BF16)
            ((unsigned short*)C)[(long)row * 128 + col] = f2bf(acc[mt][nt][r]);
          else
            ((float*)C)[(long)row * 128 + col] = acc[mt][nt][r] + bv;
        }
      }
    }
  }
}

// ---------------- CSR spmm: 4 waves/block, 1 row/wave, 4 edge-groups x 16 lanes x 8 feats ----

__global__ __launch_bounds__(256) void spmm_row_kernel(const int* __restrict__ offs,
                                                       const ull* __restrict__ edat,
                                                       const unsigned short* __restrict__ a,
                                                       const float* __restrict__ bias,
                                                       unsigned short* __restrict__ h,
                                                       const int* __restrict__ flag) {
  int wave = threadIdx.x >> 6;
  int lane = threadIdx.x & 63;
  int r = blockIdx.x * 4 + wave;           // grid = 25000, exact
  if (!flag[r]) return;                    // h1 row never read downstream
  int g = lane >> 4, l = lane & 15;
  int s = offs[r], e = offs[r + 1];
  float acc[8] = {0.f, 0.f, 0.f, 0.f, 0.f, 0.f, 0.f, 0.f};
  for (int j = s + g; j < e; j += 4) {
    ull p = edat[j];
    float v = edge_val(p);
    uint4 u = *(const uint4*)(a + (long)edge_col(p) * 128 + l * 8);
    acc[0] = fmaf(v, bflo(u.x), acc[0]);
    acc[1] = fmaf(v, bfhi(u.x), acc[1]);
    acc[2] = fmaf(v, bflo(u.y), acc[2]);
    acc[3] = fmaf(v, bfhi(u.y), acc[3]);
    acc[4] = fmaf(v, bflo(u.z), acc[4]);
    acc[5] = fmaf(v, bfhi(u.z), acc[5]);
    acc[6] = fmaf(v, bflo(u.w), acc[6]);
    acc[7] = fmaf(v, bfhi(u.w), acc[7]);
  }
#pragma unroll
  for (int k = 0; k < 8; ++k) {
    acc[k] += __shfl_xor(acc[k], 16);
    acc[k] += __shfl_xor(acc[k], 32);
  }
  if (g == 0) {
    float4 b0 = *(const float4*)(bias + l * 8);
    float4 b1 = *(const float4*)(bias + l * 8 + 4);
    uint4 o;
    o.x = packbf2(fmaxf(acc[0] + b0.x, 0.f), fmaxf(acc[1] + b0.y, 0.f));
    o.y = packbf2(fmaxf(acc[2] + b0.z, 0.f), fmaxf(acc[3] + b0.w, 0.f));
    o.z = packbf2(fmaxf(acc[4] + b1.x, 0.f), fmaxf(acc[5] + b1.y, 0.f));
    o.w = packbf2(fmaxf(acc[6] + b1.z, 0.f), fmaxf(acc[7] + b1.w, 0.f));
    *(uint4*)(h + (long)r * 128 + l * 8) = o;
  }
}

__global__ __launch_bounds__(256) void spmm_sel_kernel(const int* __restrict__ offs,
                                                       const ull* __restrict__ edat,
                                                       const unsigned short* __restrict__ h1,
                                                       const int* __restrict__ index,
                                                       float* __restrict__ g2) {
  int wave = threadIdx.x >> 6;
  int lane = threadIdx.x & 63;
  int b = blockIdx.x * 4 + wave;           // grid = 2048, exact
  int g = lane >> 4, l = lane & 15;
  int r = index[b];
  int s = offs[r], e = offs[r + 1];
  float acc[8] = {0.f, 0.f, 0.f, 0.f, 0.f, 0.f, 0.f, 0.f};
  for (int j = s + g; j < e; j += 4) {
    ull p = edat[j];
    float v = edge_val(p);
    uint4 u = *(const uint4*)(h1 + (long)edge_col(p) * 128 + l * 8);
    acc[0] = fmaf(v, bflo(u.x), acc[0]);
    acc[1] = fmaf(v, bfhi(u.x), acc[1]);
    acc[2] = fmaf(v, bflo(u.y), acc[2]);
    acc[3] = fmaf(v, bfhi(u.y), acc[3]);
    acc[4] = fmaf(v, bflo(u.z), acc[4]);
    acc[5] = fmaf(v, bfhi(u.z), acc[5]);
    acc[6] = fmaf(v, bflo(u.w), acc[6]);
    acc[7] = fmaf(v, bfhi(u.w), acc[7]);
  }
#pragma unroll
  for (int k = 0; k < 8; ++k) {
    acc[k] += __shfl_xor(acc[k], 16);
    acc[k] += __shfl_xor(acc[k], 32);
  }
  if (g == 0) {
    float* op = g2 + (long)b * 128 + l * 8;
    *(float4*)(op + 0) = make_float4(acc[0], acc[1], acc[2], acc[3]);
    *(float4*)(op + 4) = make_float4(acc[4], acc[5], acc[6], acc[7]);
  }
}

// ---------------- final: z = concat(t, s) @ Wl + bl; log_softmax ----------------

__global__ __launch_bounds__(128) void final_kernel(const float* __restrict__ t,
                                                    const float* __restrict__ s,
                                                    const float* __restrict__ Wl,
                                                    const float* __restrict__ bl,
                                                    float* __restrict__ out) {
  int b = blockIdx.x * 128 + threadIdx.x;
  float z[16];
#pragma unroll
  for (int c = 0; c < 16; ++c) z[c] = bl[c];
  const float4* tb = (const float4*)(t + (long)b * 128);
#pragma unroll 4
  for (int k4 = 0; k4 < 32; ++k4) {
    float4 tv = tb[k4];
    const float* w = Wl + (k4 * 4) * 16;
#pragma unroll
    for (int c = 0; c < 16; ++c)
      z[c] += tv.x * w[c] + tv.y * w[16 + c] + tv.z * w[32 + c] + tv.w * w[48 + c];
  }
  const float4* sb = (const float4*)(s + (long)b * 64);
#pragma unroll 4
  for (int k4 = 0; k4 < 16; ++k4) {
    float4 sv = sb[k4];
    const float* w = Wl + (128 + k4 * 4) * 16;
#pragma unroll
    for (int c = 0; c < 16; ++c)
      z[c] += sv.x * w[c] + sv.y * w[16 + c] + sv.z * w[32 + c] + sv.w * w[48 + c];
  }
  float m = z[0];
#pragma unroll
  for (int c = 1; c < 16; ++c) m = fmaxf(m, z[c]);
  float sum = 0.f;
#pragma unroll
  for (int c = 0; c < 16; ++c) sum += expf(z[c] - m);
  float lse = m + logf(sum);
  float* ob = out + (long)b * 16;
#pragma unroll
  for (int c = 0; c < 16; ++c) ob[c] = z[c] - lse;
}

// ---------------- launch ----------------

extern "C" void kernel_launch(void* const* d_in, const int* in_sizes, int n_in,
                              void* d_out, int out_size, void* d_ws, size_t ws_size,
                              hipStream_t stream) {
  const float* s_in  = (const float*)d_in[0];
  const float* x     = (const float*)d_in[1];
  const int*   row   = (const int*)d_in[2];
  const int*   col   = (const int*)d_in[3];
  const float* val   = (const float*)d_in[4];
  const int*   index = (const int*)d_in[5];
  const float* W1    = (const float*)d_in[6];
  const float* b1    = (const float*)d_in[7];
  const float* W2    = (const float*)d_in[8];
  const float* b2    = (const float*)d_in[9];
  const float* Wl    = (const float*)d_in[10];
  const float* bl    = (const float*)d_in[11];
  float* out = (float*)d_out;

  // workspace carve (~89 MB), 8B-aligned first
  ull* edat  = (ull*)d_ws;                                           // [1.6M] final CSR edges
  ull* ebuf1 = edat + N_EDGES;                                       // [1.6M] L1-bucketed temp
  unsigned short* a  = (unsigned short*)(ebuf1 + N_EDGES);           // xW1 bf16   [100000,128]
  unsigned short* h1 = a + (size_t)N_NODES * 128;                    // layer1 bf16[100000,128]
  float* g2   = (float*)(h1 + (size_t)N_NODES * 128);                // sel spmm   [8192,128]
  float* tmat = g2 + (size_t)BB * 128;                               // g2@W2+b2   [8192,128]
  int* flag   = (int*)(tmat + (size_t)BB * 128);                     // [100000] needed-row mask
  int* offs   = flag + N_NODES;                                      // [100001] (binC writes)
  int* sub_offs = offs + (N_NODES + 1);                              // [3126]
  int* subcnt = sub_offs + (NSUB + 1);                               // [3125]
  int* bsum2  = subcnt + NSUB;                                       // [13]
  int* bpre2  = bsum2 + SUB_NB;                                      // [13]
  int* gcur1  = bpre2 + SUB_NB;                                      // [49]
  int* gcur2  = gcur1 + NB1;                                         // [3125]
  uint* Wt1   = (uint*)(gcur2 + NSUB);                               // [8192] W1 bf16 [n][k]
  uint* Wt2   = Wt1 + 8192;                                          // [8192] W2 bf16 [n][k]
  int* part_hist = (int*)(Wt2 + 8192);                               // [HWG * NSUB] = 3.2 MB

  hipMemsetAsync(flag, 0, N_NODES * sizeof(int), stream);

  histsub_kernel<<<HWG, 256, 0, stream>>>(row, part_hist);
  reduce_kernel<<<SUB_NB, 256, 0, stream>>>(part_hist, subcnt);
  partial2_kernel<<<SUB_NB, 256, 0, stream>>>(subcnt, bsum2);
  scanp2_kernel<<<1, 64, 0, stream>>>(bsum2, bpre2, sub_offs);
  apply2_kernel<<<SUB_NB, 256, 0, stream>>>(subcnt, bpre2, sub_offs);
  initcur_kernel<<<(NSUB + 255) / 256, 256, 0, stream>>>(sub_offs, gcur1, gcur2);

  binA_kernel<<<512, 256, 0, stream>>>(row, col, val, gcur1, ebuf1);
  binB_kernel<<<NB1 * 8, 256, 0, stream>>>(ebuf1, sub_offs, gcur2, edat);
  binC_kernel<<<NSUB, 256, 0, stream>>>(sub_offs, edat, ebuf1, offs);
  mask_kernel<<<BB / 256, 256, 0, stream>>>(offs, edat, index, flag);

  wconv_kernel<<<32, 256, 0, stream>>>(W1, Wt1);
  wconv_kernel<<<32, 256, 0, stream>>>(W2, Wt2);

  mfma_gemm_kernel<1><<<(N_NODES + 63) / 64, 256, 0, stream>>>(x, Wt1, nullptr, a, N_NODES);
  spmm_row_kernel<<<N_NODES / 4, 256, 0, stream>>>(offs, edat, a, b1, h1, flag);
  spmm_sel_kernel<<<BB / 4, 256, 0, stream>>>(offs, edat, h1, index, g2);
  mfma_gemm_kernel<0><<<BB / 64, 256, 0, stream>>>(g2, Wt2, b2, tmat, BB);
  final_kernel<<<BB / 128, 128, 0, stream>>>(tmat, s_in, Wl, bl, out);
}

// Round 9
// 318.299 us; speedup vs baseline: 1.6296x; 1.1001x over previous
//
#include <hip/hip_runtime.h>
#include <math.h>

#define N_NODES 100000
#define N_EDGES 1600000
#define NFEAT 128
#define NHID 128
#define NS 64
#define NCLASS 16
#define BB 8192

// binned CSR build geometry
#define B1_SHIFT 11               // 2048 rows per L1 bucket
#define NB1 49                    // ceil(100000 / 2048)
#define SUB_SHIFT 5               // 32 rows per sub-bucket
#define NSUB 3125                 // 100000 / 32
#define CHUNK 1024                // edges per block-iteration in bin passes
#define HWG 256                   // histogram workgroups
#define BINC_CAP 2048             // LDS edge capacity in binC (mean 512, +68 sigma)

typedef unsigned long long ull;
typedef unsigned int uint;

// ---------------- bf16 helpers ----------------

__device__ __forceinline__ unsigned short f2bf(float f) {
  unsigned int u = __float_as_uint(f);
  return (unsigned short)((u + 0x7fffu + ((u >> 16) & 1u)) >> 16);  // RNE
}
__device__ __forceinline__ float bflo(unsigned int u) {
  return __uint_as_float(u << 16);
}
__device__ __forceinline__ float bfhi(unsigned int u) {
  return __uint_as_float(u & 0xffff0000u);
}
__device__ __forceinline__ unsigned int packbf2(float lo, float hi) {
  return (unsigned int)f2bf(lo) | ((unsigned int)f2bf(hi) << 16);
}

// ---------------- edge packing: [63:34]=val[31:2], [33:17]=row, [16:0]=col ----------------

__device__ __forceinline__ ull pack_edge(float v, int r, int c) {
  return ((ull)(__float_as_uint(v) >> 2) << 34) | ((ull)(unsigned)r << 17) | (unsigned)c;
}
__device__ __forceinline__ int edge_col(ull p) { return (int)(p & 0x1FFFFu); }
__device__ __forceinline__ int edge_row(ull p) { return (int)((unsigned)(p >> 17) & 0x1FFFFu); }
__device__ __forceinline__ float edge_val(ull p) {
  return __uint_as_float(((unsigned)(p >> 34)) << 2);
}

// ---------------- sub-bucket histogram (3125 bins, LDS-privatized, atomic flush) ------

__global__ __launch_bounds__(256) void histsub_kernel(const int* __restrict__ row,
                                                      int* __restrict__ subcnt) {
  __shared__ int lh[NSUB];
  int tid = threadIdx.x;
  for (int i = tid; i < NSUB; i += 256) lh[i] = 0;
  __syncthreads();
  for (long i = (long)blockIdx.x * 256 + tid; i < N_EDGES; i += (long)HWG * 256)
    atomicAdd(&lh[row[i] >> SUB_SHIFT], 1);
  __syncthreads();
  for (int i = tid; i < NSUB; i += 256) {
    int c = lh[i];
    if (c) atomicAdd(&subcnt[i], c);
  }
}

// ---------------- scan of 3125 sub-bucket counts -> sub_offs, gcur1, gcur2 (1 WG) ----

__global__ __launch_bounds__(1024) void scanall_kernel(const int* __restrict__ subcnt,
                                                       int* __restrict__ sub_offs,
                                                       int* __restrict__ gcur1,
                                                       int* __restrict__ gcur2) {
  __shared__ int sd[1024];
  int tid = threadIdx.x;
  int b0 = tid * 4;
  int vv[4];
  int loc = 0;
#pragma unroll
  for (int k = 0; k < 4; ++k) {
    int i = b0 + k;
    vv[k] = (i < NSUB) ? subcnt[i] : 0;
    loc += vv[k];
  }
  sd[tid] = loc;
  __syncthreads();
  for (int o = 1; o < 1024; o <<= 1) {
    int add = (tid >= o) ? sd[tid - o] : 0;
    __syncthreads();
    sd[tid] += add;
    __syncthreads();
  }
  int pre = sd[tid] - loc;   // exclusive prefix of this thread's 4-bin chunk
#pragma unroll
  for (int k = 0; k < 4; ++k) {
    int i = b0 + k;
    if (i < NSUB) {
      sub_offs[i] = pre;
      gcur2[i] = pre;
      if ((i & 63) == 0) gcur1[i >> 6] = pre;
      pre += vv[k];
    }
  }
  if (tid == 1023) sub_offs[NSUB] = sd[1023];
}

// ---------------- pass A: edges -> 49 L1 bucket regions (coalesced runs) ----------------

__global__ __launch_bounds__(256) void binA_kernel(const int* __restrict__ row,
                                                   const int* __restrict__ col,
                                                   const float* __restrict__ val,
                                                   int* __restrict__ gcur1,
                                                   ull* __restrict__ ebuf1) {
  __shared__ ull stage[CHUNK];
  __shared__ int hist[NB1], lofs[NB1 + 1], lcur[NB1], gbase[NB1];
  int tid = threadIdx.x;
  for (long base = (long)blockIdx.x * CHUNK; base < N_EDGES; base += (long)gridDim.x * CHUNK) {
    int cnt = (int)min((long)CHUNK, (long)N_EDGES - base);
    if (tid < NB1) hist[tid] = 0;
    __syncthreads();
    ull e[4]; int bk[4];
#pragma unroll
    for (int v = 0; v < 4; ++v) {
      int i = v * 256 + tid;
      bk[v] = -1;
      if (i < cnt) {
        long g = base + i;
        int r = row[g];
        e[v] = pack_edge(val[g], r, col[g]);
        bk[v] = r >> B1_SHIFT;
        atomicAdd(&hist[bk[v]], 1);
      }
    }
    __syncthreads();
    if (tid < 64) {
      int h = (tid < NB1) ? hist[tid] : 0;
      int x = h;
      for (int o = 1; o < 64; o <<= 1) {
        int y = __shfl_up(x, o);
        if (tid >= o) x += y;
      }
      if (tid < NB1) { lofs[tid] = x - h; lcur[tid] = x - h; }
      if (tid == 63) lofs[NB1] = x;  // == cnt
    }
    __syncthreads();
#pragma unroll
    for (int v = 0; v < 4; ++v) {
      if (bk[v] >= 0) {
        int pos = atomicAdd(&lcur[bk[v]], 1);
        stage[pos] = e[v];
      }
    }
    __syncthreads();
    if (tid < NB1) {
      int h = hist[tid];
      if (h > 0) gbase[tid] = atomicAdd(&gcur1[tid], h);
    }
    __syncthreads();
    for (int s = tid; s < cnt; s += 256) {
      int lo = 0, hi = NB1;
      while (hi - lo > 1) {
        int mid = (lo + hi) >> 1;
        if (lofs[mid] <= s) lo = mid; else hi = mid;
      }
      ebuf1[gbase[lo] + (s - lofs[lo])] = stage[s];
    }
    __syncthreads();
  }
}

// ---------------- pass B: L1 bucket -> 64 sub-bucket regions ----------------

__global__ __launch_bounds__(256) void binB_kernel(const ull* __restrict__ ebuf1,
                                                   const int* __restrict__ sub_offs,
                                                   int* __restrict__ gcur2,
                                                   ull* __restrict__ edat) {
  __shared__ ull stage[CHUNK];
  __shared__ int hist[64], lofs[65], lcur[64], gbase[64];
  int tid = threadIdx.x;
  int b1 = blockIdx.x >> 3, w = blockIdx.x & 7;
  int rbeg = sub_offs[b1 << 6];
  int rend = sub_offs[min((b1 + 1) << 6, NSUB)];
  for (int base = rbeg + w * CHUNK; base < rend; base += 8 * CHUNK) {
    int cnt = min(CHUNK, rend - base);
    if (tid < 64) hist[tid] = 0;
    __syncthreads();
    ull e[4]; int bk[4];
#pragma unroll
    for (int v = 0; v < 4; ++v) {
      int i = v * 256 + tid;
      bk[v] = -1;
      if (i < cnt) {
        e[v] = ebuf1[base + i];
        bk[v] = (edge_row(e[v]) >> SUB_SHIFT) - (b1 << 6);
        atomicAdd(&hist[bk[v]], 1);
      }
    }
    __syncthreads();
    if (tid < 64) {
      int h = hist[tid];
      int x = h;
      for (int o = 1; o < 64; o <<= 1) {
        int y = __shfl_up(x, o);
        if (tid >= o) x += y;
      }
      lofs[tid] = x - h;
      lcur[tid] = x - h;
      if (tid == 63) lofs[64] = x;  // == cnt
    }
    __syncthreads();
#pragma unroll
    for (int v = 0; v < 4; ++v) {
      if (bk[v] >= 0) {
        int pos = atomicAdd(&lcur[bk[v]], 1);
        stage[pos] = e[v];
      }
    }
    __syncthreads();
    if (tid < 64) {
      int h = hist[tid];
      if (h > 0) gbase[tid] = atomicAdd(&gcur2[(b1 << 6) + tid], h);
    }
    __syncthreads();
    for (int s = tid; s < cnt; s += 256) {
      int lo = 0, hi = 64;
      while (hi - lo > 1) {
        int mid = (lo + hi) >> 1;
        if (lofs[mid] <= s) lo = mid; else hi = mid;
      }
      edat[gbase[lo] + (s - lofs[lo])] = stage[s];
    }
    __syncthreads();
  }
}

// ---- pass C: exact row placement within each 32-row sub-bucket (LDS-staged); emits offs ----

__global__ __launch_bounds__(256) void binC_kernel(const int* __restrict__ sub_offs,
                                                   ull* __restrict__ edat,
                                                   ull* __restrict__ ebuf1,
                                                   int* __restrict__ offs) {
  __shared__ ull es[BINC_CAP];           // 16 KB
  __shared__ int rcnt[32], rcur[32];
  int s = blockIdx.x, tid = threadIdx.x;
  int r0 = s << SUB_SHIFT;
  int beg = sub_offs[s], end = sub_offs[s + 1];
  int n = end - beg;
  if (tid < 32) rcnt[tid] = 0;
  __syncthreads();
  if (n <= BINC_CAP) {
    for (int i = tid; i < n; i += 256) {
      ull p = edat[beg + i];
      es[i] = p;
      atomicAdd(&rcnt[edge_row(p) & 31], 1);
    }
    __syncthreads();
    if (tid < 32) {
      int h = rcnt[tid];
      int x = h;
      for (int o = 1; o < 32; o <<= 1) {
        int y = __shfl_up(x, o, 32);
        if (tid >= o) x += y;
      }
      rcur[tid] = x - h;
      offs[r0 + tid] = beg + x - h;
      if (s == NSUB - 1 && tid == 31) offs[N_NODES] = end;
    }
    __syncthreads();
    for (int i = tid; i < n; i += 256) {
      ull p = es[i];
      int pos = atomicAdd(&rcur[edge_row(p) & 31], 1);
      edat[beg + pos] = p;
    }
  } else {  // fallback: global scratch (statistically never at mean 512)
    for (int i = tid; i < n; i += 256) {
      ull p = edat[beg + i];
      ebuf1[beg + i] = p;
      atomicAdd(&rcnt[edge_row(p) & 31], 1);
    }
    __syncthreads();
    if (tid < 32) {
      int h = rcnt[tid];
      int x = h;
      for (int o = 1; o < 32; o <<= 1) {
        int y = __shfl_up(x, o, 32);
        if (tid >= o) x += y;
      }
      rcur[tid] = x - h;
      offs[r0 + tid] = beg + x - h;
      if (s == NSUB - 1 && tid == 31) offs[N_NODES] = end;
    }
    __syncthreads();
    for (int i = tid; i < n; i += 256) {
      ull p = ebuf1[beg + i];
      int pos = atomicAdd(&rcur[edge_row(p) & 31], 1);
      edat[beg + pos] = p;
    }
  }
}

// ---------------- needed-row mask: cols of edges of the 8192 selected rows ----------------

__global__ __launch_bounds__(256) void mask_kernel(const int* __restrict__ offs,
                                                   const ull* __restrict__ edat,
                                                   const int* __restrict__ index,
                                                   int* __restrict__ flag) {
  int t = blockIdx.x * 256 + threadIdx.x;  // 8192 threads exactly
  int r = index[t];
  int s = offs[r], e = offs[r + 1];
  for (int j = s; j < e; ++j) flag[edge_col(edat[j])] = 1;
}

// ------ weight convert (both): W fp32 [k][n] -> Wt bf16-packed uint [n][k/2] ----------

__global__ __launch_bounds__(256) void wconv2_kernel(const float* __restrict__ W1,
                                                     const float* __restrict__ W2,
                                                     uint* __restrict__ Wt1,
                                                     uint* __restrict__ Wt2) {
  int blk = blockIdx.x;                       // 64 blocks: 0-31 -> W1, 32-63 -> W2
  const float* W = (blk < 32) ? W1 : W2;
  uint* Wt = (blk < 32) ? Wt1 : Wt2;
  int idx = (blk & 31) * 256 + threadIdx.x;   // 0..8191
  int n = idx >> 6, kc = idx & 63;
  float lo = W[(2 * kc) * 128 + n];
  float hi = W[(2 * kc + 1) * 128 + n];
  Wt[idx] = packbf2(lo, hi);
}

// ---------------- MFMA GEMM: C[nr,128] = A[nr,128] @ W[128,128] (+bias) ----------------
// block = 256 threads (4 waves), tile M=64 x N=128, K=128 entirely in LDS.
// A frag: A[m=lane&15][k=quad*8+j]; B frag: B[n=lane&15][k=quad*8+j] (W^T layout);
// C/D layout: col = lane&15, row = (lane>>4)*4 + reg.

typedef __attribute__((ext_vector_type(8))) __bf16 bf16x8;
typedef __attribute__((ext_vector_type(4))) float f32x4;
union FragU { uint4 u; bf16x8 b; };

#define LDSTR 68   // uints per 128-feat row in LDS

template <int OUT_BF16>
__global__ __launch_bounds__(256) void mfma_gemm_kernel(const float* __restrict__ A,
                                                        const uint* __restrict__ Wt_g,
                                                        const float* __restrict__ bias,
                                                        void* __restrict__ C,
                                                        int nrows) {
  __shared__ uint As_s[64 * LDSTR];    // 17.4 KB
  __shared__ uint Wt_s[128 * LDSTR];   // 34.8 KB
  int tid = threadIdx.x;
  int rbase = blockIdx.x * 64;

  {
    const uint2* src = (const uint2*)Wt_g;
#pragma unroll
    for (int i = 0; i < 16; ++i) {
      int j = i * 256 + tid;               // uint2 index, 0..4095
      int n = j >> 5, c2 = (j & 31) * 2;
      uint2 v = src[j];
      Wt_s[n * LDSTR + c2] = v.x;
      Wt_s[n * LDSTR + c2 + 1] = v.y;
    }
  }
  {
    const float4* src = (const float4*)(A + (long)rbase * 128);
#pragma unroll
    for (int i = 0; i < 8; ++i) {
      int f = i * 256 + tid;               // float4 index, 0..2047
      int m = f >> 5;
      float4 v = (rbase + m < nrows) ? src[f] : make_float4(0.f, 0.f, 0.f, 0.f);
      int c = (f & 31) * 2;                // uint col (0..62 step 2)
      As_s[m * LDSTR + c]     = packbf2(v.x, v.y);
      As_s[m * LDSTR + c + 1] = packbf2(v.z, v.w);
    }
  }
  __syncthreads();

  int w = tid >> 6, lane = tid & 63;
  int quad = lane >> 4, lr = lane & 15;
  int n0 = w * 32;

  f32x4 acc[4][2];
#pragma unroll
  for (int mt = 0; mt < 4; ++mt)
#pragma unroll
    for (int nt = 0; nt < 2; ++nt) acc[mt][nt] = (f32x4){0.f, 0.f, 0.f, 0.f};

#pragma unroll
  for (int kk = 0; kk < 4; ++kk) {
    int kc = kk * 16 + quad * 4;
    FragU fb0, fb1;
    fb0.u = *(const uint4*)&Wt_s[(n0 + lr) * LDSTR + kc];
    fb1.u = *(const uint4*)&Wt_s[(n0 + 16 + lr) * LDSTR + kc];
#pragma unroll
    for (int mt = 0; mt < 4; ++mt) {
      FragU fa;
      fa.u = *(const uint4*)&As_s[(mt * 16 + lr) * LDSTR + kc];
      acc[mt][0] = __builtin_amdgcn_mfma_f32_16x16x32_bf16(fa.b, fb0.b, acc[mt][0], 0, 0, 0);
      acc[mt][1] = __builtin_amdgcn_mfma_f32_16x16x32_bf16(fa.b, fb1.b, acc[mt][1], 0, 0, 0);
    }
  }

#pragma unroll
  for (int mt = 0; mt < 4; ++mt) {
#pragma unroll
    for (int nt = 0; nt < 2; ++nt) {
      int col = n0 + nt * 16 + lr;
      float bv = OUT_BF16 ? 0.f : bias[col];
#pragma unroll
      for (int r = 0; r < 4; ++r) {
        int row = rbase + mt * 16 + quad * 4 + r;
        if (row < nrows) {
          if (OUT_BF16)
            ((unsigned short*)C)[(long)row * 128 + col] = f2bf(acc[mt][nt][r]);
          else
            ((float*)C)[(long)row * 128 + col] = acc[mt][nt][r] + bv;
        }
      }
    }
  }
}

// ---- CSR spmm: 4 waves/block, 1 row/wave, 4 edge-groups x 16 lanes x 8 feats, 2x unroll ----

__device__ __forceinline__ void fma_row(float* acc, float v, uint4 u) {
  acc[0] = fmaf(v, bflo(u.x), acc[0]);
  acc[1] = fmaf(v, bfhi(u.x), acc[1]);
  acc[2] = fmaf(v, bflo(u.y), acc[2]);
  acc[3] = fmaf(v, bfhi(u.y), acc[3]);
  acc[4] = fmaf(v, bflo(u.z), acc[4]);
  acc[5] = fmaf(v, bfhi(u.z), acc[5]);
  acc[6] = fmaf(v, bflo(u.w), acc[6]);
  acc[7] = fmaf(v, bfhi(u.w), acc[7]);
}

__global__ __launch_bounds__(256) void spmm_row_kernel(const int* __restrict__ offs,
                                                       const ull* __restrict__ edat,
                                                       const unsigned short* __restrict__ a,
                                                       const float* __restrict__ bias,
                                                       unsigned short* __restrict__ h,
                                                       const int* __restrict__ flag) {
  int wave = threadIdx.x >> 6;
  int lane = threadIdx.x & 63;
  int r = blockIdx.x * 4 + wave;           // grid = 25000, exact
  if (!flag[r]) return;                    // h1 row never read downstream
  int g = lane >> 4, l = lane & 15;
  int s = offs[r], e = offs[r + 1];
  float acc[8] = {0.f, 0.f, 0.f, 0.f, 0.f, 0.f, 0.f, 0.f};
  int j = s + g;
  for (; j + 4 < e; j += 8) {              // 2x unroll: 8 gathers in flight per wave
    ull p0 = edat[j];
    ull p1 = edat[j + 4];
    uint4 u0 = *(const uint4*)(a + (long)edge_col(p0) * 128 + l * 8);
    uint4 u1 = *(const uint4*)(a + (long)edge_col(p1) * 128 + l * 8);
    fma_row(acc, edge_val(p0), u0);
    fma_row(acc, edge_val(p1), u1);
  }
  if (j < e) {
    ull p = edat[j];
    uint4 u = *(const uint4*)(a + (long)edge_col(p) * 128 + l * 8);
    fma_row(acc, edge_val(p), u);
  }
#pragma unroll
  for (int k = 0; k < 8; ++k) {
    acc[k] += __shfl_xor(acc[k], 16);
    acc[k] += __shfl_xor(acc[k], 32);
  }
  if (g == 0) {
    float4 b0 = *(const float4*)(bias + l * 8);
    float4 b1 = *(const float4*)(bias + l * 8 + 4);
    uint4 o;
    o.x = packbf2(fmaxf(acc[0] + b0.x, 0.f), fmaxf(acc[1] + b0.y, 0.f));
    o.y = packbf2(fmaxf(acc[2] + b0.z, 0.f), fmaxf(acc[3] + b0.w, 0.f));
    o.z = packbf2(fmaxf(acc[4] + b1.x, 0.f), fmaxf(acc[5] + b1.y, 0.f));
    o.w = packbf2(fmaxf(acc[6] + b1.z, 0.f), fmaxf(acc[7] + b1.w, 0.f));
    *(uint4*)(h + (long)r * 128 + l * 8) = o;
  }
}

__global__ __launch_bounds__(256) void spmm_sel_kernel(const int* __restrict__ offs,
                                                       const ull* __restrict__ edat,
                                                       const unsigned short* __restrict__ h1,
                                                       const int* __restrict__ index,
                                                       float* __restrict__ g2) {
  int wave = threadIdx.x >> 6;
  int lane = threadIdx.x & 63;
  int b = blockIdx.x * 4 + wave;           // grid = 2048, exact
  int g = lane >> 4, l = lane & 15;
  int r = index[b];
  int s = offs[r], e = offs[r + 1];
  float acc[8] = {0.f, 0.f, 0.f, 0.f, 0.f, 0.f, 0.f, 0.f};
  int j = s + g;
  for (; j + 4 < e; j += 8) {
    ull p0 = edat[j];
    ull p1 = edat[j + 4];
    uint4 u0 = *(const uint4*)(h1 + (long)edge_col(p0) * 128 + l * 8);
    uint4 u1 = *(const uint4*)(h1 + (long)edge_col(p1) * 128 + l * 8);
    fma_row(acc, edge_val(p0), u0);
    fma_row(acc, edge_val(p1), u1);
  }
  if (j < e) {
    ull p = edat[j];
    uint4 u = *(const uint4*)(h1 + (long)edge_col(p) * 128 + l * 8);
    fma_row(acc, edge_val(p), u);
  }
#pragma unroll
  for (int k = 0; k < 8; ++k) {
    acc[k] += __shfl_xor(acc[k], 16);
    acc[k] += __shfl_xor(acc[k], 32);
  }
  if (g == 0) {
    float* op = g2 + (long)b * 128 + l * 8;
    *(float4*)(op + 0) = make_float4(acc[0], acc[1], acc[2], acc[3]);
    *(float4*)(op + 4) = make_float4(acc[4], acc[5], acc[6], acc[7]);
  }
}

// ---------------- final: z = concat(t, s) @ Wl + bl; log_softmax ----------------

__global__ __launch_bounds__(128) void final_kernel(const float* __restrict__ t,
                                                    const float* __restrict__ s,
                                                    const float* __restrict__ Wl,
                                                    const float* __restrict__ bl,
                                                    float* __restrict__ out) {
  int b = blockIdx.x * 128 + threadIdx.x;
  float z[16];
#pragma unroll
  for (int c = 0; c < 16; ++c) z[c] = bl[c];
  const float4* tb = (const float4*)(t + (long)b * 128);
#pragma unroll 4
  for (int k4 = 0; k4 < 32; ++k4) {
    float4 tv = tb[k4];
    const float* w = Wl + (k4 * 4) * 16;
#pragma unroll
    for (int c = 0; c < 16; ++c)
      z[c] += tv.x * w[c] + tv.y * w[16 + c] + tv.z * w[32 + c] + tv.w * w[48 + c];
  }
  const float4* sb = (const float4*)(s + (long)b * 64);
#pragma unroll 4
  for (int k4 = 0; k4 < 16; ++k4) {
    float4 sv = sb[k4];
    const float* w = Wl + (128 + k4 * 4) * 16;
#pragma unroll
    for (int c = 0; c < 16; ++c)
      z[c] += sv.x * w[c] + sv.y * w[16 + c] + sv.z * w[32 + c] + sv.w * w[48 + c];
  }
  float m = z[0];
#pragma unroll
  for (int c = 1; c < 16; ++c) m = fmaxf(m, z[c]);
  float sum = 0.f;
#pragma unroll
  for (int c = 0; c < 16; ++c) sum += expf(z[c] - m);
  float lse = m + logf(sum);
  float* ob = out + (long)b * 16;
#pragma unroll
  for (int c = 0; c < 16; ++c) ob[c] = z[c] - lse;
}

// ---------------- launch ----------------

extern "C" void kernel_launch(void* const* d_in, const int* in_sizes, int n_in,
                              void* d_out, int out_size, void* d_ws, size_t ws_size,
                              hipStream_t stream) {
  const float* s_in  = (const float*)d_in[0];
  const float* x     = (const float*)d_in[1];
  const int*   row   = (const int*)d_in[2];
  const int*   col   = (const int*)d_in[3];
  const float* val   = (const float*)d_in[4];
  const int*   index = (const int*)d_in[5];
  const float* W1    = (const float*)d_in[6];
  const float* b1    = (const float*)d_in[7];
  const float* W2    = (const float*)d_in[8];
  const float* b2    = (const float*)d_in[9];
  const float* Wl    = (const float*)d_in[10];
  const float* bl    = (const float*)d_in[11];
  float* out = (float*)d_out;

  // workspace carve (~86 MB), 8B-aligned first
  ull* edat  = (ull*)d_ws;                                           // [1.6M] final CSR edges
  ull* ebuf1 = edat + N_EDGES;                                       // [1.6M] binA out / binC fallback
  unsigned short* a  = (unsigned short*)(ebuf1 + N_EDGES);           // xW1 bf16   [100000,128]
  unsigned short* h1 = a + (size_t)N_NODES * 128;                    // layer1 bf16[100000,128]
  float* g2   = (float*)(h1 + (size_t)N_NODES * 128);                // sel spmm   [8192,128]
  float* tmat = g2 + (size_t)BB * 128;                               // g2@W2+b2   [8192,128]
  int* flag   = (int*)(tmat + (size_t)BB * 128);                     // [100000] needed-row mask
  int* subcnt = flag + N_NODES;                                      // [3125] (memset with flag)
  int* offs   = subcnt + NSUB;                                       // [100001] (binC writes)
  int* sub_offs = offs + (N_NODES + 1);                              // [3126]
  int* gcur1  = sub_offs + (NSUB + 1);                               // [49]
  int* gcur2  = gcur1 + NB1;                                         // [3125]
  uint* Wt1   = (uint*)(gcur2 + NSUB);                               // [8192] W1 bf16 [n][k]
  uint* Wt2   = Wt1 + 8192;                                          // [8192] W2 bf16 [n][k]

  hipMemsetAsync(flag, 0, (N_NODES + NSUB) * sizeof(int), stream);   // flag + subcnt

  histsub_kernel<<<HWG, 256, 0, stream>>>(row, subcnt);
  scanall_kernel<<<1, 1024, 0, stream>>>(subcnt, sub_offs, gcur1, gcur2);

  binA_kernel<<<512, 256, 0, stream>>>(row, col, val, gcur1, ebuf1);
  binB_kernel<<<NB1 * 8, 256, 0, stream>>>(ebuf1, sub_offs, gcur2, edat);
  binC_kernel<<<NSUB, 256, 0, stream>>>(sub_offs, edat, ebuf1, offs);
  mask_kernel<<<BB / 256, 256, 0, stream>>>(offs, edat, index, flag);

  wconv2_kernel<<<64, 256, 0, stream>>>(W1, W2, Wt1, Wt2);

  mfma_gemm_kernel<1><<<(N_NODES + 63) / 64, 256, 0, stream>>>(x, Wt1, nullptr, a, N_NODES);
  spmm_row_kernel<<<N_NODES / 4, 256, 0, stream>>>(offs, edat, a, b1, h1, flag);
  spmm_sel_kernel<<<BB / 4, 256, 0, stream>>>(offs, edat, h1, index, g2);
  mfma_gemm_kernel<0><<<BB / 64, 256, 0, stream>>>(g2, Wt2, b2, tmat, BB);
  final_kernel<<<BB / 128, 128, 0, stream>>>(tmat, s_in, Wl, bl, out);
}

// Round 10
// 307.104 us; speedup vs baseline: 1.6890x; 1.0365x over previous
//
#include <hip/hip_runtime.h>
#include <math.h>

#define N_NODES 100000
#define N_EDGES 1600000
#define NFEAT 128
#define NHID 128
#define NS 64
#define NCLASS 16
#define BB 8192

// binned CSR build geometry
#define B1_SHIFT 11               // 2048 rows per L1 bucket
#define NB1 49                    // ceil(100000 / 2048)
#define SUB_SHIFT 5               // 32 rows per sub-bucket
#define NSUB 3125                 // 100000 / 32
#define CHUNKA 2048               // edges per block-iteration in bin passes
#define HWG 256                   // histogram workgroups
#define BINC_CAP 2048             // LDS edge capacity in binC

typedef unsigned long long ull;
typedef unsigned int uint;

// ---------------- bf16 helpers ----------------

__device__ __forceinline__ unsigned short f2bf(float f) {
  unsigned int u = __float_as_uint(f);
  return (unsigned short)((u + 0x7fffu + ((u >> 16) & 1u)) >> 16);  // RNE
}
__device__ __forceinline__ float bflo(unsigned int u) {
  return __uint_as_float(u << 16);
}
__device__ __forceinline__ float bfhi(unsigned int u) {
  return __uint_as_float(u & 0xffff0000u);
}
__device__ __forceinline__ unsigned int packbf2(float lo, float hi) {
  return (unsigned int)f2bf(lo) | ((unsigned int)f2bf(hi) << 16);
}

// ---------------- edge packing: [63:34]=val[31:2], [33:17]=row, [16:0]=col ----------------

__device__ __forceinline__ ull pack_edge(float v, int r, int c) {
  return ((ull)(__float_as_uint(v) >> 2) << 34) | ((ull)(unsigned)r << 17) | (unsigned)c;
}
__device__ __forceinline__ int edge_col(ull p) { return (int)(p & 0x1FFFFu); }
__device__ __forceinline__ int edge_row(ull p) { return (int)((unsigned)(p >> 17) & 0x1FFFFu); }
__device__ __forceinline__ float edge_val(ull p) {
  return __uint_as_float(((unsigned)(p >> 34)) << 2);
}

// ---------------- selection mask chain (pre-binning, COO-based) ----------------

__global__ __launch_bounds__(256) void selbuild_kernel(const int* __restrict__ index,
                                                       int* __restrict__ sel) {
  int t = blockIdx.x * 256 + threadIdx.x;  // 8192 exactly
  sel[index[t]] = 1;
}

__global__ __launch_bounds__(256) void selflag_kernel(const int* __restrict__ row,
                                                      const int* __restrict__ col,
                                                      const int* __restrict__ sel,
                                                      int* __restrict__ flag) {
  int i = blockIdx.x * blockDim.x + threadIdx.x;
  int stride = gridDim.x * blockDim.x;
  for (; i < N_EDGES; i += stride)
    if (sel[row[i]]) flag[col[i]] = 1;
}

__global__ __launch_bounds__(256) void keepbits_kernel(const int* __restrict__ flag,
                                                       const int* __restrict__ sel,
                                                       uint* __restrict__ keepbits) {
  int t = blockIdx.x * 256 + threadIdx.x;
  if (t >= NSUB) return;
  uint w = 0;
  int base = t * 32;
#pragma unroll
  for (int k = 0; k < 32; ++k) {
    int r = base + k;
    if (r < N_NODES && (flag[r] | sel[r])) w |= (1u << k);
  }
  keepbits[t] = w;
}

// ---------------- sub-bucket histogram (3125 bins, LDS-privatized, keep-gated) ------

__global__ __launch_bounds__(256) void histsub_kernel(const int* __restrict__ row,
                                                      const uint* __restrict__ keepbits,
                                                      int* __restrict__ subcnt) {
  __shared__ int lh[NSUB];
  int tid = threadIdx.x;
  for (int i = tid; i < NSUB; i += 256) lh[i] = 0;
  __syncthreads();
  for (long i = (long)blockIdx.x * 256 + tid; i < N_EDGES; i += (long)HWG * 256) {
    int r = row[i];
    if ((keepbits[r >> 5] >> (r & 31)) & 1u) atomicAdd(&lh[r >> SUB_SHIFT], 1);
  }
  __syncthreads();
  for (int i = tid; i < NSUB; i += 256) {
    int c = lh[i];
    if (c) atomicAdd(&subcnt[i], c);
  }
}

// ---------------- scan of 3125 sub-bucket counts -> sub_offs, gcur1, gcur2 (1 WG) ----

__global__ __launch_bounds__(1024) void scanall_kernel(const int* __restrict__ subcnt,
                                                       int* __restrict__ sub_offs,
                                                       int* __restrict__ gcur1,
                                                       int* __restrict__ gcur2) {
  __shared__ int sd[1024];
  int tid = threadIdx.x;
  int b0 = tid * 4;
  int vv[4];
  int loc = 0;
#pragma unroll
  for (int k = 0; k < 4; ++k) {
    int i = b0 + k;
    vv[k] = (i < NSUB) ? subcnt[i] : 0;
    loc += vv[k];
  }
  sd[tid] = loc;
  __syncthreads();
  for (int o = 1; o < 1024; o <<= 1) {
    int add = (tid >= o) ? sd[tid - o] : 0;
    __syncthreads();
    sd[tid] += add;
    __syncthreads();
  }
  int pre = sd[tid] - loc;
#pragma unroll
  for (int k = 0; k < 4; ++k) {
    int i = b0 + k;
    if (i < NSUB) {
      sub_offs[i] = pre;
      gcur2[i] = pre;
      if ((i & 63) == 0) gcur1[i >> 6] = pre;
      pre += vv[k];
    }
  }
  if (tid == 1023) sub_offs[NSUB] = sd[1023];
}

// ---- pass A: kept edges -> 49 L1 bucket regions (bkt-array unstage, no binary search) ----

__global__ __launch_bounds__(256) void binA_kernel(const int* __restrict__ row,
                                                   const int* __restrict__ col,
                                                   const float* __restrict__ val,
                                                   const uint* __restrict__ keepbits,
                                                   int* __restrict__ gcur1,
                                                   ull* __restrict__ ebuf1) {
  __shared__ ull stage[CHUNKA];          // 16 KB
  __shared__ short bkt[CHUNKA];          // 4 KB
  __shared__ int hist[NB1], lofs[NB1 + 1], lcur[NB1], gbase[NB1];
  int tid = threadIdx.x;
  for (long base = (long)blockIdx.x * CHUNKA; base < N_EDGES; base += (long)gridDim.x * CHUNKA) {
    int cnt = (int)min((long)CHUNKA, (long)N_EDGES - base);
    if (tid < NB1) hist[tid] = 0;
    __syncthreads();
    ull e[8]; int bk[8];
#pragma unroll
    for (int v = 0; v < 8; ++v) {
      int i = v * 256 + tid;
      bk[v] = -1;
      if (i < cnt) {
        long g = base + i;
        int r = row[g];
        if ((keepbits[r >> 5] >> (r & 31)) & 1u) {
          e[v] = pack_edge(val[g], r, col[g]);
          bk[v] = r >> B1_SHIFT;
          atomicAdd(&hist[bk[v]], 1);
        }
      }
    }
    __syncthreads();
    if (tid < 64) {
      int h = (tid < NB1) ? hist[tid] : 0;
      int x = h;
      for (int o = 1; o < 64; o <<= 1) {
        int y = __shfl_up(x, o);
        if (tid >= o) x += y;
      }
      if (tid < NB1) { lofs[tid] = x - h; lcur[tid] = x - h; }
      if (tid == 63) lofs[NB1] = x;  // kept count in chunk
    }
    __syncthreads();
#pragma unroll
    for (int v = 0; v < 8; ++v) {
      if (bk[v] >= 0) {
        int pos = atomicAdd(&lcur[bk[v]], 1);
        stage[pos] = e[v];
        bkt[pos] = (short)bk[v];
      }
    }
    __syncthreads();
    if (tid < NB1) {
      int h = hist[tid];
      if (h > 0) gbase[tid] = atomicAdd(&gcur1[tid], h);
    }
    __syncthreads();
    int tot = lofs[NB1];
    for (int s = tid; s < tot; s += 256) {
      int lo = bkt[s];
      ebuf1[gbase[lo] + (s - lofs[lo])] = stage[s];
    }
    __syncthreads();
  }
}

// ---------------- pass B: L1 bucket -> 64 sub-bucket regions (bkt-array unstage) ------

__global__ __launch_bounds__(256) void binB_kernel(const ull* __restrict__ ebuf1,
                                                   const int* __restrict__ sub_offs,
                                                   int* __restrict__ gcur2,
                                                   ull* __restrict__ edat) {
  __shared__ ull stage[CHUNKA];          // 16 KB
  __shared__ short bkt[CHUNKA];          // 4 KB
  __shared__ int hist[64], lofs[65], lcur[64], gbase[64];
  int tid = threadIdx.x;
  int b1 = blockIdx.x >> 3, w = blockIdx.x & 7;
  int rbeg = sub_offs[b1 << 6];
  int rend = sub_offs[min((b1 + 1) << 6, NSUB)];
  for (int base = rbeg + w * CHUNKA; base < rend; base += 8 * CHUNKA) {
    int cnt = min(CHUNKA, rend - base);
    if (tid < 64) hist[tid] = 0;
    __syncthreads();
    ull e[8]; int bk[8];
#pragma unroll
    for (int v = 0; v < 8; ++v) {
      int i = v * 256 + tid;
      bk[v] = -1;
      if (i < cnt) {
        e[v] = ebuf1[base + i];
        bk[v] = (edge_row(e[v]) >> SUB_SHIFT) - (b1 << 6);
        atomicAdd(&hist[bk[v]], 1);
      }
    }
    __syncthreads();
    if (tid < 64) {
      int h = hist[tid];
      int x = h;
      for (int o = 1; o < 64; o <<= 1) {
        int y = __shfl_up(x, o);
        if (tid >= o) x += y;
      }
      lofs[tid] = x - h;
      lcur[tid] = x - h;
      if (tid == 63) lofs[64] = x;  // == cnt
    }
    __syncthreads();
#pragma unroll
    for (int v = 0; v < 8; ++v) {
      if (bk[v] >= 0) {
        int pos = atomicAdd(&lcur[bk[v]], 1);
        stage[pos] = e[v];
        bkt[pos] = (short)bk[v];
      }
    }
    __syncthreads();
    if (tid < 64) {
      int h = hist[tid];
      if (h > 0) gbase[tid] = atomicAdd(&gcur2[(b1 << 6) + tid], h);
    }
    __syncthreads();
    for (int s = tid; s < cnt; s += 256) {
      int lo = bkt[s];
      edat[gbase[lo] + (s - lofs[lo])] = stage[s];
    }
    __syncthreads();
  }
}

// ---- pass C: exact row placement within each 32-row sub-bucket (LDS-staged); emits offs ----

__global__ __launch_bounds__(256) void binC_kernel(const int* __restrict__ sub_offs,
                                                   ull* __restrict__ edat,
                                                   ull* __restrict__ ebuf1,
                                                   int* __restrict__ offs) {
  __shared__ ull es[BINC_CAP];           // 16 KB
  __shared__ int rcnt[32], rcur[32];
  int s = blockIdx.x, tid = threadIdx.x;
  int r0 = s << SUB_SHIFT;
  int beg = sub_offs[s], end = sub_offs[s + 1];
  int n = end - beg;
  if (tid < 32) rcnt[tid] = 0;
  __syncthreads();
  if (n <= BINC_CAP) {
    for (int i = tid; i < n; i += 256) {
      ull p = edat[beg + i];
      es[i] = p;
      atomicAdd(&rcnt[edge_row(p) & 31], 1);
    }
    __syncthreads();
    if (tid < 32) {
      int h = rcnt[tid];
      int x = h;
      for (int o = 1; o < 32; o <<= 1) {
        int y = __shfl_up(x, o, 32);
        if (tid >= o) x += y;
      }
      rcur[tid] = x - h;
      offs[r0 + tid] = beg + x - h;
      if (s == NSUB - 1 && tid == 31) offs[N_NODES] = end;
    }
    __syncthreads();
    for (int i = tid; i < n; i += 256) {
      ull p = es[i];
      int pos = atomicAdd(&rcur[edge_row(p) & 31], 1);
      edat[beg + pos] = p;
    }
  } else {  // fallback: global scratch (statistically never at mean ~390)
    for (int i = tid; i < n; i += 256) {
      ull p = edat[beg + i];
      ebuf1[beg + i] = p;
      atomicAdd(&rcnt[edge_row(p) & 31], 1);
    }
    __syncthreads();
    if (tid < 32) {
      int h = rcnt[tid];
      int x = h;
      for (int o = 1; o < 32; o <<= 1) {
        int y = __shfl_up(x, o, 32);
        if (tid >= o) x += y;
      }
      rcur[tid] = x - h;
      offs[r0 + tid] = beg + x - h;
      if (s == NSUB - 1 && tid == 31) offs[N_NODES] = end;
    }
    __syncthreads();
    for (int i = tid; i < n; i += 256) {
      ull p = ebuf1[beg + i];
      int pos = atomicAdd(&rcur[edge_row(p) & 31], 1);
      edat[beg + pos] = p;
    }
  }
}

// ------ weight convert (both): W fp32 [k][n] -> Wt bf16-packed uint [n][k/2] ----------

__global__ __launch_bounds__(256) void wconv2_kernel(const float* __restrict__ W1,
                                                     const float* __restrict__ W2,
                                                     uint* __restrict__ Wt1,
                                                     uint* __restrict__ Wt2) {
  int blk = blockIdx.x;                       // 64 blocks: 0-31 -> W1, 32-63 -> W2
  const float* W = (blk < 32) ? W1 : W2;
  uint* Wt = (blk < 32) ? Wt1 : Wt2;
  int idx = (blk & 31) * 256 + threadIdx.x;   // 0..8191
  int n = idx >> 6, kc = idx & 63;
  float lo = W[(2 * kc) * 128 + n];
  float hi = W[(2 * kc + 1) * 128 + n];
  Wt[idx] = packbf2(lo, hi);
}

// ---------------- MFMA GEMM: C[nr,128] = A[nr,128] @ W[128,128] (+bias) ----------------

typedef __attribute__((ext_vector_type(8))) __bf16 bf16x8;
typedef __attribute__((ext_vector_type(4))) float f32x4;
union FragU { uint4 u; bf16x8 b; };

#define LDSTR 68   // uints per 128-feat row in LDS

template <int OUT_BF16>
__global__ __launch_bounds__(256) void mfma_gemm_kernel(const float* __restrict__ A,
                                                        const uint* __restrict__ Wt_g,
                                                        const float* __restrict__ bias,
                                                        void* __restrict__ C,
                                                        int nrows) {
  __shared__ uint As_s[64 * LDSTR];    // 17.4 KB
  __shared__ uint Wt_s[128 * LDSTR];   // 34.8 KB
  int tid = threadIdx.x;
  int rbase = blockIdx.x * 64;

  {
    const uint2* src = (const uint2*)Wt_g;
#pragma unroll
    for (int i = 0; i < 16; ++i) {
      int j = i * 256 + tid;
      int n = j >> 5, c2 = (j & 31) * 2;
      uint2 v = src[j];
      Wt_s[n * LDSTR + c2] = v.x;
      Wt_s[n * LDSTR + c2 + 1] = v.y;
    }
  }
  {
    const float4* src = (const float4*)(A + (long)rbase * 128);
#pragma unroll
    for (int i = 0; i < 8; ++i) {
      int f = i * 256 + tid;
      int m = f >> 5;
      float4 v = (rbase + m < nrows) ? src[f] : make_float4(0.f, 0.f, 0.f, 0.f);
      int c = (f & 31) * 2;
      As_s[m * LDSTR + c]     = packbf2(v.x, v.y);
      As_s[m * LDSTR + c + 1] = packbf2(v.z, v.w);
    }
  }
  __syncthreads();

  int w = tid >> 6, lane = tid & 63;
  int quad = lane >> 4, lr = lane & 15;
  int n0 = w * 32;

  f32x4 acc[4][2];
#pragma unroll
  for (int mt = 0; mt < 4; ++mt)
#pragma unroll
    for (int nt = 0; nt < 2; ++nt) acc[mt][nt] = (f32x4){0.f, 0.f, 0.f, 0.f};

#pragma unroll
  for (int kk = 0; kk < 4; ++kk) {
    int kc = kk * 16 + quad * 4;
    FragU fb0, fb1;
    fb0.u = *(const uint4*)&Wt_s[(n0 + lr) * LDSTR + kc];
    fb1.u = *(const uint4*)&Wt_s[(n0 + 16 + lr) * LDSTR + kc];
#pragma unroll
    for (int mt = 0; mt < 4; ++mt) {
      FragU fa;
      fa.u = *(const uint4*)&As_s[(mt * 16 + lr) * LDSTR + kc];
      acc[mt][0] = __builtin_amdgcn_mfma_f32_16x16x32_bf16(fa.b, fb0.b, acc[mt][0], 0, 0, 0);
      acc[mt][1] = __builtin_amdgcn_mfma_f32_16x16x32_bf16(fa.b, fb1.b, acc[mt][1], 0, 0, 0);
    }
  }

#pragma unroll
  for (int mt = 0; mt < 4; ++mt) {
#pragma unroll
    for (int nt = 0; nt < 2; ++nt) {
      int col = n0 + nt * 16 + lr;
      float bv = OUT_BF16 ? 0.f : bias[col];
#pragma unroll
      for (int r = 0; r < 4; ++r) {
        int row = rbase + mt * 16 + quad * 4 + r;
        if (row < nrows) {
          if (OUT_BF16)
            ((unsigned short*)C)[(long)row * 128 + col] = f2bf(acc[mt][nt][r]);
          else
            ((float*)C)[(long)row * 128 + col] = acc[mt][nt][r] + bv;
        }
      }
    }
  }
}

// ---- CSR spmm: 4 waves/block, 1 row/wave, 4 edge-groups x 16 lanes x 8 feats, 2x unroll ----

__device__ __forceinline__ void fma_row(float* acc, float v, uint4 u) {
  acc[0] = fmaf(v, bflo(u.x), acc[0]);
  acc[1] = fmaf(v, bfhi(u.x), acc[1]);
  acc[2] = fmaf(v, bflo(u.y), acc[2]);
  acc[3] = fmaf(v, bfhi(u.y), acc[3]);
  acc[4] = fmaf(v, bflo(u.z), acc[4]);
  acc[5] = fmaf(v, bfhi(u.z), acc[5]);
  acc[6] = fmaf(v, bflo(u.w), acc[6]);
  acc[7] = fmaf(v, bfhi(u.w), acc[7]);
}

__global__ __launch_bounds__(256) void spmm_row_kernel(const int* __restrict__ offs,
                                                       const ull* __restrict__ edat,
                                                       const unsigned short* __restrict__ a,
                                                       const float* __restrict__ bias,
                                                       unsigned short* __restrict__ h,
                                                       const int* __restrict__ flag) {
  int wave = threadIdx.x >> 6;
  int lane = threadIdx.x & 63;
  int r = blockIdx.x * 4 + wave;           // grid = 25000, exact
  if (!flag[r]) return;
  int g = lane >> 4, l = lane & 15;
  int s = offs[r], e = offs[r + 1];
  float acc[8] = {0.f, 0.f, 0.f, 0.f, 0.f, 0.f, 0.f, 0.f};
  int j = s + g;
  for (; j + 4 < e; j += 8) {
    ull p0 = edat[j];
    ull p1 = edat[j + 4];
    uint4 u0 = *(const uint4*)(a + (long)edge_col(p0) * 128 + l * 8);
    uint4 u1 = *(const uint4*)(a + (long)edge_col(p1) * 128 + l * 8);
    fma_row(acc, edge_val(p0), u0);
    fma_row(acc, edge_val(p1), u1);
  }
  if (j < e) {
    ull p = edat[j];
    uint4 u = *(const uint4*)(a + (long)edge_col(p) * 128 + l * 8);
    fma_row(acc, edge_val(p), u);
  }
#pragma unroll
  for (int k = 0; k < 8; ++k) {
    acc[k] += __shfl_xor(acc[k], 16);
    acc[k] += __shfl_xor(acc[k], 32);
  }
  if (g == 0) {
    float4 b0 = *(const float4*)(bias + l * 8);
    float4 b1 = *(const float4*)(bias + l * 8 + 4);
    uint4 o;
    o.x = packbf2(fmaxf(acc[0] + b0.x, 0.f), fmaxf(acc[1] + b0.y, 0.f));
    o.y = packbf2(fmaxf(acc[2] + b0.z, 0.f), fmaxf(acc[3] + b0.w, 0.f));
    o.z = packbf2(fmaxf(acc[4] + b1.x, 0.f), fmaxf(acc[5] + b1.y, 0.f));
    o.w = packbf2(fmaxf(acc[6] + b1.z, 0.f), fmaxf(acc[7] + b1.w, 0.f));
    *(uint4*)(h + (long)r * 128 + l * 8) = o;
  }
}

__global__ __launch_bounds__(256) void spmm_sel_kernel(const int* __restrict__ offs,
                                                       const ull* __restrict__ edat,
                                                       const unsigned short* __restrict__ h1,
                                                       const int* __restrict__ index,
                                                       float* __restrict__ g2) {
  int wave = threadIdx.x >> 6;
  int lane = threadIdx.x & 63;
  int b = blockIdx.x * 4 + wave;           // grid = 2048, exact
  int g = lane >> 4, l = lane & 15;
  int r = index[b];
  int s = offs[r], e = offs[r + 1];
  float acc[8] = {0.f, 0.f, 0.f, 0.f, 0.f, 0.f, 0.f, 0.f};
  int j = s + g;
  for (; j + 4 < e; j += 8) {
    ull p0 = edat[j];
    ull p1 = edat[j + 4];
    uint4 u0 = *(const uint4*)(h1 + (long)edge_col(p0) * 128 + l * 8);
    uint4 u1 = *(const uint4*)(h1 + (long)edge_col(p1) * 128 + l * 8);
    fma_row(acc, edge_val(p0), u0);
    fma_row(acc, edge_val(p1), u1);
  }
  if (j < e) {
    ull p = edat[j];
    uint4 u = *(const uint4*)(h1 + (long)edge_col(p) * 128 + l * 8);
    fma_row(acc, edge_val(p), u);
  }
#pragma unroll
  for (int k = 0; k < 8; ++k) {
    acc[k] += __shfl_xor(acc[k], 16);
    acc[k] += __shfl_xor(acc[k], 32);
  }
  if (g == 0) {
    float* op = g2 + (long)b * 128 + l * 8;
    *(float4*)(op + 0) = make_float4(acc[0], acc[1], acc[2], acc[3]);
    *(float4*)(op + 4) = make_float4(acc[4], acc[5], acc[6], acc[7]);
  }
}

// ---------------- final: z = concat(t, s) @ Wl + bl; log_softmax ----------------

__global__ __launch_bounds__(128) void final_kernel(const float* __restrict__ t,
                                                    const float* __restrict__ s,
                                                    const float* __restrict__ Wl,
                                                    const float* __restrict__ bl,
                                                    float* __restrict__ out) {
  int b = blockIdx.x * 128 + threadIdx.x;
  float z[16];
#pragma unroll
  for (int c = 0; c < 16; ++c) z[c] = bl[c];
  const float4* tb = (const float4*)(t + (long)b * 128);
#pragma unroll 4
  for (int k4 = 0; k4 < 32; ++k4) {
    float4 tv = tb[k4];
    const float* w = Wl + (k4 * 4) * 16;
#pragma unroll
    for (int c = 0; c < 16; ++c)
      z[c] += tv.x * w[c] + tv.y * w[16 + c] + tv.z * w[32 + c] + tv.w * w[48 + c];
  }
  const float4* sb = (const float4*)(s + (long)b * 64);
#pragma unroll 4
  for (int k4 = 0; k4 < 16; ++k4) {
    float4 sv = sb[k4];
    const float* w = Wl + (128 + k4 * 4) * 16;
#pragma unroll
    for (int c = 0; c < 16; ++c)
      z[c] += sv.x * w[c] + sv.y * w[16 + c] + sv.z * w[32 + c] + sv.w * w[48 + c];
  }
  float m = z[0];
#pragma unroll
  for (int c = 1; c < 16; ++c) m = fmaxf(m, z[c]);
  float sum = 0.f;
#pragma unroll
  for (int c = 0; c < 16; ++c) sum += expf(z[c] - m);
  float lse = m + logf(sum);
  float* ob = out + (long)b * 16;
#pragma unroll
  for (int c = 0; c < 16; ++c) ob[c] = z[c] - lse;
}

// ---------------- launch ----------------

extern "C" void kernel_launch(void* const* d_in, const int* in_sizes, int n_in,
                              void* d_out, int out_size, void* d_ws, size_t ws_size,
                              hipStream_t stream) {
  const float* s_in  = (const float*)d_in[0];
  const float* x     = (const float*)d_in[1];
  const int*   row   = (const int*)d_in[2];
  const int*   col   = (const int*)d_in[3];
  const float* val   = (const float*)d_in[4];
  const int*   index = (const int*)d_in[5];
  const float* W1    = (const float*)d_in[6];
  const float* b1    = (const float*)d_in[7];
  const float* W2    = (const float*)d_in[8];
  const float* b2    = (const float*)d_in[9];
  const float* Wl    = (const float*)d_in[10];
  const float* bl    = (const float*)d_in[11];
  float* out = (float*)d_out;

  // workspace carve (~87 MB), 8B-aligned first
  ull* edat  = (ull*)d_ws;                                           // [1.6M] final CSR edges
  ull* ebuf1 = edat + N_EDGES;                                       // [1.6M] binA out / binC fallback
  unsigned short* a  = (unsigned short*)(ebuf1 + N_EDGES);           // xW1 bf16   [100000,128]
  unsigned short* h1 = a + (size_t)N_NODES * 128;                    // layer1 bf16[100000,128]
  float* g2   = (float*)(h1 + (size_t)N_NODES * 128);                // sel spmm   [8192,128]
  float* tmat = g2 + (size_t)BB * 128;                               // g2@W2+b2   [8192,128]
  int* flag   = (int*)(tmat + (size_t)BB * 128);                     // [100000] needed-row mask
  int* sel    = flag + N_NODES;                                      // [100000] selected-row mask
  int* subcnt = sel + N_NODES;                                       // [3125]
  int* offs   = subcnt + NSUB;                                       // [100001] (binC writes)
  int* sub_offs = offs + (N_NODES + 1);                              // [3126]
  int* gcur1  = sub_offs + (NSUB + 1);                               // [49]
  int* gcur2  = gcur1 + NB1;                                         // [3125]
  uint* keepbits = (uint*)(gcur2 + NSUB);                            // [3125] 12.5 KB bitmask
  uint* Wt1   = keepbits + NSUB;                                     // [8192] W1 bf16 [n][k]
  uint* Wt2   = Wt1 + 8192;                                          // [8192] W2 bf16 [n][k]

  hipMemsetAsync(flag, 0, (2 * N_NODES + NSUB) * sizeof(int), stream);  // flag+sel+subcnt

  selbuild_kernel<<<BB / 256, 256, 0, stream>>>(index, sel);
  selflag_kernel<<<4096, 256, 0, stream>>>(row, col, sel, flag);
  keepbits_kernel<<<(NSUB + 255) / 256, 256, 0, stream>>>(flag, sel, keepbits);

  histsub_kernel<<<HWG, 256, 0, stream>>>(row, keepbits, subcnt);
  scanall_kernel<<<1, 1024, 0, stream>>>(subcnt, sub_offs, gcur1, gcur2);

  binA_kernel<<<512, 256, 0, stream>>>(row, col, val, keepbits, gcur1, ebuf1);
  binB_kernel<<<NB1 * 8, 256, 0, stream>>>(ebuf1, sub_offs, gcur2, edat);
  binC_kernel<<<NSUB, 256, 0, stream>>>(sub_offs, edat, ebuf1, offs);

  wconv2_kernel<<<64, 256, 0, stream>>>(W1, W2, Wt1, Wt2);

  mfma_gemm_kernel<1><<<(N_NODES + 63) / 64, 256, 0, stream>>>(x, Wt1, nullptr, a, N_NODES);
  spmm_row_kernel<<<N_NODES / 4, 256, 0, stream>>>(offs, edat, a, b1, h1, flag);
  spmm_sel_kernel<<<BB / 4, 256, 0, stream>>>(offs, edat, h1, index, g2);
  mfma_gemm_kernel<0><<<BB / 64, 256, 0, stream>>>(g2, Wt2, b2, tmat, BB);
  final_kernel<<<BB / 128, 128, 0, stream>>>(tmat, s_in, Wl, bl, out);
}

// Round 12
// 299.165 us; speedup vs baseline: 1.7338x; 1.0265x over previous
//
#include <hip/hip_runtime.h>
#include <math.h>

#define N_NODES 100000
#define N_EDGES 1600000
#define NFEAT 128
#define NHID 128
#define NS 64
#define NCLASS 16
#define BB 8192

// binned CSR build geometry
#define B1_SHIFT 11               // 2048 rows per L1 bucket
#define NB1 49                    // ceil(100000 / 2048)
#define SUB_SHIFT 5               // 32 rows per sub-bucket
#define NSUB 3125                 // 100000 / 32
#define CHUNKA 2048               // edges per block-iteration in bin passes (R10-proven)
#define HWG 256                   // histogram workgroups
#define BINC_CAP 2048             // LDS edge capacity in binC

typedef unsigned long long ull;
typedef unsigned int uint;

// ---------------- bf16 helpers ----------------

__device__ __forceinline__ unsigned short f2bf(float f) {
  unsigned int u = __float_as_uint(f);
  return (unsigned short)((u + 0x7fffu + ((u >> 16) & 1u)) >> 16);  // RNE
}
__device__ __forceinline__ float bflo(unsigned int u) {
  return __uint_as_float(u << 16);
}
__device__ __forceinline__ float bfhi(unsigned int u) {
  return __uint_as_float(u & 0xffff0000u);
}
__device__ __forceinline__ unsigned int packbf2(float lo, float hi) {
  return (unsigned int)f2bf(lo) | ((unsigned int)f2bf(hi) << 16);
}

// ---------------- edge packing: [63:34]=val[31:2], [33:17]=row, [16:0]=col ----------------

__device__ __forceinline__ ull pack_edge(float v, int r, int c) {
  return ((ull)(__float_as_uint(v) >> 2) << 34) | ((ull)(unsigned)r << 17) | (unsigned)c;
}
__device__ __forceinline__ int edge_col(ull p) { return (int)(p & 0x1FFFFu); }
__device__ __forceinline__ int edge_row(ull p) { return (int)((unsigned)(p >> 17) & 0x1FFFFu); }
__device__ __forceinline__ float edge_val(ull p) {
  return __uint_as_float(((unsigned)(p >> 34)) << 2);
}
__device__ __forceinline__ int keep_test(const uint* keep, int r) {
  return (keep[r >> 5] >> (r & 31)) & 1u;
}

// ---------------- selection masks: sel[] + keep bitmask (flag|sel) ----------------

__global__ __launch_bounds__(256) void selbuild_kernel(const int* __restrict__ index,
                                                       int* __restrict__ sel,
                                                       uint* __restrict__ keep) {
  int t = blockIdx.x * 256 + threadIdx.x;  // 8192 exactly
  int r = index[t];
  sel[r] = 1;
  atomicOr(&keep[r >> 5], 1u << (r & 31));
}

__global__ __launch_bounds__(256) void selflag_kernel(const int* __restrict__ row,
                                                      const int* __restrict__ col,
                                                      const int* __restrict__ sel,
                                                      uint* __restrict__ keep) {
  int i = blockIdx.x * blockDim.x + threadIdx.x;
  int stride = gridDim.x * blockDim.x;
  for (; i < N_EDGES; i += stride)
    if (sel[row[i]]) {
      int c = col[i];
      atomicOr(&keep[c >> 5], 1u << (c & 31));
    }
}

// ---------------- sub-bucket histogram (3125 bins, LDS-privatized, keep-gated) ------

__global__ __launch_bounds__(256) void histsub_kernel(const int* __restrict__ row,
                                                      const uint* __restrict__ keep,
                                                      int* __restrict__ subcnt) {
  __shared__ int lh[NSUB];
  int tid = threadIdx.x;
  for (int i = tid; i < NSUB; i += 256) lh[i] = 0;
  __syncthreads();
  for (long i = (long)blockIdx.x * 256 + tid; i < N_EDGES; i += (long)HWG * 256) {
    int r = row[i];
    if (keep_test(keep, r)) atomicAdd(&lh[r >> SUB_SHIFT], 1);
  }
  __syncthreads();
  for (int i = tid; i < NSUB; i += 256) {
    int c = lh[i];
    if (c) atomicAdd(&subcnt[i], c);
  }
}

// ---------------- scan of 3125 sub-bucket counts -> sub_offs, gcur1, gcur2 (1 WG) ----

__global__ __launch_bounds__(1024) void scanall_kernel(const int* __restrict__ subcnt,
                                                       int* __restrict__ sub_offs,
                                                       int* __restrict__ gcur1,
                                                       int* __restrict__ gcur2) {
  __shared__ int sd[1024];
  int tid = threadIdx.x;
  int b0 = tid * 4;
  int vv[4];
  int loc = 0;
#pragma unroll
  for (int k = 0; k < 4; ++k) {
    int i = b0 + k;
    vv[k] = (i < NSUB) ? subcnt[i] : 0;
    loc += vv[k];
  }
  sd[tid] = loc;
  __syncthreads();
  for (int o = 1; o < 1024; o <<= 1) {
    int add = (tid >= o) ? sd[tid - o] : 0;
    __syncthreads();
    sd[tid] += add;
    __syncthreads();
  }
  int pre = sd[tid] - loc;
#pragma unroll
  for (int k = 0; k < 4; ++k) {
    int i = b0 + k;
    if (i < NSUB) {
      sub_offs[i] = pre;
      gcur2[i] = pre;
      if ((i & 63) == 0) gcur1[i >> 6] = pre;
      pre += vv[k];
    }
  }
  if (tid == 1023) sub_offs[NSUB] = sd[1023];
}

// ---- pass A: kept edges -> 49 L1 bucket regions (R10-proven geometry: grid-stride, e[8]) ----

__global__ __launch_bounds__(256) void binA_kernel(const int* __restrict__ row,
                                                   const int* __restrict__ col,
                                                   const float* __restrict__ val,
                                                   const uint* __restrict__ keep,
                                                   int* __restrict__ gcur1,
                                                   ull* __restrict__ ebuf1) {
  __shared__ ull stage[CHUNKA];          // 16 KB
  __shared__ short bkt[CHUNKA];          // 4 KB
  __shared__ int hist[NB1], lofs[NB1 + 1], lcur[NB1], gbase[NB1];
  int tid = threadIdx.x;
  for (long base = (long)blockIdx.x * CHUNKA; base < N_EDGES; base += (long)gridDim.x * CHUNKA) {
    int cnt = (int)min((long)CHUNKA, (long)N_EDGES - base);
    if (tid < NB1) hist[tid] = 0;
    __syncthreads();
    ull e[8]; int bk[8];
#pragma unroll
    for (int v = 0; v < 8; ++v) {
      int i = v * 256 + tid;
      bk[v] = -1;
      if (i < cnt) {
        long g = base + i;
        int r = row[g];
        if (keep_test(keep, r)) {
          e[v] = pack_edge(val[g], r, col[g]);
          bk[v] = r >> B1_SHIFT;
          atomicAdd(&hist[bk[v]], 1);
        }
      }
    }
    __syncthreads();
    if (tid < 64) {
      int h = (tid < NB1) ? hist[tid] : 0;
      int x = h;
      for (int o = 1; o < 64; o <<= 1) {
        int y = __shfl_up(x, o);
        if (tid >= o) x += y;
      }
      if (tid < NB1) { lofs[tid] = x - h; lcur[tid] = x - h; }
      if (tid == 63) lofs[NB1] = x;  // kept count in chunk
    }
    __syncthreads();
#pragma unroll
    for (int v = 0; v < 8; ++v) {
      if (bk[v] >= 0) {
        int pos = atomicAdd(&lcur[bk[v]], 1);
        stage[pos] = e[v];
        bkt[pos] = (short)bk[v];
      }
    }
    __syncthreads();
    if (tid < NB1) {
      int h = hist[tid];
      if (h > 0) gbase[tid] = atomicAdd(&gcur1[tid], h);
    }
    __syncthreads();
    int tot = lofs[NB1];
    for (int s = tid; s < tot; s += 256) {
      int lo = bkt[s];
      ebuf1[gbase[lo] + (s - lofs[lo])] = stage[s];
    }
    __syncthreads();
  }
}

// ---------------- pass B: L1 bucket -> 64 sub-bucket regions (R10-proven geometry) ------

__global__ __launch_bounds__(256) void binB_kernel(const ull* __restrict__ ebuf1,
                                                   const int* __restrict__ sub_offs,
                                                   int* __restrict__ gcur2,
                                                   ull* __restrict__ edat) {
  __shared__ ull stage[CHUNKA];          // 16 KB
  __shared__ short bkt[CHUNKA];          // 4 KB
  __shared__ int hist[64], lofs[65], lcur[64], gbase[64];
  int tid = threadIdx.x;
  int b1 = blockIdx.x >> 3, w = blockIdx.x & 7;
  int rbeg = sub_offs[b1 << 6];
  int rend = sub_offs[min((b1 + 1) << 6, NSUB)];
  for (int base = rbeg + w * CHUNKA; base < rend; base += 8 * CHUNKA) {
    int cnt = min(CHUNKA, rend - base);
    if (tid < 64) hist[tid] = 0;
    __syncthreads();
    ull e[8]; int bk[8];
#pragma unroll
    for (int v = 0; v < 8; ++v) {
      int i = v * 256 + tid;
      bk[v] = -1;
      if (i < cnt) {
        e[v] = ebuf1[base + i];
        bk[v] = (edge_row(e[v]) >> SUB_SHIFT) - (b1 << 6);
        atomicAdd(&hist[bk[v]], 1);
      }
    }
    __syncthreads();
    if (tid < 64) {
      int h = hist[tid];
      int x = h;
      for (int o = 1; o < 64; o <<= 1) {
        int y = __shfl_up(x, o);
        if (tid >= o) x += y;
      }
      lofs[tid] = x - h;
      lcur[tid] = x - h;
      if (tid == 63) lofs[64] = x;  // == cnt
    }
    __syncthreads();
#pragma unroll
    for (int v = 0; v < 8; ++v) {
      if (bk[v] >= 0) {
        int pos = atomicAdd(&lcur[bk[v]], 1);
        stage[pos] = e[v];
        bkt[pos] = (short)bk[v];
      }
    }
    __syncthreads();
    if (tid < 64) {
      int h = hist[tid];
      if (h > 0) gbase[tid] = atomicAdd(&gcur2[(b1 << 6) + tid], h);
    }
    __syncthreads();
    for (int s = tid; s < cnt; s += 256) {
      int lo = bkt[s];
      edat[gbase[lo] + (s - lofs[lo])] = stage[s];
    }
    __syncthreads();
  }
}

// ---- pass C: exact row placement within each 32-row sub-bucket (LDS-staged); emits offs ----

__global__ __launch_bounds__(256) void binC_kernel(const int* __restrict__ sub_offs,
                                                   ull* __restrict__ edat,
                                                   ull* __restrict__ ebuf1,
                                                   int* __restrict__ offs) {
  __shared__ ull es[BINC_CAP];           // 16 KB
  __shared__ int rcnt[32], rcur[32];
  int s = blockIdx.x, tid = threadIdx.x;
  int r0 = s << SUB_SHIFT;
  int beg = sub_offs[s], end = sub_offs[s + 1];
  int n = end - beg;
  if (tid < 32) rcnt[tid] = 0;
  __syncthreads();
  if (n <= BINC_CAP) {
    for (int i = tid; i < n; i += 256) {
      ull p = edat[beg + i];
      es[i] = p;
      atomicAdd(&rcnt[edge_row(p) & 31], 1);
    }
    __syncthreads();
    if (tid < 32) {
      int h = rcnt[tid];
      int x = h;
      for (int o = 1; o < 32; o <<= 1) {
        int y = __shfl_up(x, o, 32);
        if (tid >= o) x += y;
      }
      rcur[tid] = x - h;
      offs[r0 + tid] = beg + x - h;
      if (s == NSUB - 1 && tid == 31) offs[N_NODES] = end;
    }
    __syncthreads();
    for (int i = tid; i < n; i += 256) {
      ull p = es[i];
      int pos = atomicAdd(&rcur[edge_row(p) & 31], 1);
      edat[beg + pos] = p;
    }
  } else {  // fallback: global scratch (statistically never at mean ~390)
    for (int i = tid; i < n; i += 256) {
      ull p = edat[beg + i];
      ebuf1[beg + i] = p;
      atomicAdd(&rcnt[edge_row(p) & 31], 1);
    }
    __syncthreads();
    if (tid < 32) {
      int h = rcnt[tid];
      int x = h;
      for (int o = 1; o < 32; o <<= 1) {
        int y = __shfl_up(x, o, 32);
        if (tid >= o) x += y;
      }
      rcur[tid] = x - h;
      offs[r0 + tid] = beg + x - h;
      if (s == NSUB - 1 && tid == 31) offs[N_NODES] = end;
    }
    __syncthreads();
    for (int i = tid; i < n; i += 256) {
      ull p = ebuf1[beg + i];
      int pos = atomicAdd(&rcur[edge_row(p) & 31], 1);
      edat[beg + pos] = p;
    }
  }
}

// ---------------- MFMA GEMM1: a = bf16(x @ W1), W staged fp32->bf16 in-kernel --------
// A frag: A[m=lane&15][k=quad*8+j]; B frag: B[n=lane&15][k=quad*8+j] (W^T layout);
// C/D layout: col = lane&15, row = (lane>>4)*4 + reg.

typedef __attribute__((ext_vector_type(8))) __bf16 bf16x8;
typedef __attribute__((ext_vector_type(4))) float f32x4;
union FragU { uint4 u; bf16x8 b; };

#define LDSTR 68   // uints per 128-feat row in LDS

__global__ __launch_bounds__(256) void gemm1_kernel(const float* __restrict__ A,
                                                    const float* __restrict__ W,
                                                    unsigned short* __restrict__ C,
                                                    int nrows) {
  __shared__ uint As_s[64 * LDSTR];    // 17.4 KB
  __shared__ uint Wt_s[128 * LDSTR];   // 34.8 KB
  int tid = threadIdx.x;
  int rbase = blockIdx.x * 64;

  // stage W fp32 [k][n] -> bf16 [n][k] (reads coalesced along n)
  {
    int n = tid & 127, hh = tid >> 7;
#pragma unroll
    for (int kk = 0; kk < 32; ++kk) {
      int kc = hh * 32 + kk;
      Wt_s[n * LDSTR + kc] = packbf2(W[(2 * kc) * 128 + n], W[(2 * kc + 1) * 128 + n]);
    }
  }
  // stage A tile fp32 -> bf16
  {
    const float4* src = (const float4*)(A + (long)rbase * 128);
#pragma unroll
    for (int i = 0; i < 8; ++i) {
      int f = i * 256 + tid;
      int m = f >> 5;
      float4 v = (rbase + m < nrows) ? src[f] : make_float4(0.f, 0.f, 0.f, 0.f);
      int c = (f & 31) * 2;
      As_s[m * LDSTR + c]     = packbf2(v.x, v.y);
      As_s[m * LDSTR + c + 1] = packbf2(v.z, v.w);
    }
  }
  __syncthreads();

  int w = tid >> 6, lane = tid & 63;
  int quad = lane >> 4, lr = lane & 15;
  int n0 = w * 32;

  f32x4 acc[4][2];
#pragma unroll
  for (int mt = 0; mt < 4; ++mt)
#pragma unroll
    for (int nt = 0; nt < 2; ++nt) acc[mt][nt] = (f32x4){0.f, 0.f, 0.f, 0.f};

#pragma unroll
  for (int kk = 0; kk < 4; ++kk) {
    int kc = kk * 16 + quad * 4;
    FragU fb0, fb1;
    fb0.u = *(const uint4*)&Wt_s[(n0 + lr) * LDSTR + kc];
    fb1.u = *(const uint4*)&Wt_s[(n0 + 16 + lr) * LDSTR + kc];
#pragma unroll
    for (int mt = 0; mt < 4; ++mt) {
      FragU fa;
      fa.u = *(const uint4*)&As_s[(mt * 16 + lr) * LDSTR + kc];
      acc[mt][0] = __builtin_amdgcn_mfma_f32_16x16x32_bf16(fa.b, fb0.b, acc[mt][0], 0, 0, 0);
      acc[mt][1] = __builtin_amdgcn_mfma_f32_16x16x32_bf16(fa.b, fb1.b, acc[mt][1], 0, 0, 0);
    }
  }

#pragma unroll
  for (int mt = 0; mt < 4; ++mt) {
#pragma unroll
    for (int nt = 0; nt < 2; ++nt) {
      int col = n0 + nt * 16 + lr;
#pragma unroll
      for (int r = 0; r < 4; ++r) {
        int row = rbase + mt * 16 + quad * 4 + r;
        if (row < nrows) C[(long)row * 128 + col] = f2bf(acc[mt][nt][r]);
      }
    }
  }
}

// ---- fused GEMM2 + final: t = g2@W2+b2 (MFMA) -> LDS; z = [t,s]@Wl+bl; log_softmax ----

__global__ __launch_bounds__(256) void gemm2f_kernel(const float* __restrict__ g2,
                                                     const float* __restrict__ W2,
                                                     const float* __restrict__ b2,
                                                     const float* __restrict__ s_in,
                                                     const float* __restrict__ Wl,
                                                     const float* __restrict__ bl,
                                                     float* __restrict__ out) {
  __shared__ uint smem[13056];               // 52.2 KB
  uint* Wt_s = smem;                         // [128*68]
  uint* As_s = smem + 128 * LDSTR;           // [64*68]
  float* ts  = (float*)smem;                 // 64 x 129 fp32 (8256 <= 8704, inside Wt area)
  float* Wls = (float*)(smem + 128 * LDSTR); // 3072 fp32 (reuses As area)
  int tid = threadIdx.x;
  int rbase = blockIdx.x * 64;               // grid = 128, exact

  {
    int n = tid & 127, hh = tid >> 7;
#pragma unroll
    for (int kk = 0; kk < 32; ++kk) {
      int kc = hh * 32 + kk;
      Wt_s[n * LDSTR + kc] = packbf2(W2[(2 * kc) * 128 + n], W2[(2 * kc + 1) * 128 + n]);
    }
  }
  {
    const float4* src = (const float4*)(g2 + (long)rbase * 128);
#pragma unroll
    for (int i = 0; i < 8; ++i) {
      int f = i * 256 + tid;
      int m = f >> 5, c = (f & 31) * 2;
      float4 v = src[f];
      As_s[m * LDSTR + c]     = packbf2(v.x, v.y);
      As_s[m * LDSTR + c + 1] = packbf2(v.z, v.w);
    }
  }
  __syncthreads();

  int w = tid >> 6, lane = tid & 63;
  int quad = lane >> 4, lr = lane & 15;
  int n0 = w * 32;

  f32x4 acc[4][2];
#pragma unroll
  for (int mt = 0; mt < 4; ++mt)
#pragma unroll
    for (int nt = 0; nt < 2; ++nt) acc[mt][nt] = (f32x4){0.f, 0.f, 0.f, 0.f};

#pragma unroll
  for (int kk = 0; kk < 4; ++kk) {
    int kc = kk * 16 + quad * 4;
    FragU fb0, fb1;
    fb0.u = *(const uint4*)&Wt_s[(n0 + lr) * LDSTR + kc];
    fb1.u = *(const uint4*)&Wt_s[(n0 + 16 + lr) * LDSTR + kc];
#pragma unroll
    for (int mt = 0; mt < 4; ++mt) {
      FragU fa;
      fa.u = *(const uint4*)&As_s[(mt * 16 + lr) * LDSTR + kc];
      acc[mt][0] = __builtin_amdgcn_mfma_f32_16x16x32_bf16(fa.b, fb0.b, acc[mt][0], 0, 0, 0);
      acc[mt][1] = __builtin_amdgcn_mfma_f32_16x16x32_bf16(fa.b, fb1.b, acc[mt][1], 0, 0, 0);
    }
  }
  __syncthreads();   // all LDS reads complete before region reuse

  // t -> LDS (stride 129: conflict-free column reads); stage Wl
#pragma unroll
  for (int mt = 0; mt < 4; ++mt) {
#pragma unroll
    for (int nt = 0; nt < 2; ++nt) {
      int col = n0 + nt * 16 + lr;
      float bv = b2[col];
#pragma unroll
      for (int r = 0; r < 4; ++r)
        ts[(mt * 16 + quad * 4 + r) * 129 + col] = acc[mt][nt][r] + bv;
    }
  }
  for (int i = tid; i < 192 * 16; i += 256) Wls[i] = Wl[i];
  __syncthreads();

  // z = [t, s] @ Wl + bl; 4 lanes per row, 48 k-dims each, shfl reduce
  int q = lane & 3;
  int mrow = w * 16 + (lane >> 2);
  int b = rbase + mrow;
  float z[16];
#pragma unroll
  for (int c = 0; c < 16; ++c) z[c] = 0.f;
  int k0 = q * 48;
  for (int kk = 0; kk < 48; ++kk) {
    int k = k0 + kk;
    float xv = (k < 128) ? ts[mrow * 129 + k] : s_in[(long)b * 64 + (k - 128)];
    const float* wp = Wls + k * 16;
#pragma unroll
    for (int c = 0; c < 16; ++c) z[c] = fmaf(xv, wp[c], z[c]);
  }
#pragma unroll
  for (int c = 0; c < 16; ++c) {
    z[c] += __shfl_xor(z[c], 1);
    z[c] += __shfl_xor(z[c], 2);
  }
  if (q == 0) {
#pragma unroll
    for (int c = 0; c < 16; ++c) z[c] += bl[c];
    float mx = z[0];
#pragma unroll
    for (int c = 1; c < 16; ++c) mx = fmaxf(mx, z[c]);
    float sum = 0.f;
#pragma unroll
    for (int c = 0; c < 16; ++c) sum += expf(z[c] - mx);
    float lse = mx + logf(sum);
    float4* ob = (float4*)(out + (long)b * 16);
    ob[0] = make_float4(z[0] - lse, z[1] - lse, z[2] - lse, z[3] - lse);
    ob[1] = make_float4(z[4] - lse, z[5] - lse, z[6] - lse, z[7] - lse);
    ob[2] = make_float4(z[8] - lse, z[9] - lse, z[10] - lse, z[11] - lse);
    ob[3] = make_float4(z[12] - lse, z[13] - lse, z[14] - lse, z[15] - lse);
  }
}

// ---- CSR spmm: 4 waves/block, 1 row/wave, 4 edge-groups x 16 lanes x 8 feats, 2x unroll ----

__device__ __forceinline__ void fma_row(float* acc, float v, uint4 u) {
  acc[0] = fmaf(v, bflo(u.x), acc[0]);
  acc[1] = fmaf(v, bfhi(u.x), acc[1]);
  acc[2] = fmaf(v, bflo(u.y), acc[2]);
  acc[3] = fmaf(v, bfhi(u.y), acc[3]);
  acc[4] = fmaf(v, bflo(u.z), acc[4]);
  acc[5] = fmaf(v, bfhi(u.z), acc[5]);
  acc[6] = fmaf(v, bflo(u.w), acc[6]);
  acc[7] = fmaf(v, bfhi(u.w), acc[7]);
}

__global__ __launch_bounds__(256) void spmm_row_kernel(const int* __restrict__ offs,
                                                       const ull* __restrict__ edat,
                                                       const unsigned short* __restrict__ a,
                                                       const float* __restrict__ bias,
                                                       unsigned short* __restrict__ h,
                                                       const uint* __restrict__ keep) {
  int wave = threadIdx.x >> 6;
  int lane = threadIdx.x & 63;
  int r = blockIdx.x * 4 + wave;           // grid = 25000, exact
  if (!keep_test(keep, r)) return;
  int g = lane >> 4, l = lane & 15;
  int s = offs[r], e = offs[r + 1];
  float acc[8] = {0.f, 0.f, 0.f, 0.f, 0.f, 0.f, 0.f, 0.f};
  int j = s + g;
  for (; j + 4 < e; j += 8) {
    ull p0 = edat[j];
    ull p1 = edat[j + 4];
    uint4 u0 = *(const uint4*)(a + (long)edge_col(p0) * 128 + l * 8);
    uint4 u1 = *(const uint4*)(a + (long)edge_col(p1) * 128 + l * 8);
    fma_row(acc, edge_val(p0), u0);
    fma_row(acc, edge_val(p1), u1);
  }
  if (j < e) {
    ull p = edat[j];
    uint4 u = *(const uint4*)(a + (long)edge_col(p) * 128 + l * 8);
    fma_row(acc, edge_val(p), u);
  }
#pragma unroll
  for (int k = 0; k < 8; ++k) {
    acc[k] += __shfl_xor(acc[k], 16);
    acc[k] += __shfl_xor(acc[k], 32);
  }
  if (g == 0) {
    float4 b0 = *(const float4*)(bias + l * 8);
    float4 b1 = *(const float4*)(bias + l * 8 + 4);
    uint4 o;
    o.x = packbf2(fmaxf(acc[0] + b0.x, 0.f), fmaxf(acc[1] + b0.y, 0.f));
    o.y = packbf2(fmaxf(acc[2] + b0.z, 0.f), fmaxf(acc[3] + b0.w, 0.f));
    o.z = packbf2(fmaxf(acc[4] + b1.x, 0.f), fmaxf(acc[5] + b1.y, 0.f));
    o.w = packbf2(fmaxf(acc[6] + b1.z, 0.f), fmaxf(acc[7] + b1.w, 0.f));
    *(uint4*)(h + (long)r * 128 + l * 8) = o;
  }
}

__global__ __launch_bounds__(256) void spmm_sel_kernel(const int* __restrict__ offs,
                                                       const ull* __restrict__ edat,
                                                       const unsigned short* __restrict__ h1,
                                                       const int* __restrict__ index,
                                                       float* __restrict__ g2) {
  int wave = threadIdx.x >> 6;
  int lane = threadIdx.x & 63;
  int b = blockIdx.x * 4 + wave;           // grid = 2048, exact
  int g = lane >> 4, l = lane & 15;
  int r = index[b];
  int s = offs[r], e = offs[r + 1];
  float acc[8] = {0.f, 0.f, 0.f, 0.f, 0.f, 0.f, 0.f, 0.f};
  int j = s + g;
  for (; j + 4 < e; j += 8) {
    ull p0 = edat[j];
    ull p1 = edat[j + 4];
    uint4 u0 = *(const uint4*)(h1 + (long)edge_col(p0) * 128 + l * 8);
    uint4 u1 = *(const uint4*)(h1 + (long)edge_col(p1) * 128 + l * 8);
    fma_row(acc, edge_val(p0), u0);
    fma_row(acc, edge_val(p1), u1);
  }
  if (j < e) {
    ull p = edat[j];
    uint4 u = *(const uint4*)(h1 + (long)edge_col(p) * 128 + l * 8);
    fma_row(acc, edge_val(p), u);
  }
#pragma unroll
  for (int k = 0; k < 8; ++k) {
    acc[k] += __shfl_xor(acc[k], 16);
    acc[k] += __shfl_xor(acc[k], 32);
  }
  if (g == 0) {
    float* op = g2 + (long)b * 128 + l * 8;
    *(float4*)(op + 0) = make_float4(acc[0], acc[1], acc[2], acc[3]);
    *(float4*)(op + 4) = make_float4(acc[4], acc[5], acc[6], acc[7]);
  }
}

// ---------------- launch ----------------

extern "C" void kernel_launch(void* const* d_in, const int* in_sizes, int n_in,
                              void* d_out, int out_size, void* d_ws, size_t ws_size,
                              hipStream_t stream) {
  const float* s_in  = (const float*)d_in[0];
  const float* x     = (const float*)d_in[1];
  const int*   row   = (const int*)d_in[2];
  const int*   col   = (const int*)d_in[3];
  const float* val   = (const float*)d_in[4];
  const int*   index = (const int*)d_in[5];
  const float* W1    = (const float*)d_in[6];
  const float* b1    = (const float*)d_in[7];
  const float* W2    = (const float*)d_in[8];
  const float* b2    = (const float*)d_in[9];
  const float* Wl    = (const float*)d_in[10];
  const float* bl    = (const float*)d_in[11];
  float* out = (float*)d_out;

  // workspace carve (~82 MB), 8B-aligned first
  ull* edat  = (ull*)d_ws;                                           // [1.6M] final CSR edges
  ull* ebuf1 = edat + N_EDGES;                                       // [1.6M] binA out / binC fallback
  unsigned short* a  = (unsigned short*)(ebuf1 + N_EDGES);           // xW1 bf16   [100000,128]
  unsigned short* h1 = a + (size_t)N_NODES * 128;                    // layer1 bf16[100000,128]
  float* g2   = (float*)(h1 + (size_t)N_NODES * 128);                // sel spmm   [8192,128]
  int* sel    = (int*)(g2 + (size_t)BB * 128);                       // [100000] selected mask
  int* subcnt = sel + N_NODES;                                       // [3125]
  uint* keep  = (uint*)(subcnt + NSUB);                              // [3125] flag|sel bitmask
  int* offs   = (int*)(keep + NSUB);                                 // [100001] (binC writes)
  int* sub_offs = offs + (N_NODES + 1);                              // [3126]
  int* gcur1  = sub_offs + (NSUB + 1);                               // [49]
  int* gcur2  = gcur1 + NB1;                                         // [3125]

  hipMemsetAsync(sel, 0, (N_NODES + 2 * NSUB) * sizeof(int), stream);  // sel+subcnt+keep

  selbuild_kernel<<<BB / 256, 256, 0, stream>>>(index, sel, keep);
  selflag_kernel<<<4096, 256, 0, stream>>>(row, col, sel, keep);
  histsub_kernel<<<HWG, 256, 0, stream>>>(row, keep, subcnt);
  scanall_kernel<<<1, 1024, 0, stream>>>(subcnt, sub_offs, gcur1, gcur2);

  binA_kernel<<<512, 256, 0, stream>>>(row, col, val, keep, gcur1, ebuf1);
  binB_kernel<<<NB1 * 8, 256, 0, stream>>>(ebuf1, sub_offs, gcur2, edat);
  binC_kernel<<<NSUB, 256, 0, stream>>>(sub_offs, edat, ebuf1, offs);

  gemm1_kernel<<<(N_NODES + 63) / 64, 256, 0, stream>>>(x, W1, a, N_NODES);
  spmm_row_kernel<<<N_NODES / 4, 256, 0, stream>>>(offs, edat, a, b1, h1, keep);
  spmm_sel_kernel<<<BB / 4, 256, 0, stream>>>(offs, edat, h1, index, g2);
  gemm2f_kernel<<<BB / 64, 256, 0, stream>>>(g2, W2, b2, s_in, Wl, bl, out);
}